// Round 11
// baseline (835.092 us; speedup 1.0000x reference)
//
#include <hip/hip_runtime.h>
#include <math.h>

#define NPTS 16384
#define KNB 20
#define SCAP 512
#define SCAP2 448

typedef __attribute__((ext_vector_type(8))) short short8;
typedef __attribute__((ext_vector_type(4))) float f32x4;

// ---------------- workspace layout (bytes, all naturally 256-aligned) ----------------
static const size_t OFF_F0   = 0;                                   // N x float4
static const size_t OFF_SSQ0 = OFF_F0   + (size_t)NPTS*4*4;         // N f32
static const size_t OFF_IDX1 = OFF_SSQ0 + (size_t)NPTS*4;           // N*20 i32
static const size_t OFF_XMX1 = OFF_IDX1 + (size_t)NPTS*KNB*4;       // N*64 f32
static const size_t OFF_XMN1 = OFF_XMX1 + (size_t)NPTS*64*4;        // N*64 f32
static const size_t OFF_SUM1 = OFF_XMN1 + (size_t)NPTS*64*4;        // 128 f32 (sum,sumsq)
static const size_t OFF_X1   = OFF_SUM1 + 512;                      // N*64 f32
static const size_t OFF_SSQ1 = OFF_X1   + (size_t)NPTS*64*4;        // N f32
static const size_t OFF_IDX2 = OFF_SSQ1 + (size_t)NPTS*4;           // N*20 i32 (global idx)
static const size_t OFF_XMX2 = OFF_IDX2 + (size_t)NPTS*KNB*4;       // N*128 f32
static const size_t OFF_XMN2 = OFF_XMX2 + (size_t)NPTS*128*4;       // N*128 f32
static const size_t OFF_SUM2 = OFF_XMN2 + (size_t)NPTS*128*4;       // 256 f32
static const size_t OFF_X2   = OFF_SUM2 + 1024;                     // N*128 f32
static const size_t OFF_SUMF = OFF_X2   + (size_t)NPTS*128*4;       // 512 f32
static const size_t OFF_HPMX = OFF_SUMF + 2048;                     // 8*256 u32 (float bits)
static const size_t OFF_HPMN = OFF_HPMX + 8*256*4;                  // 8*256 u32
// WT_g (bf16 W^T for mlp2, 32 KB) ALIASES x2 head: x2 is dead until bn2apply,
// which runs AFTER mlp2 has consumed wtg. k_init writes it first thing.

// ---------------- helpers ----------------
__device__ __forceinline__ float dot4f(float4 a, float4 b) {
  return a.x*b.x + a.y*b.y + a.z*b.z + a.w*b.w;
}

__device__ __forceinline__ float dot64v(const float* a, const float4* b4) {
  float s = 0.f;
  #pragma unroll
  for (int d4 = 0; d4 < 16; ++d4) {
    float4 b = b4[d4];
    s += a[4*d4+0]*b.x + a[4*d4+1]*b.y + a[4*d4+2]*b.z + a[4*d4+3]*b.w;
  }
  return s;
}

// f32 -> bf16 (RNE)
__device__ __forceinline__ short f2bf(float x) {
  union { float f; unsigned u; } v; v.f = x;
  unsigned r = (v.u + 0x7FFFu + ((v.u >> 16) & 1u)) >> 16;
  return (short)r;
}

// ---------------- branch-free sorting-network top-k machinery (with indices) ----------------
__device__ __forceinline__ void ce(float& a, int& ai, float& b, int& bi) {
  bool sw = b < a;
  float d0 = sw ? b : a;  float d1 = sw ? a : b;
  int   j0 = sw ? bi : ai; int  j1 = sw ? ai : bi;
  a = d0; ai = j0; b = d1; bi = j1;
}

__device__ __forceinline__ void sort16(float (&d)[16], int (&ix)[16]) {
  #pragma unroll
  for (int k = 2; k <= 16; k <<= 1) {
    #pragma unroll
    for (int j = k >> 1; j > 0; j >>= 1) {
      #pragma unroll
      for (int i = 0; i < 16; ++i) {
        int l = i ^ j;
        if (l > i) {
          if ((i & k) == 0) ce(d[i], ix[i], d[l], ix[l]);
          else              ce(d[l], ix[l], d[i], ix[i]);
        }
      }
    }
  }
}

__device__ __forceinline__ void bimerge32(float (&rd)[32], int (&ri)[32]) {
  #pragma unroll
  for (int j = 16; j > 0; j >>= 1) {
    #pragma unroll
    for (int i = 0; i < 32; ++i) {
      int l = i ^ j;
      if (l > i) ce(rd[i], ri[i], rd[l], ri[l]);
    }
  }
}

__device__ __forceinline__ void merge16(float (&rd)[32], int (&ri)[32],
                                        float (&bd)[16], int (&bi)[16]) {
  #pragma unroll
  for (int k = 0; k < 16; ++k) {
    bool sw = bd[15-k] < rd[16+k];
    rd[16+k] = sw ? bd[15-k] : rd[16+k];
    ri[16+k] = sw ? bi[15-k] : ri[16+k];
  }
  bimerge32(rd, ri);
}

__device__ __forceinline__ void mergelane(float (&rd)[32], int (&ri)[32], int mask) {
  float pd[32]; int pi[32];
  #pragma unroll
  for (int s = 0; s < 32; ++s) { pd[s] = __shfl_xor(rd[s], mask); pi[s] = __shfl_xor(ri[s], mask); }
  #pragma unroll
  for (int k = 0; k < 32; ++k) {
    bool sw = pd[31-k] < rd[k];
    rd[k] = sw ? pd[31-k] : rd[k];
    ri[k] = sw ? pi[31-k] : ri[k];
  }
  bimerge32(rd, ri);
}

// ---------------- value-only versions (threshold computation, 2 ops/CE) ----------------
__device__ __forceinline__ void vce(float& a, float& b) {
  float lo = fminf(a, b);
  b = fmaxf(a, b);
  a = lo;
}

__device__ __forceinline__ void vsort16(float (&d)[16]) {
  #pragma unroll
  for (int k = 2; k <= 16; k <<= 1) {
    #pragma unroll
    for (int j = k >> 1; j > 0; j >>= 1) {
      #pragma unroll
      for (int i = 0; i < 16; ++i) {
        int l = i ^ j;
        if (l > i) {
          if ((i & k) == 0) vce(d[i], d[l]);
          else              vce(d[l], d[i]);
        }
      }
    }
  }
}

__device__ __forceinline__ void vbimerge32(float (&rd)[32]) {
  #pragma unroll
  for (int j = 16; j > 0; j >>= 1) {
    #pragma unroll
    for (int i = 0; i < 32; ++i) {
      int l = i ^ j;
      if (l > i) vce(rd[i], rd[l]);
    }
  }
}

__device__ __forceinline__ void vmerge16(float (&rd)[32], float (&bd)[16]) {
  #pragma unroll
  for (int k = 0; k < 16; ++k) rd[16+k] = fminf(rd[16+k], bd[15-k]);
  vbimerge32(rd);
}

__device__ __forceinline__ void vmergelane(float (&rd)[32], int mask) {
  float pd[32];
  #pragma unroll
  for (int s = 0; s < 32; ++s) pd[s] = __shfl_xor(rd[s], mask);
  #pragma unroll
  for (int k = 0; k < 32; ++k) rd[k] = fminf(rd[k], pd[31-k]);
  vbimerge32(rd);
}

// ---------------- init + f0 + wprep fused (grid 64; accumulators reset EVERY launch) ----------------
__global__ __launch_bounds__(256) void k_init(const float* __restrict__ pos, const float* __restrict__ x,
                                              const float* __restrict__ w2,
                                              float4* __restrict__ f0, float* __restrict__ ssq,
                                              short* __restrict__ wtg,
                                              float* sum1, float* sum2, float* sumF,
                                              unsigned* hpmx, unsigned* hpmn) {
  int gt = blockIdx.x*256 + threadIdx.x;   // 0..16383
  float4 f;
  f.x = pos[3*gt+0]; f.y = pos[3*gt+1]; f.z = pos[3*gt+2]; f.w = x[gt];
  f0[gt] = f;
  ssq[gt] = dot4f(f, f);
  { int c = gt >> 7, k = gt & 127; wtg[c*128 + k] = f2bf(w2[k*128 + c]); }
  if (gt < 128) sum1[gt] = 0.f;
  if (gt < 256) sum2[gt] = 0.f;
  if (gt < 512) sumF[gt] = 0.f;
  if (gt < 2048) { hpmx[gt] = 0u; hpmn[gt] = 0x7f800000u; }   // relu>=0 -> uint order == float order
}

// ---------------- knn1 v4: global-direct two-phase exact; survivors store INDEX ONLY ----------------
__global__ __launch_bounds__(256) void k_knn1(const float4* __restrict__ f0, const float* __restrict__ ssq,
                                              int* __restrict__ idx1) {
  __shared__ int survj[8][SCAP];
  __shared__ int scnt[8];
  __shared__ float rowT[8];
  int t = threadIdx.x;
  int r = t >> 5;
  int lane = t & 31;
  int row = blockIdx.x*8 + r;
  if (t < 8) scnt[t] = 0;
  float4 fi = f0[row];
  float sqi = ssq[row];
  // ---- pass 1: value-only top-32 of sample [0,2048)
  {
    float rd[32];
    #pragma unroll
    for (int s = 0; s < 32; ++s) rd[s] = INFINITY;
    #pragma unroll
    for (int b = 0; b < 4; ++b) {
      float bd[16];
      #pragma unroll
      for (int u = 0; u < 16; ++u) {
        int j = b*512 + u*32 + lane;
        float4 c = f0[j];
        bd[u] = (sqi - 2.f*dot4f(fi, c)) + ssq[j];
      }
      vsort16(bd);
      vmerge16(rd, bd);
    }
    vmergelane(rd, 1); vmergelane(rd, 2); vmergelane(rd, 4);
    vmergelane(rd, 8); vmergelane(rd, 16);
    if (lane == 0) rowT[r] = rd[19];
  }
  __syncthreads();
  // ---- pass 2: candidate-major filter over all 16384
  {
    float4 fr[8]; float sr[8], Tr[8];
    #pragma unroll
    for (int q = 0; q < 8; ++q) {
      fr[q] = f0[blockIdx.x*8 + q];
      sr[q] = ssq[blockIdx.x*8 + q];
      Tr[q] = rowT[q];
    }
    #pragma unroll 4
    for (int k = 0; k < 64; ++k) {
      int j = k*256 + t;
      float4 c = f0[j];
      float cq = ssq[j];
      #pragma unroll
      for (int q = 0; q < 8; ++q) {
        float d = (sr[q] - 2.f*dot4f(fr[q], c)) + cq;
        if (d <= Tr[q]) {
          int slot = atomicAdd(&scnt[q], 1);
          if (slot < SCAP) survj[q][slot] = j;
        }
      }
    }
  }
  __syncthreads();
  int n = scnt[r] < SCAP ? scnt[r] : SCAP;
  // ---- pass 3: recompute d (bitwise-identical expr) + exact index top-20
  float rd[32]; int ri[32];
  #pragma unroll
  for (int s = 0; s < 32; ++s) { rd[s] = INFINITY; ri[s] = 0; }
  {
    float bd[16]; int bix[16];
    #pragma unroll
    for (int u = 0; u < 16; ++u) {
      int s = u*32 + lane;
      if (s < n) {
        int j = survj[r][s];
        float4 c = f0[j];
        bd[u] = (sqi - 2.f*dot4f(fi, c)) + ssq[j];
        bix[u] = j;
      } else { bd[u] = INFINITY; bix[u] = 0; }
    }
    sort16(bd, bix);
    merge16(rd, ri, bd, bix);
  }
  mergelane(rd, ri, 1); mergelane(rd, ri, 2); mergelane(rd, ri, 4);
  mergelane(rd, ri, 8); mergelane(rd, ri, 16);
  if (lane == 0) {
    int4* p = (int4*)&idx1[row*KNB];
    p[0] = make_int4(ri[0],ri[1],ri[2],ri[3]);
    p[1] = make_int4(ri[4],ri[5],ri[6],ri[7]);
    p[2] = make_int4(ri[8],ri[9],ri[10],ri[11]);
    p[3] = make_int4(ri[12],ri[13],ri[14],ri[15]);
    p[4] = make_int4(ri[16],ri[17],ri[18],ri[19]);
  }
}

// ---------------- mlp1: edge MLP 8->64, relu, per-point max/min (pre-BN), channel sums ----------------
__global__ __launch_bounds__(256) void k_mlp1(const float4* __restrict__ f0, const int* __restrict__ idx1,
                                              const float* __restrict__ w1, const float* __restrict__ b1,
                                              float* __restrict__ xmx, float* __restrict__ xmn,
                                              float* __restrict__ sums) {
  __shared__ float rs[256], rs2[256];
  int t = threadIdx.x;
  int c = t & 63;
  int w = t >> 6;
  float wc[8];
  #pragma unroll
  for (int d = 0; d < 8; ++d) wc[d] = w1[d*64 + c];
  float bc = b1[c];
  float s = 0.f, s2 = 0.f;
  for (int p = 0; p < 8; ++p) {
    int i = blockIdx.x*32 + p*4 + w;
    float4 fi = f0[i];
    float mx = -INFINITY, mn = INFINITY;
    #pragma unroll
    for (int k = 0; k < KNB; ++k) {
      int j = idx1[i*KNB + k];
      float4 fj = f0[j];
      float h = bc + fi.x*wc[0] + fi.y*wc[1] + fi.z*wc[2] + fi.w*wc[3]
                   + (fj.x-fi.x)*wc[4] + (fj.y-fi.y)*wc[5] + (fj.z-fi.z)*wc[6] + (fj.w-fi.w)*wc[7];
      h = fmaxf(h, 0.f);
      mx = fmaxf(mx, h); mn = fminf(mn, h);
      s += h; s2 += h*h;
    }
    xmx[i*64+c] = mx; xmn[i*64+c] = mn;
  }
  rs[t] = s; rs2[t] = s2;
  __syncthreads();
  if (t < 64) {
    atomicAdd(&sums[c],      rs[t]+rs[t+64]+rs[t+128]+rs[t+192]);
    atomicAdd(&sums[64+c],   rs2[t]+rs2[t+64]+rs2[t+128]+rs2[t+192]);
  }
}

// ---------------- bn1 apply: x1 = affine(max or min by scale sign) ----------------
__global__ __launch_bounds__(256) void k_bn1apply(const float* __restrict__ sums, const float* __restrict__ g,
                                                  const float* __restrict__ be, const float* __restrict__ xmx,
                                                  const float* __restrict__ xmn, float* __restrict__ x1) {
  __shared__ float sc_s[64], sh_s[64];
  int t = threadIdx.x;
  if (t < 64) {
    float m = sums[t] * (1.f/327680.f);
    float v = sums[64+t] * (1.f/327680.f) - m*m;
    float sc = g[t] / sqrtf(v + 1e-5f);
    sc_s[t] = sc; sh_s[t] = be[t] - m*sc;
  }
  __syncthreads();
  int c = t & 63;
  int i = blockIdx.x*4 + (t>>6);
  float sc = sc_s[c], sh = sh_s[c];
  float val = (sc >= 0.f) ? xmx[i*64+c] : xmn[i*64+c];
  x1[i*64+c] = sc*val + sh;
}

// ---------------- ssq1 (same dot64v ordering as knn2 pass-3 for exact self-distance) ----------------
__global__ __launch_bounds__(256) void k_ssq1(const float* __restrict__ x1, float* __restrict__ ssq1) {
  int i = blockIdx.x*256 + threadIdx.x;
  alignas(16) float f[64];
  #pragma unroll
  for (int d4 = 0; d4 < 16; ++d4) ((float4*)f)[d4] = ((const float4*)x1)[i*16 + d4];
  ssq1[i] = dot64v(f, (const float4*)f);
}

// ---------------- knn2 v2: per-batch 2048-point 64-d knn, MFMA-filtered exact 3-phase ----------------
// Block = 32 query rows x one batch; grid 512 = 8 batches x 64 row-groups.
// Phase 1: exact fp32 sample-256 threshold rowT (value-only network).
// Phase 2: bf16 MFMA Gram tiles -> d_hat; accept iff d_hat <= rowT + M where
//          M = 2^-7 (sq_i + sq_j) >= 3.9x the provable bf16-rounding bound
//          |d_hat - d| <= ~2.0e-3 (sq_i+sq_j)  -> survivors PROVABLY contain
//          the true top-20. Survivors as ushort (batch-local idx), cap 448 (~9 sigma).
// Phase 3: exact fp32 recompute (expression-identical to ssq1 -> d(i,i)==0) +
//          exact index network. Selection set is EXACT -> output unchanged.
__global__ __launch_bounds__(256) void k_knn2(const float* __restrict__ x1, const float* __restrict__ ssq1,
                                              int* __restrict__ idx2) {
  __shared__ __align__(16) short Abf[32*72];
  __shared__ __align__(16) short Bbf[128*72];
  __shared__ float sqA[32];
  __shared__ float sqB[128];
  __shared__ float rowT[32];
  __shared__ unsigned short surv[32][SCAP2];
  __shared__ int scnt[32];
  int t = threadIdx.x;
  int b = blockIdx.x >> 6;
  int rg = blockIdx.x & 63;
  int cbase = b*2048;
  int row0 = cbase + rg*32;
  if (t < 32) { scnt[t] = 0; sqA[t] = ssq1[row0 + t]; }
  // stage A rows bf16: 32 rows x 8 k-chunks (1 short8/thread)
  {
    int rr = t >> 3, kc = t & 7;
    float4 a0 = ((const float4*)x1)[(row0+rr)*16 + kc*2];
    float4 a1 = ((const float4*)x1)[(row0+rr)*16 + kc*2 + 1];
    short8 o;
    o[0]=f2bf(a0.x); o[1]=f2bf(a0.y); o[2]=f2bf(a0.z); o[3]=f2bf(a0.w);
    o[4]=f2bf(a1.x); o[5]=f2bf(a1.y); o[6]=f2bf(a1.z); o[7]=f2bf(a1.w);
    *(short8*)&Abf[rr*72 + kc*8] = o;
  }
  // ---- phase 1: exact fp32 threshold from sample [cbase, cbase+256); 32 rows x 8 lanes
  {
    int r = t >> 3, lane = t & 7;
    int row = row0 + r;
    alignas(16) float fi[64];
    #pragma unroll
    for (int d4 = 0; d4 < 16; ++d4) ((float4*)fi)[d4] = ((const float4*)x1)[row*16 + d4];
    float sqi = ssq1[row];
    float rd[32];
    #pragma unroll
    for (int s = 0; s < 32; ++s) rd[s] = INFINITY;
    #pragma unroll
    for (int bb = 0; bb < 2; ++bb) {
      float bd[16];
      #pragma unroll
      for (int u = 0; u < 16; ++u) {
        int j = cbase + bb*128 + u*8 + lane;
        bd[u] = (sqi - 2.f*dot64v(fi, (const float4*)&x1[j*64])) + ssq1[j];
      }
      vsort16(bd);
      vmerge16(rd, bd);
    }
    vmergelane(rd, 1); vmergelane(rd, 2); vmergelane(rd, 4);
    if (lane == 0) rowT[r] = rd[19];
  }
  __syncthreads();
  // ---- phase 2: MFMA-filtered scan of all 2048 candidates
  int w = t >> 6, l = t & 63;
  short8 af[2][2];
  #pragma unroll
  for (int m = 0; m < 2; ++m)
    #pragma unroll
    for (int kb = 0; kb < 2; ++kb)
      af[m][kb] = *(short8*)&Abf[(m*16 + (l & 15))*72 + kb*32 + (l >> 4)*8];
  for (int ct = 0; ct < 16; ++ct) {
    int cb = ct*128;
    __syncthreads();                       // protect Bbf/sqB reuse
    #pragma unroll
    for (int cc = 0; cc < 4; ++cc) {
      int v = t + cc*256;
      int rr = v >> 3, kc = v & 7;
      int j = cbase + cb + rr;
      float4 a0 = ((const float4*)x1)[j*16 + kc*2];
      float4 a1 = ((const float4*)x1)[j*16 + kc*2 + 1];
      short8 o;
      o[0]=f2bf(a0.x); o[1]=f2bf(a0.y); o[2]=f2bf(a0.z); o[3]=f2bf(a0.w);
      o[4]=f2bf(a1.x); o[5]=f2bf(a1.y); o[6]=f2bf(a1.z); o[7]=f2bf(a1.w);
      *(short8*)&Bbf[rr*72 + kc*8] = o;
      if (kc == 0) sqB[rr] = ssq1[j];
    }
    __syncthreads();
    #pragma unroll
    for (int cs = 0; cs < 2; ++cs) {
      int c16 = (w*2 + cs)*16;
      short8 bfr[2];
      #pragma unroll
      for (int kb = 0; kb < 2; ++kb)
        bfr[kb] = *(short8*)&Bbf[(c16 + (l & 15))*72 + kb*32 + (l >> 4)*8];
      int jcol = c16 + (l & 15);
      float sb = sqB[jcol];
      #pragma unroll
      for (int m = 0; m < 2; ++m) {
        f32x4 acc = {0.f, 0.f, 0.f, 0.f};
        acc = __builtin_amdgcn_mfma_f32_16x16x32_bf16(af[m][0], bfr[0], acc, 0, 0, 0);
        acc = __builtin_amdgcn_mfma_f32_16x16x32_bf16(af[m][1], bfr[1], acc, 0, 0, 0);
        #pragma unroll
        for (int reg = 0; reg < 4; ++reg) {
          int il = m*16 + (l >> 4)*4 + reg;
          float sa = sqA[il];
          float dh = (sa - 2.f*acc[reg]) + sb;
          float M = 0.0078125f*(sa + sb);
          if (dh <= rowT[il] + M) {
            int slot = atomicAdd(&scnt[il], 1);
            if (slot < SCAP2) surv[il][slot] = (unsigned short)(cb + jcol);
          }
        }
      }
    }
  }
  __syncthreads();
  // ---- phase 3: exact fp32 recompute + index top-20; 32 rows x 8 lanes
  {
    int r = t >> 3, lane = t & 7;
    int row = row0 + r;
    int n = scnt[r] < SCAP2 ? scnt[r] : SCAP2;
    alignas(16) float fi[64];
    #pragma unroll
    for (int d4 = 0; d4 < 16; ++d4) ((float4*)fi)[d4] = ((const float4*)x1)[row*16 + d4];
    float sqi = ssq1[row];
    float rd[32]; int ri[32];
    #pragma unroll
    for (int s = 0; s < 32; ++s) { rd[s] = INFINITY; ri[s] = 0; }
    #pragma unroll
    for (int g = 0; g < 4; ++g) {
      float bd[16]; int bix[16];
      #pragma unroll
      for (int u = 0; u < 16; ++u) {
        int s = (g*16 + u)*8 + lane;
        if (s < n) {
          int j = cbase + (int)surv[r][s];
          bd[u] = (sqi - 2.f*dot64v(fi, (const float4*)&x1[j*64])) + ssq1[j];
          bix[u] = j;
        } else { bd[u] = INFINITY; bix[u] = 0; }
      }
      sort16(bd, bix);
      merge16(rd, ri, bd, bix);
    }
    mergelane(rd, ri, 1); mergelane(rd, ri, 2); mergelane(rd, ri, 4);
    if (lane == 0) {
      int4* p = (int4*)&idx2[row*KNB];
      p[0] = make_int4(ri[0],ri[1],ri[2],ri[3]);
      p[1] = make_int4(ri[4],ri[5],ri[6],ri[7]);
      p[2] = make_int4(ri[8],ri[9],ri[10],ri[11]);
      p[3] = make_int4(ri[12],ri[13],ri[14],ri[15]);
      p[4] = make_int4(ri[16],ri[17],ri[18],ri[19]);
    }
  }
}

// ---------------- mlp2: edge MLP 128->128, shared-xi decomposition ----------------
__global__ __launch_bounds__(256) void k_mlp2(const float* __restrict__ x1, const int* __restrict__ idx2,
                                              const short* __restrict__ wtg, const float* __restrict__ w2,
                                              const float* __restrict__ b2,
                                              float* __restrict__ xmx, float* __restrict__ xmn,
                                              float* __restrict__ sums) {
  __shared__ __align__(16) short Elds[4*32*72];   // diffs only: [p][row][k<64], pitch 72
  __shared__ float xi_s[4][64];
  __shared__ float vi[4][128];
  __shared__ int js[4][KNB];
  int t = threadIdx.x;
  if (t < 4*KNB) js[t/KNB][t%KNB] = idx2[blockIdx.x*4*KNB + t];
  {
    int p = t >> 6, k = t & 63;
    xi_s[p][k] = x1[(blockIdx.x*4 + p)*64 + k];
  }
  __syncthreads();
  // vi[p][c] = b2[c] + sum_{k<64} xi[k]*w2[k][c]  (fp32 exact top-half + bias)
  #pragma unroll
  for (int v2 = 0; v2 < 2; ++v2) {
    int v = t + v2*256;
    int p = v >> 7, c = v & 127;
    float a = b2[c];
    #pragma unroll 8
    for (int k = 0; k < 64; ++k) a += xi_s[p][k] * w2[k*128 + c];
    vi[p][c] = a;
  }
  // stage E diffs (bf16): 4 pts x 32 rows x 8 chunks of 8
  #pragma unroll
  for (int cc = 0; cc < 4; ++cc) {
    int v = t + cc*256;
    int p  = v >> 8;
    int rr = (v >> 3) & 31;
    int kc = v & 7;
    short8 outv = {0,0,0,0,0,0,0,0};
    if (rr < KNB) {
      int j = js[p][rr];
      float4 j0 = ((const float4*)x1)[j*16 + kc*2];
      float4 j1 = ((const float4*)x1)[j*16 + kc*2 + 1];
      const float* xp = &xi_s[p][kc*8];
      outv[0]=f2bf(j0.x-xp[0]); outv[1]=f2bf(j0.y-xp[1]); outv[2]=f2bf(j0.z-xp[2]); outv[3]=f2bf(j0.w-xp[3]);
      outv[4]=f2bf(j1.x-xp[4]); outv[5]=f2bf(j1.y-xp[5]); outv[6]=f2bf(j1.z-xp[6]); outv[7]=f2bf(j1.w-xp[7]);
    }
    *(short8*)&Elds[p*2304 + rr*72 + kc*8] = outv;
  }
  __syncthreads();
  // compute: wave w owns cols [w*32, w*32+32); B-frags from global wtg (bottom half)
  int w = t >> 6, l = t & 63;
  int colA = w*32 + (l & 15);
  int colB = colA + 16;
  short8 bfr[2][2];
  #pragma unroll
  for (int n = 0; n < 2; ++n)
    #pragma unroll
    for (int kb = 0; kb < 2; ++kb) {
      int col = w*32 + n*16 + (l & 15);
      int k0 = 64 + kb*32 + (l >> 4)*8;
      bfr[n][kb] = *(const short8*)&wtg[col*128 + k0];
    }
  float sT0=0.f, qT0=0.f, sT1=0.f, qT1=0.f;
  #pragma unroll
  for (int p = 0; p < 4; ++p) {
    int i = blockIdx.x*4 + p;
    float vA = vi[p][colA], vB = vi[p][colB];
    float mx0=-INFINITY, mn0=INFINITY, s0=0.f, q0=0.f;
    float mx1=-INFINITY, mn1=INFINITY, s1=0.f, q1=0.f;
    #pragma unroll
    for (int m = 0; m < 2; ++m) {
      short8 af[2];
      #pragma unroll
      for (int kb = 0; kb < 2; ++kb) {
        int row = m*16 + (l & 15);
        int k0 = kb*32 + (l >> 4)*8;
        af[kb] = *(short8*)&Elds[p*2304 + row*72 + k0];
      }
      f32x4 acc0 = {vA, vA, vA, vA};
      f32x4 acc1 = {vB, vB, vB, vB};
      #pragma unroll
      for (int kb = 0; kb < 2; ++kb) {
        acc0 = __builtin_amdgcn_mfma_f32_16x16x32_bf16(af[kb], bfr[0][kb], acc0, 0, 0, 0);
        acc1 = __builtin_amdgcn_mfma_f32_16x16x32_bf16(af[kb], bfr[1][kb], acc1, 0, 0, 0);
      }
      int rbase = (l >> 4)*4 + m*16;
      #pragma unroll
      for (int reg = 0; reg < 4; ++reg) {
        bool valid = (rbase + reg) < KNB;
        float h0 = fmaxf(acc0[reg], 0.f);
        float h1 = fmaxf(acc1[reg], 0.f);
        if (valid) {
          mx0 = fmaxf(mx0, h0); mn0 = fminf(mn0, h0); s0 += h0; q0 += h0*h0;
          mx1 = fmaxf(mx1, h1); mn1 = fminf(mn1, h1); s1 += h1; q1 += h1*h1;
        }
      }
    }
    // butterfly over the 4 lane-groups sharing each col
    #pragma unroll
    for (int dlt = 16; dlt <= 32; dlt <<= 1) {
      mx0 = fmaxf(mx0, __shfl_xor(mx0, dlt)); mn0 = fminf(mn0, __shfl_xor(mn0, dlt));
      s0 += __shfl_xor(s0, dlt);              q0 += __shfl_xor(q0, dlt);
      mx1 = fmaxf(mx1, __shfl_xor(mx1, dlt)); mn1 = fminf(mn1, __shfl_xor(mn1, dlt));
      s1 += __shfl_xor(s1, dlt);              q1 += __shfl_xor(q1, dlt);
    }
    if (l < 16) {
      xmx[i*128 + colA] = mx0; xmx[i*128 + colB] = mx1;
      xmn[i*128 + colA] = mn0; xmn[i*128 + colB] = mn1;
    }
    sT0 += s0; qT0 += q0; sT1 += s1; qT1 += q1;
  }
  if (l < 16) {
    atomicAdd(&sums[colA], sT0);       atomicAdd(&sums[colB], sT1);
    atomicAdd(&sums[128 + colA], qT0); atomicAdd(&sums[128 + colB], qT1);
  }
}

// ---------------- bn2 apply ----------------
__global__ __launch_bounds__(256) void k_bn2apply(const float* __restrict__ sums, const float* __restrict__ g,
                                                  const float* __restrict__ be, const float* __restrict__ xmx,
                                                  const float* __restrict__ xmn, float* __restrict__ x2) {
  __shared__ float sc_s[128], sh_s[128];
  int t = threadIdx.x;
  if (t < 128) {
    float m = sums[t] * (1.f/327680.f);
    float v = sums[128+t] * (1.f/327680.f) - m*m;
    float sc = g[t] / sqrtf(v + 1e-5f);
    sc_s[t] = sc; sh_s[t] = be[t] - m*sc;
  }
  __syncthreads();
  int c = t & 127;
  int i = blockIdx.x*2 + (t>>7);
  float sc = sc_s[c], sh = sh_s[c];
  float val = (sc >= 0.f) ? xmx[i*128+c] : xmn[i*128+c];
  x2[i*128+c] = sc*val + sh;
}

// ---------------- gemmF: relu([x1|x2] @ wf + bf); channel sums + per-batch max/min only ----------------
__global__ __launch_bounds__(256) void k_gemmF(const float* __restrict__ x1, const float* __restrict__ x2,
                                               const float* __restrict__ wf, const float* __restrict__ bf,
                                               float* __restrict__ sumsF, unsigned* __restrict__ hpmx,
                                               unsigned* __restrict__ hpmn) {
  __shared__ float A_s[64*193];
  __shared__ __align__(16) float B_s[192*64];
  __shared__ float red[1024];
  int t = threadIdx.x;
  int rt = blockIdx.x >> 2;
  int ct = blockIdx.x & 3;
  for (int v = t; v < 64*48; v += 256) {
    int r = v / 48, gg = v - r*48;
    int row = rt*64 + r;
    float4 e = (gg < 16) ? ((const float4*)x1)[row*16 + gg]
                         : ((const float4*)x2)[row*32 + (gg-16)];
    float* p = &A_s[r*193 + gg*4];
    p[0]=e.x; p[1]=e.y; p[2]=e.z; p[3]=e.w;
  }
  for (int v = t; v < 192*16; v += 256) {
    int d = v >> 4, c4 = v & 15;
    *(float4*)&B_s[d*64 + c4*4] = ((const float4*)wf)[d*64 + ct*16 + c4];
  }
  __syncthreads();
  int rg = t & 15, cg = t >> 4;
  float acc[4][4];
  #pragma unroll
  for (int a=0;a<4;a++) { acc[a][0]=0.f; acc[a][1]=0.f; acc[a][2]=0.f; acc[a][3]=0.f; }
  for (int d = 0; d < 192; ++d) {
    float a0 = A_s[(rg*4+0)*193 + d];
    float a1 = A_s[(rg*4+1)*193 + d];
    float a2 = A_s[(rg*4+2)*193 + d];
    float a3 = A_s[(rg*4+3)*193 + d];
    float b0 = B_s[d*64 + cg];
    float b1 = B_s[d*64 + cg + 16];
    float b2 = B_s[d*64 + cg + 32];
    float b3 = B_s[d*64 + cg + 48];
    acc[0][0]+=a0*b0; acc[0][1]+=a0*b1; acc[0][2]+=a0*b2; acc[0][3]+=a0*b3;
    acc[1][0]+=a1*b0; acc[1][1]+=a1*b1; acc[1][2]+=a1*b2; acc[1][3]+=a1*b3;
    acc[2][0]+=a2*b0; acc[2][1]+=a2*b1; acc[2][2]+=a2*b2; acc[2][3]+=a2*b3;
    acc[3][0]+=a3*b0; acc[3][1]+=a3*b1; acc[3][2]+=a3*b2; acc[3][3]+=a3*b3;
  }
  float hv[4][4];
  #pragma unroll
  for (int ss=0; ss<4; ++ss) {
    float bb = bf[ct*64 + cg + ss*16];
    #pragma unroll
    for (int rr=0; rr<4; ++rr) hv[rr][ss] = fmaxf(acc[rr][ss] + bb, 0.f);
  }
  int b = rt >> 5;
  #pragma unroll
  for (int ss=0; ss<4; ++ss) red[rg*64 + cg + ss*16] = hv[0][ss]+hv[1][ss]+hv[2][ss]+hv[3][ss];
  __syncthreads();
  if (t < 64) {
    float v = 0.f;
    #pragma unroll
    for (int r=0;r<16;r++) v += red[r*64 + t];
    atomicAdd(&sumsF[ct*64 + t], v);
  }
  __syncthreads();
  #pragma unroll
  for (int ss=0; ss<4; ++ss) red[rg*64 + cg + ss*16] =
      hv[0][ss]*hv[0][ss]+hv[1][ss]*hv[1][ss]+hv[2][ss]*hv[2][ss]+hv[3][ss]*hv[3][ss];
  __syncthreads();
  if (t < 64) {
    float v = 0.f;
    #pragma unroll
    for (int r=0;r<16;r++) v += red[r*64 + t];
    atomicAdd(&sumsF[256 + ct*64 + t], v);
  }
  __syncthreads();
  #pragma unroll
  for (int ss=0; ss<4; ++ss) red[rg*64 + cg + ss*16] =
      fmaxf(fmaxf(hv[0][ss],hv[1][ss]), fmaxf(hv[2][ss],hv[3][ss]));
  __syncthreads();
  if (t < 64) {
    float v = -INFINITY;
    #pragma unroll
    for (int r=0;r<16;r++) v = fmaxf(v, red[r*64 + t]);
    atomicMax(&hpmx[b*256 + ct*64 + t], __float_as_uint(v));
  }
  __syncthreads();
  #pragma unroll
  for (int ss=0; ss<4; ++ss) red[rg*64 + cg + ss*16] =
      fminf(fminf(hv[0][ss],hv[1][ss]), fminf(hv[2][ss],hv[3][ss]));
  __syncthreads();
  if (t < 64) {
    float v = INFINITY;
    #pragma unroll
    for (int r=0;r<16;r++) v = fminf(v, red[r*64 + t]);
    atomicMin(&hpmn[b*256 + ct*64 + t], __float_as_uint(v));
  }
}

// ---------------- head ----------------
__global__ __launch_bounds__(256) void k_head(const float* __restrict__ sumsF, const float* __restrict__ gf,
                                              const float* __restrict__ bef,
                                              const unsigned* __restrict__ hpmx, const unsigned* __restrict__ hpmn,
                                              const float* __restrict__ wo1, const float* __restrict__ bo1,
                                              const float* __restrict__ go1, const float* __restrict__ beo1,
                                              const float* __restrict__ wo2, const float* __restrict__ bo2,
                                              const float* __restrict__ go2, const float* __restrict__ beo2,
                                              const float* __restrict__ wo3, const float* __restrict__ bo3,
                                              float* __restrict__ out) {
  __shared__ float hp[8][256];
  __shared__ float u1[8][128];
  __shared__ float u2[8][64];
  __shared__ float lg[8][16];
  int t = threadIdx.x;
  {
    float m = sumsF[t] * (1.f/16384.f);
    float v = sumsF[256+t] * (1.f/16384.f) - m*m;
    float sc = gf[t] / sqrtf(v + 1e-5f);
    float sh = bef[t] - m*sc;
    for (int b = 0; b < 8; ++b) {
      unsigned bits = (sc >= 0.f) ? hpmx[b*256+t] : hpmn[b*256+t];
      hp[b][t] = sc*__uint_as_float(bits) + sh;
    }
  }
  __syncthreads();
  for (int p = t; p < 1024; p += 256) {
    int b = p >> 7, c = p & 127;
    float z = bo1[c];
    for (int d = 0; d < 256; ++d) z += hp[b][d]*wo1[d*128+c];
    u1[b][c] = fmaxf(z, 0.f);
  }
  __syncthreads();
  if (t < 128) {
    float m = 0.f;
    for (int b=0;b<8;b++) m += u1[b][t];
    m *= 0.125f;
    float v = 0.f;
    for (int b=0;b<8;b++) { float dd = u1[b][t]-m; v += dd*dd; }
    v *= 0.125f;
    float sc = go1[t]/sqrtf(v+1e-5f), sh = beo1[t]-m*sc;
    for (int b=0;b<8;b++) u1[b][t] = sc*u1[b][t]+sh;
  }
  __syncthreads();
  for (int p = t; p < 512; p += 256) {
    int b = p >> 6, c = p & 63;
    float z = bo2[c];
    for (int d = 0; d < 128; ++d) z += u1[b][d]*wo2[d*64+c];
    u2[b][c] = fmaxf(z, 0.f);
  }
  __syncthreads();
  if (t < 64) {
    float m = 0.f;
    for (int b=0;b<8;b++) m += u2[b][t];
    m *= 0.125f;
    float v = 0.f;
    for (int b=0;b<8;b++) { float dd = u2[b][t]-m; v += dd*dd; }
    v *= 0.125f;
    float sc = go2[t]/sqrtf(v+1e-5f), sh = beo2[t]-m*sc;
    for (int b=0;b<8;b++) u2[b][t] = sc*u2[b][t]+sh;
  }
  __syncthreads();
  if (t < 128) {
    int b = t >> 4, c = t & 15;
    float z = bo3[c];
    for (int d = 0; d < 64; ++d) z += u2[b][d]*wo3[d*16+c];
    lg[b][c] = z;
  }
  __syncthreads();
  if (t < 8) {
    float m = -INFINITY;
    for (int j=0;j<16;j++) m = fmaxf(m, lg[t][j]);
    float s = 0.f;
    for (int j=0;j<16;j++) s += expf(lg[t][j]-m);
    float ls = logf(s);
    for (int j=0;j<16;j++) out[t*16+j] = (lg[t][j]-m) - ls;
  }
}

// ---------------- launch ----------------
extern "C" void kernel_launch(void* const* d_in, const int* in_sizes, int n_in,
                              void* d_out, int out_size, void* d_ws, size_t ws_size,
                              hipStream_t stream) {
  (void)in_sizes; (void)n_in; (void)out_size; (void)ws_size;
  const float* pos = (const float*)d_in[0];
  const float* x   = (const float*)d_in[1];
  const float* w1  = (const float*)d_in[3];
  const float* b1  = (const float*)d_in[4];
  const float* g1  = (const float*)d_in[5];
  const float* be1 = (const float*)d_in[6];
  const float* w2  = (const float*)d_in[7];
  const float* b2  = (const float*)d_in[8];
  const float* g2  = (const float*)d_in[9];
  const float* be2 = (const float*)d_in[10];
  const float* wf  = (const float*)d_in[11];
  const float* bf  = (const float*)d_in[12];
  const float* gf  = (const float*)d_in[13];
  const float* bef = (const float*)d_in[14];
  const float* wo1 = (const float*)d_in[15];
  const float* bo1 = (const float*)d_in[16];
  const float* go1 = (const float*)d_in[17];
  const float* beo1= (const float*)d_in[18];
  const float* wo2 = (const float*)d_in[19];
  const float* bo2 = (const float*)d_in[20];
  const float* go2 = (const float*)d_in[21];
  const float* beo2= (const float*)d_in[22];
  const float* wo3 = (const float*)d_in[23];
  const float* bo3 = (const float*)d_in[24];

  char* ws = (char*)d_ws;
  float4*   f0    = (float4*)  (ws + OFF_F0);
  float*    ssq0  = (float*)   (ws + OFF_SSQ0);
  int*      idx1  = (int*)     (ws + OFF_IDX1);
  float*    xmx1  = (float*)   (ws + OFF_XMX1);
  float*    xmn1  = (float*)   (ws + OFF_XMN1);
  float*    sum1  = (float*)   (ws + OFF_SUM1);
  float*    x1    = (float*)   (ws + OFF_X1);
  float*    ssq1  = (float*)   (ws + OFF_SSQ1);
  int*      idx2  = (int*)     (ws + OFF_IDX2);
  float*    xmx2  = (float*)   (ws + OFF_XMX2);
  float*    xmn2  = (float*)   (ws + OFF_XMN2);
  float*    sum2  = (float*)   (ws + OFF_SUM2);
  float*    x2    = (float*)   (ws + OFF_X2);
  float*    sumF  = (float*)   (ws + OFF_SUMF);
  unsigned* hpmx  = (unsigned*)(ws + OFF_HPMX);
  unsigned* hpmn  = (unsigned*)(ws + OFF_HPMN);
  short*    wtg   = (short*)   (ws + OFF_X2);    // aliases x2 head (x2 dead until bn2apply)

  k_init    <<<64,   256, 0, stream>>>(pos, x, w2, f0, ssq0, wtg, sum1, sum2, sumF, hpmx, hpmn);
  k_knn1    <<<2048, 256, 0, stream>>>(f0, ssq0, idx1);
  k_mlp1    <<<512,  256, 0, stream>>>(f0, idx1, w1, b1, xmx1, xmn1, sum1);
  k_bn1apply<<<4096, 256, 0, stream>>>(sum1, g1, be1, xmx1, xmn1, x1);
  k_ssq1    <<<64,   256, 0, stream>>>(x1, ssq1);
  k_knn2    <<<512,  256, 0, stream>>>(x1, ssq1, idx2);
  k_mlp2    <<<4096, 256, 0, stream>>>(x1, idx2, wtg, w2, b2, xmx2, xmn2, sum2);
  k_bn2apply<<<8192, 256, 0, stream>>>(sum2, g2, be2, xmx2, xmn2, x2);
  k_gemmF   <<<1024, 256, 0, stream>>>(x1, x2, wf, bf, sumF, hpmx, hpmn);
  k_head    <<<1,    256, 0, stream>>>(sumF, gf, bef, hpmx, hpmn,
                                       wo1, bo1, go1, beo1, wo2, bo2, go2, beo2, wo3, bo3,
                                       (float*)d_out);
}

// Round 12
// 792.445 us; speedup vs baseline: 1.0538x; 1.0538x over previous
//
#include <hip/hip_runtime.h>
#include <math.h>

#define NPTS 16384
#define KNB 20
#define SCAP 512
#define SCAP2 448

typedef __attribute__((ext_vector_type(8))) short short8;
typedef __attribute__((ext_vector_type(4))) float f32x4;

// ---------------- workspace layout (bytes, all naturally 256-aligned) ----------------
static const size_t OFF_F0   = 0;                                   // N x float4
static const size_t OFF_SSQ0 = OFF_F0   + (size_t)NPTS*4*4;         // N f32
static const size_t OFF_IDX1 = OFF_SSQ0 + (size_t)NPTS*4;           // N*20 i32
static const size_t OFF_XMX1 = OFF_IDX1 + (size_t)NPTS*KNB*4;       // N*64 f32
static const size_t OFF_XMN1 = OFF_XMX1 + (size_t)NPTS*64*4;        // N*64 f32
static const size_t OFF_SUM1 = OFF_XMN1 + (size_t)NPTS*64*4;        // 128 f32 (sum,sumsq)
static const size_t OFF_X1   = OFF_SUM1 + 512;                      // N*64 f32
static const size_t OFF_SSQ1 = OFF_X1   + (size_t)NPTS*64*4;        // N f32
static const size_t OFF_IDX2 = OFF_SSQ1 + (size_t)NPTS*4;           // N*20 i32 (global idx)
static const size_t OFF_XMX2 = OFF_IDX2 + (size_t)NPTS*KNB*4;       // N*128 f32
static const size_t OFF_XMN2 = OFF_XMX2 + (size_t)NPTS*128*4;       // N*128 f32
static const size_t OFF_SUM2 = OFF_XMN2 + (size_t)NPTS*128*4;       // 256 f32
static const size_t OFF_X2   = OFF_SUM2 + 1024;                     // N*128 f32
static const size_t OFF_SUMF = OFF_X2   + (size_t)NPTS*128*4;       // 512 f32
static const size_t OFF_HPMX = OFF_SUMF + 2048;                     // 8*256 u32 (float bits)
static const size_t OFF_HPMN = OFF_HPMX + 8*256*4;                  // 8*256 u32
// WT_g (bf16 W^T for mlp2, 32 KB) ALIASES x2 head: x2 is dead until bn2apply,
// which runs AFTER mlp2 has consumed wtg. k_init writes it first thing.

// ---------------- helpers ----------------
__device__ __forceinline__ float dot4f(float4 a, float4 b) {
  return a.x*b.x + a.y*b.y + a.z*b.z + a.w*b.w;
}

__device__ __forceinline__ float dot64v(const float* a, const float4* b4) {
  float s = 0.f;
  #pragma unroll
  for (int d4 = 0; d4 < 16; ++d4) {
    float4 b = b4[d4];
    s += a[4*d4+0]*b.x + a[4*d4+1]*b.y + a[4*d4+2]*b.z + a[4*d4+3]*b.w;
  }
  return s;
}

// f32 -> bf16 (RNE)
__device__ __forceinline__ short f2bf(float x) {
  union { float f; unsigned u; } v; v.f = x;
  unsigned r = (v.u + 0x7FFFu + ((v.u >> 16) & 1u)) >> 16;
  return (short)r;
}

// ---------------- branch-free sorting-network top-k machinery (with indices) ----------------
__device__ __forceinline__ void ce(float& a, int& ai, float& b, int& bi) {
  bool sw = b < a;
  float d0 = sw ? b : a;  float d1 = sw ? a : b;
  int   j0 = sw ? bi : ai; int  j1 = sw ? ai : bi;
  a = d0; ai = j0; b = d1; bi = j1;
}

__device__ __forceinline__ void sort16(float (&d)[16], int (&ix)[16]) {
  #pragma unroll
  for (int k = 2; k <= 16; k <<= 1) {
    #pragma unroll
    for (int j = k >> 1; j > 0; j >>= 1) {
      #pragma unroll
      for (int i = 0; i < 16; ++i) {
        int l = i ^ j;
        if (l > i) {
          if ((i & k) == 0) ce(d[i], ix[i], d[l], ix[l]);
          else              ce(d[l], ix[l], d[i], ix[i]);
        }
      }
    }
  }
}

__device__ __forceinline__ void bimerge32(float (&rd)[32], int (&ri)[32]) {
  #pragma unroll
  for (int j = 16; j > 0; j >>= 1) {
    #pragma unroll
    for (int i = 0; i < 32; ++i) {
      int l = i ^ j;
      if (l > i) ce(rd[i], ri[i], rd[l], ri[l]);
    }
  }
}

__device__ __forceinline__ void merge16(float (&rd)[32], int (&ri)[32],
                                        float (&bd)[16], int (&bi)[16]) {
  #pragma unroll
  for (int k = 0; k < 16; ++k) {
    bool sw = bd[15-k] < rd[16+k];
    rd[16+k] = sw ? bd[15-k] : rd[16+k];
    ri[16+k] = sw ? bi[15-k] : ri[16+k];
  }
  bimerge32(rd, ri);
}

__device__ __forceinline__ void mergelane(float (&rd)[32], int (&ri)[32], int mask) {
  float pd[32]; int pi[32];
  #pragma unroll
  for (int s = 0; s < 32; ++s) { pd[s] = __shfl_xor(rd[s], mask); pi[s] = __shfl_xor(ri[s], mask); }
  #pragma unroll
  for (int k = 0; k < 32; ++k) {
    bool sw = pd[31-k] < rd[k];
    rd[k] = sw ? pd[31-k] : rd[k];
    ri[k] = sw ? pi[31-k] : ri[k];
  }
  bimerge32(rd, ri);
}

// ---------------- value-only versions (threshold computation, 2 ops/CE) ----------------
__device__ __forceinline__ void vce(float& a, float& b) {
  float lo = fminf(a, b);
  b = fmaxf(a, b);
  a = lo;
}

__device__ __forceinline__ void vsort16(float (&d)[16]) {
  #pragma unroll
  for (int k = 2; k <= 16; k <<= 1) {
    #pragma unroll
    for (int j = k >> 1; j > 0; j >>= 1) {
      #pragma unroll
      for (int i = 0; i < 16; ++i) {
        int l = i ^ j;
        if (l > i) {
          if ((i & k) == 0) vce(d[i], d[l]);
          else              vce(d[l], d[i]);
        }
      }
    }
  }
}

__device__ __forceinline__ void vbimerge32(float (&rd)[32]) {
  #pragma unroll
  for (int j = 16; j > 0; j >>= 1) {
    #pragma unroll
    for (int i = 0; i < 32; ++i) {
      int l = i ^ j;
      if (l > i) vce(rd[i], rd[l]);
    }
  }
}

__device__ __forceinline__ void vmerge16(float (&rd)[32], float (&bd)[16]) {
  #pragma unroll
  for (int k = 0; k < 16; ++k) rd[16+k] = fminf(rd[16+k], bd[15-k]);
  vbimerge32(rd);
}

__device__ __forceinline__ void vmergelane(float (&rd)[32], int mask) {
  float pd[32];
  #pragma unroll
  for (int s = 0; s < 32; ++s) pd[s] = __shfl_xor(rd[s], mask);
  #pragma unroll
  for (int k = 0; k < 32; ++k) rd[k] = fminf(rd[k], pd[31-k]);
  vbimerge32(rd);
}

// ---------------- init + f0 + wprep fused (grid 64; accumulators reset EVERY launch) ----------------
__global__ __launch_bounds__(256) void k_init(const float* __restrict__ pos, const float* __restrict__ x,
                                              const float* __restrict__ w2,
                                              float4* __restrict__ f0, float* __restrict__ ssq,
                                              short* __restrict__ wtg,
                                              float* sum1, float* sum2, float* sumF,
                                              unsigned* hpmx, unsigned* hpmn) {
  int gt = blockIdx.x*256 + threadIdx.x;   // 0..16383
  float4 f;
  f.x = pos[3*gt+0]; f.y = pos[3*gt+1]; f.z = pos[3*gt+2]; f.w = x[gt];
  f0[gt] = f;
  ssq[gt] = dot4f(f, f);
  { int c = gt >> 7, k = gt & 127; wtg[c*128 + k] = f2bf(w2[k*128 + c]); }
  if (gt < 128) sum1[gt] = 0.f;
  if (gt < 256) sum2[gt] = 0.f;
  if (gt < 512) sumF[gt] = 0.f;
  if (gt < 2048) { hpmx[gt] = 0u; hpmn[gt] = 0x7f800000u; }   // relu>=0 -> uint order == float order
}

// ---------------- knn1 v4: global-direct two-phase exact; survivors store INDEX ONLY ----------------
__global__ __launch_bounds__(256) void k_knn1(const float4* __restrict__ f0, const float* __restrict__ ssq,
                                              int* __restrict__ idx1) {
  __shared__ int survj[8][SCAP];
  __shared__ int scnt[8];
  __shared__ float rowT[8];
  int t = threadIdx.x;
  int r = t >> 5;
  int lane = t & 31;
  int row = blockIdx.x*8 + r;
  if (t < 8) scnt[t] = 0;
  float4 fi = f0[row];
  float sqi = ssq[row];
  // ---- pass 1: value-only top-32 of sample [0,2048)
  {
    float rd[32];
    #pragma unroll
    for (int s = 0; s < 32; ++s) rd[s] = INFINITY;
    #pragma unroll
    for (int b = 0; b < 4; ++b) {
      float bd[16];
      #pragma unroll
      for (int u = 0; u < 16; ++u) {
        int j = b*512 + u*32 + lane;
        float4 c = f0[j];
        bd[u] = (sqi - 2.f*dot4f(fi, c)) + ssq[j];
      }
      vsort16(bd);
      vmerge16(rd, bd);
    }
    vmergelane(rd, 1); vmergelane(rd, 2); vmergelane(rd, 4);
    vmergelane(rd, 8); vmergelane(rd, 16);
    if (lane == 0) rowT[r] = rd[19];
  }
  __syncthreads();
  // ---- pass 2: candidate-major filter over all 16384
  {
    float4 fr[8]; float sr[8], Tr[8];
    #pragma unroll
    for (int q = 0; q < 8; ++q) {
      fr[q] = f0[blockIdx.x*8 + q];
      sr[q] = ssq[blockIdx.x*8 + q];
      Tr[q] = rowT[q];
    }
    #pragma unroll 4
    for (int k = 0; k < 64; ++k) {
      int j = k*256 + t;
      float4 c = f0[j];
      float cq = ssq[j];
      #pragma unroll
      for (int q = 0; q < 8; ++q) {
        float d = (sr[q] - 2.f*dot4f(fr[q], c)) + cq;
        if (d <= Tr[q]) {
          int slot = atomicAdd(&scnt[q], 1);
          if (slot < SCAP) survj[q][slot] = j;
        }
      }
    }
  }
  __syncthreads();
  int n = scnt[r] < SCAP ? scnt[r] : SCAP;
  // ---- pass 3: recompute d (bitwise-identical expr) + exact index top-20
  float rd[32]; int ri[32];
  #pragma unroll
  for (int s = 0; s < 32; ++s) { rd[s] = INFINITY; ri[s] = 0; }
  {
    float bd[16]; int bix[16];
    #pragma unroll
    for (int u = 0; u < 16; ++u) {
      int s = u*32 + lane;
      if (s < n) {
        int j = survj[r][s];
        float4 c = f0[j];
        bd[u] = (sqi - 2.f*dot4f(fi, c)) + ssq[j];
        bix[u] = j;
      } else { bd[u] = INFINITY; bix[u] = 0; }
    }
    sort16(bd, bix);
    merge16(rd, ri, bd, bix);
  }
  mergelane(rd, ri, 1); mergelane(rd, ri, 2); mergelane(rd, ri, 4);
  mergelane(rd, ri, 8); mergelane(rd, ri, 16);
  if (lane == 0) {
    int4* p = (int4*)&idx1[row*KNB];
    p[0] = make_int4(ri[0],ri[1],ri[2],ri[3]);
    p[1] = make_int4(ri[4],ri[5],ri[6],ri[7]);
    p[2] = make_int4(ri[8],ri[9],ri[10],ri[11]);
    p[3] = make_int4(ri[12],ri[13],ri[14],ri[15]);
    p[4] = make_int4(ri[16],ri[17],ri[18],ri[19]);
  }
}

// ---------------- mlp1: edge MLP 8->64, relu, per-point max/min (pre-BN), channel sums ----------------
__global__ __launch_bounds__(256) void k_mlp1(const float4* __restrict__ f0, const int* __restrict__ idx1,
                                              const float* __restrict__ w1, const float* __restrict__ b1,
                                              float* __restrict__ xmx, float* __restrict__ xmn,
                                              float* __restrict__ sums) {
  __shared__ float rs[256], rs2[256];
  int t = threadIdx.x;
  int c = t & 63;
  int w = t >> 6;
  float wc[8];
  #pragma unroll
  for (int d = 0; d < 8; ++d) wc[d] = w1[d*64 + c];
  float bc = b1[c];
  float s = 0.f, s2 = 0.f;
  for (int p = 0; p < 8; ++p) {
    int i = blockIdx.x*32 + p*4 + w;
    float4 fi = f0[i];
    float mx = -INFINITY, mn = INFINITY;
    #pragma unroll
    for (int k = 0; k < KNB; ++k) {
      int j = idx1[i*KNB + k];
      float4 fj = f0[j];
      float h = bc + fi.x*wc[0] + fi.y*wc[1] + fi.z*wc[2] + fi.w*wc[3]
                   + (fj.x-fi.x)*wc[4] + (fj.y-fi.y)*wc[5] + (fj.z-fi.z)*wc[6] + (fj.w-fi.w)*wc[7];
      h = fmaxf(h, 0.f);
      mx = fmaxf(mx, h); mn = fminf(mn, h);
      s += h; s2 += h*h;
    }
    xmx[i*64+c] = mx; xmn[i*64+c] = mn;
  }
  rs[t] = s; rs2[t] = s2;
  __syncthreads();
  if (t < 64) {
    atomicAdd(&sums[c],      rs[t]+rs[t+64]+rs[t+128]+rs[t+192]);
    atomicAdd(&sums[64+c],   rs2[t]+rs2[t+64]+rs2[t+128]+rs2[t+192]);
  }
}

// ---------------- bn1 apply: x1 = affine(max or min by scale sign) ----------------
__global__ __launch_bounds__(256) void k_bn1apply(const float* __restrict__ sums, const float* __restrict__ g,
                                                  const float* __restrict__ be, const float* __restrict__ xmx,
                                                  const float* __restrict__ xmn, float* __restrict__ x1) {
  __shared__ float sc_s[64], sh_s[64];
  int t = threadIdx.x;
  if (t < 64) {
    float m = sums[t] * (1.f/327680.f);
    float v = sums[64+t] * (1.f/327680.f) - m*m;
    float sc = g[t] / sqrtf(v + 1e-5f);
    sc_s[t] = sc; sh_s[t] = be[t] - m*sc;
  }
  __syncthreads();
  int c = t & 63;
  int i = blockIdx.x*4 + (t>>6);
  float sc = sc_s[c], sh = sh_s[c];
  float val = (sc >= 0.f) ? xmx[i*64+c] : xmn[i*64+c];
  x1[i*64+c] = sc*val + sh;
}

// ---------------- ssq1 (same dot64v ordering as knn2 pass-3 for exact self-distance) ----------------
__global__ __launch_bounds__(256) void k_ssq1(const float* __restrict__ x1, float* __restrict__ ssq1) {
  int i = blockIdx.x*256 + threadIdx.x;
  alignas(16) float f[64];
  #pragma unroll
  for (int d4 = 0; d4 < 16; ++d4) ((float4*)f)[d4] = ((const float4*)x1)[i*16 + d4];
  ssq1[i] = dot64v(f, (const float4*)f);
}

// ---------------- knn2 v3: MFMA-filtered exact 3-phase, 16 rows/block (latency fix) ----------------
// R11's v2 was latency-bound: 52.7 KB LDS -> 2 blocks/CU, VALUBusy 14%, Occ 11%.
// v3: 16 rows/block, grid 1024, LDS ~36 KB -> 4 blocks/CU (16 waves/CU).
// Same exact algorithm: fp32 sample-256 threshold; bf16-MFMA filter with margin
// M = 2^-7(sq_i+sq_j) >= 3.9x provable bf16 error -> survivors superset of true
// top-20; exact fp32 recompute + index network. Output identical.
__global__ __launch_bounds__(256) void k_knn2(const float* __restrict__ x1, const float* __restrict__ ssq1,
                                              int* __restrict__ idx2) {
  __shared__ __align__(16) short Abf[16*72];
  __shared__ __align__(16) short Bbf[128*72];
  __shared__ float sqA[16];
  __shared__ float sqB[128];
  __shared__ float rowT[16];
  __shared__ unsigned short surv[16][SCAP2];
  __shared__ int scnt[16];
  int t = threadIdx.x;
  int b = blockIdx.x >> 7;
  int rg = blockIdx.x & 127;
  int cbase = b*2048;
  int row0 = cbase + rg*16;
  if (t < 16) { scnt[t] = 0; sqA[t] = ssq1[row0 + t]; }
  if (t < 128) {
    int rr = t >> 3, kc = t & 7;
    float4 a0 = ((const float4*)x1)[(row0+rr)*16 + kc*2];
    float4 a1 = ((const float4*)x1)[(row0+rr)*16 + kc*2 + 1];
    short8 o;
    o[0]=f2bf(a0.x); o[1]=f2bf(a0.y); o[2]=f2bf(a0.z); o[3]=f2bf(a0.w);
    o[4]=f2bf(a1.x); o[5]=f2bf(a1.y); o[6]=f2bf(a1.z); o[7]=f2bf(a1.w);
    *(short8*)&Abf[rr*72 + kc*8] = o;
  }
  // ---- phase 1: exact fp32 threshold from sample [cbase, cbase+256); 16 rows x 16 lanes
  {
    int r = t >> 4, lane = t & 15;
    int row = row0 + r;
    alignas(16) float fi[64];
    #pragma unroll
    for (int d4 = 0; d4 < 16; ++d4) ((float4*)fi)[d4] = ((const float4*)x1)[row*16 + d4];
    float sqi = ssq1[row];
    float rd[32];
    #pragma unroll
    for (int s = 0; s < 32; ++s) rd[s] = INFINITY;
    float bd[16];
    #pragma unroll
    for (int u = 0; u < 16; ++u) {
      int j = cbase + u*16 + lane;
      bd[u] = (sqi - 2.f*dot64v(fi, (const float4*)&x1[j*64])) + ssq1[j];
    }
    vsort16(bd);
    vmerge16(rd, bd);
    vmergelane(rd, 1); vmergelane(rd, 2); vmergelane(rd, 4); vmergelane(rd, 8);
    if (lane == 0) rowT[r] = rd[19];
  }
  __syncthreads();
  // ---- phase 2: MFMA-filtered scan of all 2048 candidates
  int w = t >> 6, l = t & 63;
  short8 af[2];
  #pragma unroll
  for (int kb = 0; kb < 2; ++kb)
    af[kb] = *(short8*)&Abf[(l & 15)*72 + kb*32 + (l >> 4)*8];
  for (int ct = 0; ct < 16; ++ct) {
    int cb = ct*128;
    __syncthreads();                       // protect Bbf/sqB reuse
    #pragma unroll
    for (int cc = 0; cc < 4; ++cc) {
      int v = t + cc*256;
      int rr = v >> 3, kc = v & 7;
      int j = cbase + cb + rr;
      float4 a0 = ((const float4*)x1)[j*16 + kc*2];
      float4 a1 = ((const float4*)x1)[j*16 + kc*2 + 1];
      short8 o;
      o[0]=f2bf(a0.x); o[1]=f2bf(a0.y); o[2]=f2bf(a0.z); o[3]=f2bf(a0.w);
      o[4]=f2bf(a1.x); o[5]=f2bf(a1.y); o[6]=f2bf(a1.z); o[7]=f2bf(a1.w);
      *(short8*)&Bbf[rr*72 + kc*8] = o;
      if (kc == 0) sqB[rr] = ssq1[j];
    }
    __syncthreads();
    #pragma unroll
    for (int cs = 0; cs < 2; ++cs) {
      int c16 = (w*2 + cs)*16;
      short8 bfr[2];
      #pragma unroll
      for (int kb = 0; kb < 2; ++kb)
        bfr[kb] = *(short8*)&Bbf[(c16 + (l & 15))*72 + kb*32 + (l >> 4)*8];
      int jcol = c16 + (l & 15);
      float sb = sqB[jcol];
      f32x4 acc = {0.f, 0.f, 0.f, 0.f};
      acc = __builtin_amdgcn_mfma_f32_16x16x32_bf16(af[0], bfr[0], acc, 0, 0, 0);
      acc = __builtin_amdgcn_mfma_f32_16x16x32_bf16(af[1], bfr[1], acc, 0, 0, 0);
      #pragma unroll
      for (int reg = 0; reg < 4; ++reg) {
        int il = (l >> 4)*4 + reg;
        float sa = sqA[il];
        float dh = (sa - 2.f*acc[reg]) + sb;
        float M = 0.0078125f*(sa + sb);
        if (dh <= rowT[il] + M) {
          int slot = atomicAdd(&scnt[il], 1);
          if (slot < SCAP2) surv[il][slot] = (unsigned short)(cb + jcol);
        }
      }
    }
  }
  __syncthreads();
  // ---- phase 3: exact fp32 recompute + index top-20; 16 rows x 16 lanes
  {
    int r = t >> 4, lane = t & 15;
    int row = row0 + r;
    int n = scnt[r] < SCAP2 ? scnt[r] : SCAP2;
    alignas(16) float fi[64];
    #pragma unroll
    for (int d4 = 0; d4 < 16; ++d4) ((float4*)fi)[d4] = ((const float4*)x1)[row*16 + d4];
    float sqi = ssq1[row];
    float rd[32]; int ri[32];
    #pragma unroll
    for (int s = 0; s < 32; ++s) { rd[s] = INFINITY; ri[s] = 0; }
    #pragma unroll
    for (int g = 0; g < 2; ++g) {
      float bd[16]; int bix[16];
      #pragma unroll
      for (int u = 0; u < 16; ++u) {
        int s = (g*16 + u)*16 + lane;
        if (s < n) {
          int j = cbase + (int)surv[r][s];
          bd[u] = (sqi - 2.f*dot64v(fi, (const float4*)&x1[j*64])) + ssq1[j];
          bix[u] = j;
        } else { bd[u] = INFINITY; bix[u] = 0; }
      }
      sort16(bd, bix);
      merge16(rd, ri, bd, bix);
    }
    mergelane(rd, ri, 1); mergelane(rd, ri, 2); mergelane(rd, ri, 4); mergelane(rd, ri, 8);
    if (lane == 0) {
      int4* p = (int4*)&idx2[row*KNB];
      p[0] = make_int4(ri[0],ri[1],ri[2],ri[3]);
      p[1] = make_int4(ri[4],ri[5],ri[6],ri[7]);
      p[2] = make_int4(ri[8],ri[9],ri[10],ri[11]);
      p[3] = make_int4(ri[12],ri[13],ri[14],ri[15]);
      p[4] = make_int4(ri[16],ri[17],ri[18],ri[19]);
    }
  }
}

// ---------------- mlp2: edge MLP 128->128, shared-xi decomposition ----------------
__global__ __launch_bounds__(256) void k_mlp2(const float* __restrict__ x1, const int* __restrict__ idx2,
                                              const short* __restrict__ wtg, const float* __restrict__ w2,
                                              const float* __restrict__ b2,
                                              float* __restrict__ xmx, float* __restrict__ xmn,
                                              float* __restrict__ sums) {
  __shared__ __align__(16) short Elds[4*32*72];   // diffs only: [p][row][k<64], pitch 72
  __shared__ float xi_s[4][64];
  __shared__ float vi[4][128];
  __shared__ int js[4][KNB];
  int t = threadIdx.x;
  if (t < 4*KNB) js[t/KNB][t%KNB] = idx2[blockIdx.x*4*KNB + t];
  {
    int p = t >> 6, k = t & 63;
    xi_s[p][k] = x1[(blockIdx.x*4 + p)*64 + k];
  }
  __syncthreads();
  // vi[p][c] = b2[c] + sum_{k<64} xi[k]*w2[k][c]  (fp32 exact top-half + bias)
  #pragma unroll
  for (int v2 = 0; v2 < 2; ++v2) {
    int v = t + v2*256;
    int p = v >> 7, c = v & 127;
    float a = b2[c];
    #pragma unroll 8
    for (int k = 0; k < 64; ++k) a += xi_s[p][k] * w2[k*128 + c];
    vi[p][c] = a;
  }
  // stage E diffs (bf16): 4 pts x 32 rows x 8 chunks of 8
  #pragma unroll
  for (int cc = 0; cc < 4; ++cc) {
    int v = t + cc*256;
    int p  = v >> 8;
    int rr = (v >> 3) & 31;
    int kc = v & 7;
    short8 outv = {0,0,0,0,0,0,0,0};
    if (rr < KNB) {
      int j = js[p][rr];
      float4 j0 = ((const float4*)x1)[j*16 + kc*2];
      float4 j1 = ((const float4*)x1)[j*16 + kc*2 + 1];
      const float* xp = &xi_s[p][kc*8];
      outv[0]=f2bf(j0.x-xp[0]); outv[1]=f2bf(j0.y-xp[1]); outv[2]=f2bf(j0.z-xp[2]); outv[3]=f2bf(j0.w-xp[3]);
      outv[4]=f2bf(j1.x-xp[4]); outv[5]=f2bf(j1.y-xp[5]); outv[6]=f2bf(j1.z-xp[6]); outv[7]=f2bf(j1.w-xp[7]);
    }
    *(short8*)&Elds[p*2304 + rr*72 + kc*8] = outv;
  }
  __syncthreads();
  // compute: wave w owns cols [w*32, w*32+32); B-frags from global wtg (bottom half)
  int w = t >> 6, l = t & 63;
  int colA = w*32 + (l & 15);
  int colB = colA + 16;
  short8 bfr[2][2];
  #pragma unroll
  for (int n = 0; n < 2; ++n)
    #pragma unroll
    for (int kb = 0; kb < 2; ++kb) {
      int col = w*32 + n*16 + (l & 15);
      int k0 = 64 + kb*32 + (l >> 4)*8;
      bfr[n][kb] = *(const short8*)&wtg[col*128 + k0];
    }
  float sT0=0.f, qT0=0.f, sT1=0.f, qT1=0.f;
  #pragma unroll
  for (int p = 0; p < 4; ++p) {
    int i = blockIdx.x*4 + p;
    float vA = vi[p][colA], vB = vi[p][colB];
    float mx0=-INFINITY, mn0=INFINITY, s0=0.f, q0=0.f;
    float mx1=-INFINITY, mn1=INFINITY, s1=0.f, q1=0.f;
    #pragma unroll
    for (int m = 0; m < 2; ++m) {
      short8 af[2];
      #pragma unroll
      for (int kb = 0; kb < 2; ++kb) {
        int row = m*16 + (l & 15);
        int k0 = kb*32 + (l >> 4)*8;
        af[kb] = *(short8*)&Elds[p*2304 + row*72 + k0];
      }
      f32x4 acc0 = {vA, vA, vA, vA};
      f32x4 acc1 = {vB, vB, vB, vB};
      #pragma unroll
      for (int kb = 0; kb < 2; ++kb) {
        acc0 = __builtin_amdgcn_mfma_f32_16x16x32_bf16(af[kb], bfr[0][kb], acc0, 0, 0, 0);
        acc1 = __builtin_amdgcn_mfma_f32_16x16x32_bf16(af[kb], bfr[1][kb], acc1, 0, 0, 0);
      }
      int rbase = (l >> 4)*4 + m*16;
      #pragma unroll
      for (int reg = 0; reg < 4; ++reg) {
        bool valid = (rbase + reg) < KNB;
        float h0 = fmaxf(acc0[reg], 0.f);
        float h1 = fmaxf(acc1[reg], 0.f);
        if (valid) {
          mx0 = fmaxf(mx0, h0); mn0 = fminf(mn0, h0); s0 += h0; q0 += h0*h0;
          mx1 = fmaxf(mx1, h1); mn1 = fminf(mn1, h1); s1 += h1; q1 += h1*h1;
        }
      }
    }
    // butterfly over the 4 lane-groups sharing each col
    #pragma unroll
    for (int dlt = 16; dlt <= 32; dlt <<= 1) {
      mx0 = fmaxf(mx0, __shfl_xor(mx0, dlt)); mn0 = fminf(mn0, __shfl_xor(mn0, dlt));
      s0 += __shfl_xor(s0, dlt);              q0 += __shfl_xor(q0, dlt);
      mx1 = fmaxf(mx1, __shfl_xor(mx1, dlt)); mn1 = fminf(mn1, __shfl_xor(mn1, dlt));
      s1 += __shfl_xor(s1, dlt);              q1 += __shfl_xor(q1, dlt);
    }
    if (l < 16) {
      xmx[i*128 + colA] = mx0; xmx[i*128 + colB] = mx1;
      xmn[i*128 + colA] = mn0; xmn[i*128 + colB] = mn1;
    }
    sT0 += s0; qT0 += q0; sT1 += s1; qT1 += q1;
  }
  if (l < 16) {
    atomicAdd(&sums[colA], sT0);       atomicAdd(&sums[colB], sT1);
    atomicAdd(&sums[128 + colA], qT0); atomicAdd(&sums[128 + colB], qT1);
  }
}

// ---------------- bn2 apply ----------------
__global__ __launch_bounds__(256) void k_bn2apply(const float* __restrict__ sums, const float* __restrict__ g,
                                                  const float* __restrict__ be, const float* __restrict__ xmx,
                                                  const float* __restrict__ xmn, float* __restrict__ x2) {
  __shared__ float sc_s[128], sh_s[128];
  int t = threadIdx.x;
  if (t < 128) {
    float m = sums[t] * (1.f/327680.f);
    float v = sums[128+t] * (1.f/327680.f) - m*m;
    float sc = g[t] / sqrtf(v + 1e-5f);
    sc_s[t] = sc; sh_s[t] = be[t] - m*sc;
  }
  __syncthreads();
  int c = t & 127;
  int i = blockIdx.x*2 + (t>>7);
  float sc = sc_s[c], sh = sh_s[c];
  float val = (sc >= 0.f) ? xmx[i*128+c] : xmn[i*128+c];
  x2[i*128+c] = sc*val + sh;
}

// ---------------- gemmF: relu([x1|x2] @ wf + bf); channel sums + per-batch max/min only ----------------
__global__ __launch_bounds__(256) void k_gemmF(const float* __restrict__ x1, const float* __restrict__ x2,
                                               const float* __restrict__ wf, const float* __restrict__ bf,
                                               float* __restrict__ sumsF, unsigned* __restrict__ hpmx,
                                               unsigned* __restrict__ hpmn) {
  __shared__ float A_s[64*193];
  __shared__ __align__(16) float B_s[192*64];
  __shared__ float red[1024];
  int t = threadIdx.x;
  int rt = blockIdx.x >> 2;
  int ct = blockIdx.x & 3;
  for (int v = t; v < 64*48; v += 256) {
    int r = v / 48, gg = v - r*48;
    int row = rt*64 + r;
    float4 e = (gg < 16) ? ((const float4*)x1)[row*16 + gg]
                         : ((const float4*)x2)[row*32 + (gg-16)];
    float* p = &A_s[r*193 + gg*4];
    p[0]=e.x; p[1]=e.y; p[2]=e.z; p[3]=e.w;
  }
  for (int v = t; v < 192*16; v += 256) {
    int d = v >> 4, c4 = v & 15;
    *(float4*)&B_s[d*64 + c4*4] = ((const float4*)wf)[d*64 + ct*16 + c4];
  }
  __syncthreads();
  int rg = t & 15, cg = t >> 4;
  float acc[4][4];
  #pragma unroll
  for (int a=0;a<4;a++) { acc[a][0]=0.f; acc[a][1]=0.f; acc[a][2]=0.f; acc[a][3]=0.f; }
  for (int d = 0; d < 192; ++d) {
    float a0 = A_s[(rg*4+0)*193 + d];
    float a1 = A_s[(rg*4+1)*193 + d];
    float a2 = A_s[(rg*4+2)*193 + d];
    float a3 = A_s[(rg*4+3)*193 + d];
    float b0 = B_s[d*64 + cg];
    float b1 = B_s[d*64 + cg + 16];
    float b2 = B_s[d*64 + cg + 32];
    float b3 = B_s[d*64 + cg + 48];
    acc[0][0]+=a0*b0; acc[0][1]+=a0*b1; acc[0][2]+=a0*b2; acc[0][3]+=a0*b3;
    acc[1][0]+=a1*b0; acc[1][1]+=a1*b1; acc[1][2]+=a1*b2; acc[1][3]+=a1*b3;
    acc[2][0]+=a2*b0; acc[2][1]+=a2*b1; acc[2][2]+=a2*b2; acc[2][3]+=a2*b3;
    acc[3][0]+=a3*b0; acc[3][1]+=a3*b1; acc[3][2]+=a3*b2; acc[3][3]+=a3*b3;
  }
  float hv[4][4];
  #pragma unroll
  for (int ss=0; ss<4; ++ss) {
    float bb = bf[ct*64 + cg + ss*16];
    #pragma unroll
    for (int rr=0; rr<4; ++rr) hv[rr][ss] = fmaxf(acc[rr][ss] + bb, 0.f);
  }
  int b = rt >> 5;
  #pragma unroll
  for (int ss=0; ss<4; ++ss) red[rg*64 + cg + ss*16] = hv[0][ss]+hv[1][ss]+hv[2][ss]+hv[3][ss];
  __syncthreads();
  if (t < 64) {
    float v = 0.f;
    #pragma unroll
    for (int r=0;r<16;r++) v += red[r*64 + t];
    atomicAdd(&sumsF[ct*64 + t], v);
  }
  __syncthreads();
  #pragma unroll
  for (int ss=0; ss<4; ++ss) red[rg*64 + cg + ss*16] =
      hv[0][ss]*hv[0][ss]+hv[1][ss]*hv[1][ss]+hv[2][ss]*hv[2][ss]+hv[3][ss]*hv[3][ss];
  __syncthreads();
  if (t < 64) {
    float v = 0.f;
    #pragma unroll
    for (int r=0;r<16;r++) v += red[r*64 + t];
    atomicAdd(&sumsF[256 + ct*64 + t], v);
  }
  __syncthreads();
  #pragma unroll
  for (int ss=0; ss<4; ++ss) red[rg*64 + cg + ss*16] =
      fmaxf(fmaxf(hv[0][ss],hv[1][ss]), fmaxf(hv[2][ss],hv[3][ss]));
  __syncthreads();
  if (t < 64) {
    float v = -INFINITY;
    #pragma unroll
    for (int r=0;r<16;r++) v = fmaxf(v, red[r*64 + t]);
    atomicMax(&hpmx[b*256 + ct*64 + t], __float_as_uint(v));
  }
  __syncthreads();
  #pragma unroll
  for (int ss=0; ss<4; ++ss) red[rg*64 + cg + ss*16] =
      fminf(fminf(hv[0][ss],hv[1][ss]), fminf(hv[2][ss],hv[3][ss]));
  __syncthreads();
  if (t < 64) {
    float v = INFINITY;
    #pragma unroll
    for (int r=0;r<16;r++) v = fminf(v, red[r*64 + t]);
    atomicMin(&hpmn[b*256 + ct*64 + t], __float_as_uint(v));
  }
}

// ---------------- head ----------------
__global__ __launch_bounds__(256) void k_head(const float* __restrict__ sumsF, const float* __restrict__ gf,
                                              const float* __restrict__ bef,
                                              const unsigned* __restrict__ hpmx, const unsigned* __restrict__ hpmn,
                                              const float* __restrict__ wo1, const float* __restrict__ bo1,
                                              const float* __restrict__ go1, const float* __restrict__ beo1,
                                              const float* __restrict__ wo2, const float* __restrict__ bo2,
                                              const float* __restrict__ go2, const float* __restrict__ beo2,
                                              const float* __restrict__ wo3, const float* __restrict__ bo3,
                                              float* __restrict__ out) {
  __shared__ float hp[8][256];
  __shared__ float u1[8][128];
  __shared__ float u2[8][64];
  __shared__ float lg[8][16];
  int t = threadIdx.x;
  {
    float m = sumsF[t] * (1.f/16384.f);
    float v = sumsF[256+t] * (1.f/16384.f) - m*m;
    float sc = gf[t] / sqrtf(v + 1e-5f);
    float sh = bef[t] - m*sc;
    for (int b = 0; b < 8; ++b) {
      unsigned bits = (sc >= 0.f) ? hpmx[b*256+t] : hpmn[b*256+t];
      hp[b][t] = sc*__uint_as_float(bits) + sh;
    }
  }
  __syncthreads();
  for (int p = t; p < 1024; p += 256) {
    int b = p >> 7, c = p & 127;
    float z = bo1[c];
    for (int d = 0; d < 256; ++d) z += hp[b][d]*wo1[d*128+c];
    u1[b][c] = fmaxf(z, 0.f);
  }
  __syncthreads();
  if (t < 128) {
    float m = 0.f;
    for (int b=0;b<8;b++) m += u1[b][t];
    m *= 0.125f;
    float v = 0.f;
    for (int b=0;b<8;b++) { float dd = u1[b][t]-m; v += dd*dd; }
    v *= 0.125f;
    float sc = go1[t]/sqrtf(v+1e-5f), sh = beo1[t]-m*sc;
    for (int b=0;b<8;b++) u1[b][t] = sc*u1[b][t]+sh;
  }
  __syncthreads();
  for (int p = t; p < 512; p += 256) {
    int b = p >> 6, c = p & 63;
    float z = bo2[c];
    for (int d = 0; d < 128; ++d) z += u1[b][d]*wo2[d*64+c];
    u2[b][c] = fmaxf(z, 0.f);
  }
  __syncthreads();
  if (t < 64) {
    float m = 0.f;
    for (int b=0;b<8;b++) m += u2[b][t];
    m *= 0.125f;
    float v = 0.f;
    for (int b=0;b<8;b++) { float dd = u2[b][t]-m; v += dd*dd; }
    v *= 0.125f;
    float sc = go2[t]/sqrtf(v+1e-5f), sh = beo2[t]-m*sc;
    for (int b=0;b<8;b++) u2[b][t] = sc*u2[b][t]+sh;
  }
  __syncthreads();
  if (t < 128) {
    int b = t >> 4, c = t & 15;
    float z = bo3[c];
    for (int d = 0; d < 64; ++d) z += u2[b][d]*wo3[d*16+c];
    lg[b][c] = z;
  }
  __syncthreads();
  if (t < 8) {
    float m = -INFINITY;
    for (int j=0;j<16;j++) m = fmaxf(m, lg[t][j]);
    float s = 0.f;
    for (int j=0;j<16;j++) s += expf(lg[t][j]-m);
    float ls = logf(s);
    for (int j=0;j<16;j++) out[t*16+j] = (lg[t][j]-m) - ls;
  }
}

// ---------------- launch ----------------
extern "C" void kernel_launch(void* const* d_in, const int* in_sizes, int n_in,
                              void* d_out, int out_size, void* d_ws, size_t ws_size,
                              hipStream_t stream) {
  (void)in_sizes; (void)n_in; (void)out_size; (void)ws_size;
  const float* pos = (const float*)d_in[0];
  const float* x   = (const float*)d_in[1];
  const float* w1  = (const float*)d_in[3];
  const float* b1  = (const float*)d_in[4];
  const float* g1  = (const float*)d_in[5];
  const float* be1 = (const float*)d_in[6];
  const float* w2  = (const float*)d_in[7];
  const float* b2  = (const float*)d_in[8];
  const float* g2  = (const float*)d_in[9];
  const float* be2 = (const float*)d_in[10];
  const float* wf  = (const float*)d_in[11];
  const float* bf  = (const float*)d_in[12];
  const float* gf  = (const float*)d_in[13];
  const float* bef = (const float*)d_in[14];
  const float* wo1 = (const float*)d_in[15];
  const float* bo1 = (const float*)d_in[16];
  const float* go1 = (const float*)d_in[17];
  const float* beo1= (const float*)d_in[18];
  const float* wo2 = (const float*)d_in[19];
  const float* bo2 = (const float*)d_in[20];
  const float* go2 = (const float*)d_in[21];
  const float* beo2= (const float*)d_in[22];
  const float* wo3 = (const float*)d_in[23];
  const float* bo3 = (const float*)d_in[24];

  char* ws = (char*)d_ws;
  float4*   f0    = (float4*)  (ws + OFF_F0);
  float*    ssq0  = (float*)   (ws + OFF_SSQ0);
  int*      idx1  = (int*)     (ws + OFF_IDX1);
  float*    xmx1  = (float*)   (ws + OFF_XMX1);
  float*    xmn1  = (float*)   (ws + OFF_XMN1);
  float*    sum1  = (float*)   (ws + OFF_SUM1);
  float*    x1    = (float*)   (ws + OFF_X1);
  float*    ssq1  = (float*)   (ws + OFF_SSQ1);
  int*      idx2  = (int*)     (ws + OFF_IDX2);
  float*    xmx2  = (float*)   (ws + OFF_XMX2);
  float*    xmn2  = (float*)   (ws + OFF_XMN2);
  float*    sum2  = (float*)   (ws + OFF_SUM2);
  float*    x2    = (float*)   (ws + OFF_X2);
  float*    sumF  = (float*)   (ws + OFF_SUMF);
  unsigned* hpmx  = (unsigned*)(ws + OFF_HPMX);
  unsigned* hpmn  = (unsigned*)(ws + OFF_HPMN);
  short*    wtg   = (short*)   (ws + OFF_X2);    // aliases x2 head (x2 dead until bn2apply)

  k_init    <<<64,   256, 0, stream>>>(pos, x, w2, f0, ssq0, wtg, sum1, sum2, sumF, hpmx, hpmn);
  k_knn1    <<<2048, 256, 0, stream>>>(f0, ssq0, idx1);
  k_mlp1    <<<512,  256, 0, stream>>>(f0, idx1, w1, b1, xmx1, xmn1, sum1);
  k_bn1apply<<<4096, 256, 0, stream>>>(sum1, g1, be1, xmx1, xmn1, x1);
  k_ssq1    <<<64,   256, 0, stream>>>(x1, ssq1);
  k_knn2    <<<1024, 256, 0, stream>>>(x1, ssq1, idx2);
  k_mlp2    <<<4096, 256, 0, stream>>>(x1, idx2, wtg, w2, b2, xmx2, xmn2, sum2);
  k_bn2apply<<<8192, 256, 0, stream>>>(sum2, g2, be2, xmx2, xmn2, x2);
  k_gemmF   <<<1024, 256, 0, stream>>>(x1, x2, wf, bf, sumF, hpmx, hpmn);
  k_head    <<<1,    256, 0, stream>>>(sumF, gf, bef, hpmx, hpmn,
                                       wo1, bo1, go1, beo1, wo2, bo2, go2, beo2, wo3, bo3,
                                       (float*)d_out);
}

// Round 13
// 673.625 us; speedup vs baseline: 1.2397x; 1.1764x over previous
//
#include <hip/hip_runtime.h>
#include <math.h>

#define NPTS 16384
#define KNB 20
#define SCAP 512

typedef __attribute__((ext_vector_type(8))) short short8;
typedef __attribute__((ext_vector_type(4))) float f32x4;

// ---------------- workspace layout (bytes, all naturally 256-aligned) ----------------
static const size_t OFF_F0   = 0;                                   // N x float4
static const size_t OFF_SSQ0 = OFF_F0   + (size_t)NPTS*4*4;         // N f32
static const size_t OFF_IDX1 = OFF_SSQ0 + (size_t)NPTS*4;           // N*20 i32
static const size_t OFF_XMX1 = OFF_IDX1 + (size_t)NPTS*KNB*4;       // N*64 f32
static const size_t OFF_XMN1 = OFF_XMX1 + (size_t)NPTS*64*4;        // N*64 f32
static const size_t OFF_SUM1 = OFF_XMN1 + (size_t)NPTS*64*4;        // 128 f32 (sum,sumsq)
static const size_t OFF_X1   = OFF_SUM1 + 512;                      // N*64 f32
static const size_t OFF_SSQ1 = OFF_X1   + (size_t)NPTS*64*4;        // N f32
static const size_t OFF_IDX2 = OFF_SSQ1 + (size_t)NPTS*4;           // N*20 i32 (global idx)
static const size_t OFF_XMX2 = OFF_IDX2 + (size_t)NPTS*KNB*4;       // N*128 f32
static const size_t OFF_XMN2 = OFF_XMX2 + (size_t)NPTS*128*4;       // N*128 f32
static const size_t OFF_SUM2 = OFF_XMN2 + (size_t)NPTS*128*4;       // 256 f32
static const size_t OFF_X2   = OFF_SUM2 + 1024;                     // N*128 f32
static const size_t OFF_SUMF = OFF_X2   + (size_t)NPTS*128*4;       // 512 f32
static const size_t OFF_HPMX = OFF_SUMF + 2048;                     // 8*256 u32 (float bits)
static const size_t OFF_HPMN = OFF_HPMX + 8*256*4;                  // 8*256 u32
// WT_g (bf16 W^T for mlp2, 32 KB) ALIASES x2 head: x2 is dead until bn2apply,
// which runs AFTER mlp2 has consumed wtg. k_init writes it first thing.

// ---------------- helpers ----------------
__device__ __forceinline__ float dot4f(float4 a, float4 b) {
  return a.x*b.x + a.y*b.y + a.z*b.z + a.w*b.w;
}

__device__ __forceinline__ float dot64v(const float* a, const float4* b4) {
  float s = 0.f;
  #pragma unroll
  for (int d4 = 0; d4 < 16; ++d4) {
    float4 b = b4[d4];
    s += a[4*d4+0]*b.x + a[4*d4+1]*b.y + a[4*d4+2]*b.z + a[4*d4+3]*b.w;
  }
  return s;
}

// f32 -> bf16 (RNE)
__device__ __forceinline__ short f2bf(float x) {
  union { float f; unsigned u; } v; v.f = x;
  unsigned r = (v.u + 0x7FFFu + ((v.u >> 16) & 1u)) >> 16;
  return (short)r;
}

// ---------------- branch-free sorting-network top-k machinery (with indices) ----------------
__device__ __forceinline__ void ce(float& a, int& ai, float& b, int& bi) {
  bool sw = b < a;
  float d0 = sw ? b : a;  float d1 = sw ? a : b;
  int   j0 = sw ? bi : ai; int  j1 = sw ? ai : bi;
  a = d0; ai = j0; b = d1; bi = j1;
}

__device__ __forceinline__ void sort16(float (&d)[16], int (&ix)[16]) {
  #pragma unroll
  for (int k = 2; k <= 16; k <<= 1) {
    #pragma unroll
    for (int j = k >> 1; j > 0; j >>= 1) {
      #pragma unroll
      for (int i = 0; i < 16; ++i) {
        int l = i ^ j;
        if (l > i) {
          if ((i & k) == 0) ce(d[i], ix[i], d[l], ix[l]);
          else              ce(d[l], ix[l], d[i], ix[i]);
        }
      }
    }
  }
}

__device__ __forceinline__ void bimerge32(float (&rd)[32], int (&ri)[32]) {
  #pragma unroll
  for (int j = 16; j > 0; j >>= 1) {
    #pragma unroll
    for (int i = 0; i < 32; ++i) {
      int l = i ^ j;
      if (l > i) ce(rd[i], ri[i], rd[l], ri[l]);
    }
  }
}

__device__ __forceinline__ void merge16(float (&rd)[32], int (&ri)[32],
                                        float (&bd)[16], int (&bi)[16]) {
  #pragma unroll
  for (int k = 0; k < 16; ++k) {
    bool sw = bd[15-k] < rd[16+k];
    rd[16+k] = sw ? bd[15-k] : rd[16+k];
    ri[16+k] = sw ? bi[15-k] : ri[16+k];
  }
  bimerge32(rd, ri);
}

__device__ __forceinline__ void mergelane(float (&rd)[32], int (&ri)[32], int mask) {
  float pd[32]; int pi[32];
  #pragma unroll
  for (int s = 0; s < 32; ++s) { pd[s] = __shfl_xor(rd[s], mask); pi[s] = __shfl_xor(ri[s], mask); }
  #pragma unroll
  for (int k = 0; k < 32; ++k) {
    bool sw = pd[31-k] < rd[k];
    rd[k] = sw ? pd[31-k] : rd[k];
    ri[k] = sw ? pi[31-k] : ri[k];
  }
  bimerge32(rd, ri);
}

// ---------------- value-only versions (threshold computation, 2 ops/CE) ----------------
__device__ __forceinline__ void vce(float& a, float& b) {
  float lo = fminf(a, b);
  b = fmaxf(a, b);
  a = lo;
}

__device__ __forceinline__ void vsort16(float (&d)[16]) {
  #pragma unroll
  for (int k = 2; k <= 16; k <<= 1) {
    #pragma unroll
    for (int j = k >> 1; j > 0; j >>= 1) {
      #pragma unroll
      for (int i = 0; i < 16; ++i) {
        int l = i ^ j;
        if (l > i) {
          if ((i & k) == 0) vce(d[i], d[l]);
          else              vce(d[l], d[i]);
        }
      }
    }
  }
}

__device__ __forceinline__ void vbimerge32(float (&rd)[32]) {
  #pragma unroll
  for (int j = 16; j > 0; j >>= 1) {
    #pragma unroll
    for (int i = 0; i < 32; ++i) {
      int l = i ^ j;
      if (l > i) vce(rd[i], rd[l]);
    }
  }
}

__device__ __forceinline__ void vmerge16(float (&rd)[32], float (&bd)[16]) {
  #pragma unroll
  for (int k = 0; k < 16; ++k) rd[16+k] = fminf(rd[16+k], bd[15-k]);
  vbimerge32(rd);
}

__device__ __forceinline__ void vmergelane(float (&rd)[32], int mask) {
  float pd[32];
  #pragma unroll
  for (int s = 0; s < 32; ++s) pd[s] = __shfl_xor(rd[s], mask);
  #pragma unroll
  for (int k = 0; k < 32; ++k) rd[k] = fminf(rd[k], pd[31-k]);
  vbimerge32(rd);
}

// ---------------- init + f0 + wprep fused (grid 64; accumulators reset EVERY launch) ----------------
__global__ __launch_bounds__(256) void k_init(const float* __restrict__ pos, const float* __restrict__ x,
                                              const float* __restrict__ w2,
                                              float4* __restrict__ f0, float* __restrict__ ssq,
                                              short* __restrict__ wtg,
                                              float* sum1, float* sum2, float* sumF,
                                              unsigned* hpmx, unsigned* hpmn) {
  int gt = blockIdx.x*256 + threadIdx.x;   // 0..16383
  float4 f;
  f.x = pos[3*gt+0]; f.y = pos[3*gt+1]; f.z = pos[3*gt+2]; f.w = x[gt];
  f0[gt] = f;
  ssq[gt] = dot4f(f, f);
  { int c = gt >> 7, k = gt & 127; wtg[c*128 + k] = f2bf(w2[k*128 + c]); }
  if (gt < 128) sum1[gt] = 0.f;
  if (gt < 256) sum2[gt] = 0.f;
  if (gt < 512) sumF[gt] = 0.f;
  if (gt < 2048) { hpmx[gt] = 0u; hpmn[gt] = 0x7f800000u; }   // relu>=0 -> uint order == float order
}

// ---------------- knn1 v4: global-direct two-phase exact; survivors store INDEX ONLY ----------------
__global__ __launch_bounds__(256) void k_knn1(const float4* __restrict__ f0, const float* __restrict__ ssq,
                                              int* __restrict__ idx1) {
  __shared__ int survj[8][SCAP];
  __shared__ int scnt[8];
  __shared__ float rowT[8];
  int t = threadIdx.x;
  int r = t >> 5;
  int lane = t & 31;
  int row = blockIdx.x*8 + r;
  if (t < 8) scnt[t] = 0;
  float4 fi = f0[row];
  float sqi = ssq[row];
  // ---- pass 1: value-only top-32 of sample [0,2048)
  {
    float rd[32];
    #pragma unroll
    for (int s = 0; s < 32; ++s) rd[s] = INFINITY;
    #pragma unroll
    for (int b = 0; b < 4; ++b) {
      float bd[16];
      #pragma unroll
      for (int u = 0; u < 16; ++u) {
        int j = b*512 + u*32 + lane;
        float4 c = f0[j];
        bd[u] = (sqi - 2.f*dot4f(fi, c)) + ssq[j];
      }
      vsort16(bd);
      vmerge16(rd, bd);
    }
    vmergelane(rd, 1); vmergelane(rd, 2); vmergelane(rd, 4);
    vmergelane(rd, 8); vmergelane(rd, 16);
    if (lane == 0) rowT[r] = rd[19];
  }
  __syncthreads();
  // ---- pass 2: candidate-major filter over all 16384
  {
    float4 fr[8]; float sr[8], Tr[8];
    #pragma unroll
    for (int q = 0; q < 8; ++q) {
      fr[q] = f0[blockIdx.x*8 + q];
      sr[q] = ssq[blockIdx.x*8 + q];
      Tr[q] = rowT[q];
    }
    #pragma unroll 4
    for (int k = 0; k < 64; ++k) {
      int j = k*256 + t;
      float4 c = f0[j];
      float cq = ssq[j];
      #pragma unroll
      for (int q = 0; q < 8; ++q) {
        float d = (sr[q] - 2.f*dot4f(fr[q], c)) + cq;
        if (d <= Tr[q]) {
          int slot = atomicAdd(&scnt[q], 1);
          if (slot < SCAP) survj[q][slot] = j;
        }
      }
    }
  }
  __syncthreads();
  int n = scnt[r] < SCAP ? scnt[r] : SCAP;
  // ---- pass 3: recompute d (bitwise-identical expr) + exact index top-20
  float rd[32]; int ri[32];
  #pragma unroll
  for (int s = 0; s < 32; ++s) { rd[s] = INFINITY; ri[s] = 0; }
  {
    float bd[16]; int bix[16];
    #pragma unroll
    for (int u = 0; u < 16; ++u) {
      int s = u*32 + lane;
      if (s < n) {
        int j = survj[r][s];
        float4 c = f0[j];
        bd[u] = (sqi - 2.f*dot4f(fi, c)) + ssq[j];
        bix[u] = j;
      } else { bd[u] = INFINITY; bix[u] = 0; }
    }
    sort16(bd, bix);
    merge16(rd, ri, bd, bix);
  }
  mergelane(rd, ri, 1); mergelane(rd, ri, 2); mergelane(rd, ri, 4);
  mergelane(rd, ri, 8); mergelane(rd, ri, 16);
  if (lane == 0) {
    int4* p = (int4*)&idx1[row*KNB];
    p[0] = make_int4(ri[0],ri[1],ri[2],ri[3]);
    p[1] = make_int4(ri[4],ri[5],ri[6],ri[7]);
    p[2] = make_int4(ri[8],ri[9],ri[10],ri[11]);
    p[3] = make_int4(ri[12],ri[13],ri[14],ri[15]);
    p[4] = make_int4(ri[16],ri[17],ri[18],ri[19]);
  }
}

// ---------------- mlp1: edge MLP 8->64, relu, per-point max/min (pre-BN), channel sums ----------------
__global__ __launch_bounds__(256) void k_mlp1(const float4* __restrict__ f0, const int* __restrict__ idx1,
                                              const float* __restrict__ w1, const float* __restrict__ b1,
                                              float* __restrict__ xmx, float* __restrict__ xmn,
                                              float* __restrict__ sums) {
  __shared__ float rs[256], rs2[256];
  int t = threadIdx.x;
  int c = t & 63;
  int w = t >> 6;
  float wc[8];
  #pragma unroll
  for (int d = 0; d < 8; ++d) wc[d] = w1[d*64 + c];
  float bc = b1[c];
  float s = 0.f, s2 = 0.f;
  for (int p = 0; p < 8; ++p) {
    int i = blockIdx.x*32 + p*4 + w;
    float4 fi = f0[i];
    float mx = -INFINITY, mn = INFINITY;
    #pragma unroll
    for (int k = 0; k < KNB; ++k) {
      int j = idx1[i*KNB + k];
      float4 fj = f0[j];
      float h = bc + fi.x*wc[0] + fi.y*wc[1] + fi.z*wc[2] + fi.w*wc[3]
                   + (fj.x-fi.x)*wc[4] + (fj.y-fi.y)*wc[5] + (fj.z-fi.z)*wc[6] + (fj.w-fi.w)*wc[7];
      h = fmaxf(h, 0.f);
      mx = fmaxf(mx, h); mn = fminf(mn, h);
      s += h; s2 += h*h;
    }
    xmx[i*64+c] = mx; xmn[i*64+c] = mn;
  }
  rs[t] = s; rs2[t] = s2;
  __syncthreads();
  if (t < 64) {
    atomicAdd(&sums[c],      rs[t]+rs[t+64]+rs[t+128]+rs[t+192]);
    atomicAdd(&sums[64+c],   rs2[t]+rs2[t+64]+rs2[t+128]+rs2[t+192]);
  }
}

// ---------------- bn1 apply: x1 = affine(max or min by scale sign) ----------------
__global__ __launch_bounds__(256) void k_bn1apply(const float* __restrict__ sums, const float* __restrict__ g,
                                                  const float* __restrict__ be, const float* __restrict__ xmx,
                                                  const float* __restrict__ xmn, float* __restrict__ x1) {
  __shared__ float sc_s[64], sh_s[64];
  int t = threadIdx.x;
  if (t < 64) {
    float m = sums[t] * (1.f/327680.f);
    float v = sums[64+t] * (1.f/327680.f) - m*m;
    float sc = g[t] / sqrtf(v + 1e-5f);
    sc_s[t] = sc; sh_s[t] = be[t] - m*sc;
  }
  __syncthreads();
  int c = t & 63;
  int i = blockIdx.x*4 + (t>>6);
  float sc = sc_s[c], sh = sh_s[c];
  float val = (sc >= 0.f) ? xmx[i*64+c] : xmn[i*64+c];
  x1[i*64+c] = sc*val + sh;
}

// ---------------- ssq1 (same dot64v ordering as knn2 for exact self-distance) ----------------
__global__ __launch_bounds__(256) void k_ssq1(const float* __restrict__ x1, float* __restrict__ ssq1) {
  int i = blockIdx.x*256 + threadIdx.x;
  alignas(16) float f[64];
  #pragma unroll
  for (int d4 = 0; d4 < 16; ++d4) ((float4*)f)[d4] = ((const float4*)x1)[i*16 + d4];
  ssq1[i] = dot64v(f, (const float4*)f);
}

// ---------------- knn2 (R10 bitonic version, reverted): per-batch 2048-point 64-d knn ----------------
// 32 rows/block x 8 lanes/row, grid 512; one 16-batch per 128-candidate tile.
// tf pad 68 -> bank-arithmetic conflict-free (8 distinct 4-bank groups/wave).
__global__ __launch_bounds__(256) void k_knn2(const float* __restrict__ x1, const float* __restrict__ ssq1,
                                              int* __restrict__ idx2) {
  __shared__ __align__(16) float tf[128][68];
  __shared__ float tq[128];
  int t = threadIdx.x;
  int row = blockIdx.x*32 + (t>>3);
  int lane = t & 7;
  int cbase = (row >> 11) << 11;                // batch column base
  alignas(16) float fi[64];
  #pragma unroll
  for (int d4 = 0; d4 < 16; ++d4) ((float4*)fi)[d4] = ((const float4*)x1)[row*16 + d4];
  float sqi = ssq1[row];
  float rd[32]; int ri[32];
  #pragma unroll
  for (int s = 0; s < 32; ++s) { rd[s] = INFINITY; ri[s] = 0; }
  for (int tile = 0; tile < 16; ++tile) {
    int base = cbase + tile*128;
    __syncthreads();
    for (int v = t; v < 128*16; v += 256) {
      int jl = v >> 4, d4 = v & 15;
      *(float4*)&tf[jl][d4*4] = ((const float4*)x1)[(base+jl)*16 + d4];
    }
    if (t < 128) tq[t] = ssq1[base + t];
    __syncthreads();
    float bd[16]; int bix[16];
    #pragma unroll
    for (int u = 0; u < 16; ++u) {
      int jl = u*8 + lane;
      bd[u] = (sqi - 2.f*dot64v(fi, (const float4*)&tf[jl][0])) + tq[jl];
      bix[u] = base + jl;
    }
    sort16(bd, bix);
    merge16(rd, ri, bd, bix);
  }
  mergelane(rd, ri, 1);
  mergelane(rd, ri, 2);
  mergelane(rd, ri, 4);
  if (lane == 0) {
    int4* p = (int4*)&idx2[row*KNB];
    p[0] = make_int4(ri[0],ri[1],ri[2],ri[3]);
    p[1] = make_int4(ri[4],ri[5],ri[6],ri[7]);
    p[2] = make_int4(ri[8],ri[9],ri[10],ri[11]);
    p[3] = make_int4(ri[12],ri[13],ri[14],ri[15]);
    p[4] = make_int4(ri[16],ri[17],ri[18],ri[19]);
  }
}

// ---------------- mlp2: edge MLP 128->128, shared-xi decomposition ----------------
__global__ __launch_bounds__(256) void k_mlp2(const float* __restrict__ x1, const int* __restrict__ idx2,
                                              const short* __restrict__ wtg, const float* __restrict__ w2,
                                              const float* __restrict__ b2,
                                              float* __restrict__ xmx, float* __restrict__ xmn,
                                              float* __restrict__ sums) {
  __shared__ __align__(16) short Elds[4*32*72];   // diffs only: [p][row][k<64], pitch 72
  __shared__ float xi_s[4][64];
  __shared__ float vi[4][128];
  __shared__ int js[4][KNB];
  int t = threadIdx.x;
  if (t < 4*KNB) js[t/KNB][t%KNB] = idx2[blockIdx.x*4*KNB + t];
  {
    int p = t >> 6, k = t & 63;
    xi_s[p][k] = x1[(blockIdx.x*4 + p)*64 + k];
  }
  __syncthreads();
  // vi[p][c] = b2[c] + sum_{k<64} xi[k]*w2[k][c]  (fp32 exact top-half + bias)
  #pragma unroll
  for (int v2 = 0; v2 < 2; ++v2) {
    int v = t + v2*256;
    int p = v >> 7, c = v & 127;
    float a = b2[c];
    #pragma unroll 8
    for (int k = 0; k < 64; ++k) a += xi_s[p][k] * w2[k*128 + c];
    vi[p][c] = a;
  }
  // stage E diffs (bf16): 4 pts x 32 rows x 8 chunks of 8
  #pragma unroll
  for (int cc = 0; cc < 4; ++cc) {
    int v = t + cc*256;
    int p  = v >> 8;
    int rr = (v >> 3) & 31;
    int kc = v & 7;
    short8 outv = {0,0,0,0,0,0,0,0};
    if (rr < KNB) {
      int j = js[p][rr];
      float4 j0 = ((const float4*)x1)[j*16 + kc*2];
      float4 j1 = ((const float4*)x1)[j*16 + kc*2 + 1];
      const float* xp = &xi_s[p][kc*8];
      outv[0]=f2bf(j0.x-xp[0]); outv[1]=f2bf(j0.y-xp[1]); outv[2]=f2bf(j0.z-xp[2]); outv[3]=f2bf(j0.w-xp[3]);
      outv[4]=f2bf(j1.x-xp[4]); outv[5]=f2bf(j1.y-xp[5]); outv[6]=f2bf(j1.z-xp[6]); outv[7]=f2bf(j1.w-xp[7]);
    }
    *(short8*)&Elds[p*2304 + rr*72 + kc*8] = outv;
  }
  __syncthreads();
  // compute: wave w owns cols [w*32, w*32+32); B-frags from global wtg (bottom half)
  int w = t >> 6, l = t & 63;
  int colA = w*32 + (l & 15);
  int colB = colA + 16;
  short8 bfr[2][2];
  #pragma unroll
  for (int n = 0; n < 2; ++n)
    #pragma unroll
    for (int kb = 0; kb < 2; ++kb) {
      int col = w*32 + n*16 + (l & 15);
      int k0 = 64 + kb*32 + (l >> 4)*8;
      bfr[n][kb] = *(const short8*)&wtg[col*128 + k0];
    }
  float sT0=0.f, qT0=0.f, sT1=0.f, qT1=0.f;
  #pragma unroll
  for (int p = 0; p < 4; ++p) {
    int i = blockIdx.x*4 + p;
    float vA = vi[p][colA], vB = vi[p][colB];
    float mx0=-INFINITY, mn0=INFINITY, s0=0.f, q0=0.f;
    float mx1=-INFINITY, mn1=INFINITY, s1=0.f, q1=0.f;
    #pragma unroll
    for (int m = 0; m < 2; ++m) {
      short8 af[2];
      #pragma unroll
      for (int kb = 0; kb < 2; ++kb) {
        int row = m*16 + (l & 15);
        int k0 = kb*32 + (l >> 4)*8;
        af[kb] = *(short8*)&Elds[p*2304 + row*72 + k0];
      }
      f32x4 acc0 = {vA, vA, vA, vA};
      f32x4 acc1 = {vB, vB, vB, vB};
      #pragma unroll
      for (int kb = 0; kb < 2; ++kb) {
        acc0 = __builtin_amdgcn_mfma_f32_16x16x32_bf16(af[kb], bfr[0][kb], acc0, 0, 0, 0);
        acc1 = __builtin_amdgcn_mfma_f32_16x16x32_bf16(af[kb], bfr[1][kb], acc1, 0, 0, 0);
      }
      int rbase = (l >> 4)*4 + m*16;
      #pragma unroll
      for (int reg = 0; reg < 4; ++reg) {
        bool valid = (rbase + reg) < KNB;
        float h0 = fmaxf(acc0[reg], 0.f);
        float h1 = fmaxf(acc1[reg], 0.f);
        if (valid) {
          mx0 = fmaxf(mx0, h0); mn0 = fminf(mn0, h0); s0 += h0; q0 += h0*h0;
          mx1 = fmaxf(mx1, h1); mn1 = fminf(mn1, h1); s1 += h1; q1 += h1*h1;
        }
      }
    }
    // butterfly over the 4 lane-groups sharing each col
    #pragma unroll
    for (int dlt = 16; dlt <= 32; dlt <<= 1) {
      mx0 = fmaxf(mx0, __shfl_xor(mx0, dlt)); mn0 = fminf(mn0, __shfl_xor(mn0, dlt));
      s0 += __shfl_xor(s0, dlt);              q0 += __shfl_xor(q0, dlt);
      mx1 = fmaxf(mx1, __shfl_xor(mx1, dlt)); mn1 = fminf(mn1, __shfl_xor(mn1, dlt));
      s1 += __shfl_xor(s1, dlt);              q1 += __shfl_xor(q1, dlt);
    }
    if (l < 16) {
      xmx[i*128 + colA] = mx0; xmx[i*128 + colB] = mx1;
      xmn[i*128 + colA] = mn0; xmn[i*128 + colB] = mn1;
    }
    sT0 += s0; qT0 += q0; sT1 += s1; qT1 += q1;
  }
  if (l < 16) {
    atomicAdd(&sums[colA], sT0);       atomicAdd(&sums[colB], sT1);
    atomicAdd(&sums[128 + colA], qT0); atomicAdd(&sums[128 + colB], qT1);
  }
}

// ---------------- bn2 apply ----------------
__global__ __launch_bounds__(256) void k_bn2apply(const float* __restrict__ sums, const float* __restrict__ g,
                                                  const float* __restrict__ be, const float* __restrict__ xmx,
                                                  const float* __restrict__ xmn, float* __restrict__ x2) {
  __shared__ float sc_s[128], sh_s[128];
  int t = threadIdx.x;
  if (t < 128) {
    float m = sums[t] * (1.f/327680.f);
    float v = sums[128+t] * (1.f/327680.f) - m*m;
    float sc = g[t] / sqrtf(v + 1e-5f);
    sc_s[t] = sc; sh_s[t] = be[t] - m*sc;
  }
  __syncthreads();
  int c = t & 127;
  int i = blockIdx.x*2 + (t>>7);
  float sc = sc_s[c], sh = sh_s[c];
  float val = (sc >= 0.f) ? xmx[i*128+c] : xmn[i*128+c];
  x2[i*128+c] = sc*val + sh;
}

// ---------------- gemmF: relu([x1|x2] @ wf + bf); channel sums + per-batch max/min only ----------------
__global__ __launch_bounds__(256) void k_gemmF(const float* __restrict__ x1, const float* __restrict__ x2,
                                               const float* __restrict__ wf, const float* __restrict__ bf,
                                               float* __restrict__ sumsF, unsigned* __restrict__ hpmx,
                                               unsigned* __restrict__ hpmn) {
  __shared__ float A_s[64*193];
  __shared__ __align__(16) float B_s[192*64];
  __shared__ float red[1024];
  int t = threadIdx.x;
  int rt = blockIdx.x >> 2;
  int ct = blockIdx.x & 3;
  for (int v = t; v < 64*48; v += 256) {
    int r = v / 48, gg = v - r*48;
    int row = rt*64 + r;
    float4 e = (gg < 16) ? ((const float4*)x1)[row*16 + gg]
                         : ((const float4*)x2)[row*32 + (gg-16)];
    float* p = &A_s[r*193 + gg*4];
    p[0]=e.x; p[1]=e.y; p[2]=e.z; p[3]=e.w;
  }
  for (int v = t; v < 192*16; v += 256) {
    int d = v >> 4, c4 = v & 15;
    *(float4*)&B_s[d*64 + c4*4] = ((const float4*)wf)[d*64 + ct*16 + c4];
  }
  __syncthreads();
  int rg = t & 15, cg = t >> 4;
  float acc[4][4];
  #pragma unroll
  for (int a=0;a<4;a++) { acc[a][0]=0.f; acc[a][1]=0.f; acc[a][2]=0.f; acc[a][3]=0.f; }
  for (int d = 0; d < 192; ++d) {
    float a0 = A_s[(rg*4+0)*193 + d];
    float a1 = A_s[(rg*4+1)*193 + d];
    float a2 = A_s[(rg*4+2)*193 + d];
    float a3 = A_s[(rg*4+3)*193 + d];
    float b0 = B_s[d*64 + cg];
    float b1 = B_s[d*64 + cg + 16];
    float b2 = B_s[d*64 + cg + 32];
    float b3 = B_s[d*64 + cg + 48];
    acc[0][0]+=a0*b0; acc[0][1]+=a0*b1; acc[0][2]+=a0*b2; acc[0][3]+=a0*b3;
    acc[1][0]+=a1*b0; acc[1][1]+=a1*b1; acc[1][2]+=a1*b2; acc[1][3]+=a1*b3;
    acc[2][0]+=a2*b0; acc[2][1]+=a2*b1; acc[2][2]+=a2*b2; acc[2][3]+=a2*b3;
    acc[3][0]+=a3*b0; acc[3][1]+=a3*b1; acc[3][2]+=a3*b2; acc[3][3]+=a3*b3;
  }
  float hv[4][4];
  #pragma unroll
  for (int ss=0; ss<4; ++ss) {
    float bb = bf[ct*64 + cg + ss*16];
    #pragma unroll
    for (int rr=0; rr<4; ++rr) hv[rr][ss] = fmaxf(acc[rr][ss] + bb, 0.f);
  }
  int b = rt >> 5;
  #pragma unroll
  for (int ss=0; ss<4; ++ss) red[rg*64 + cg + ss*16] = hv[0][ss]+hv[1][ss]+hv[2][ss]+hv[3][ss];
  __syncthreads();
  if (t < 64) {
    float v = 0.f;
    #pragma unroll
    for (int r=0;r<16;r++) v += red[r*64 + t];
    atomicAdd(&sumsF[ct*64 + t], v);
  }
  __syncthreads();
  #pragma unroll
  for (int ss=0; ss<4; ++ss) red[rg*64 + cg + ss*16] =
      hv[0][ss]*hv[0][ss]+hv[1][ss]*hv[1][ss]+hv[2][ss]*hv[2][ss]+hv[3][ss]*hv[3][ss];
  __syncthreads();
  if (t < 64) {
    float v = 0.f;
    #pragma unroll
    for (int r=0;r<16;r++) v += red[r*64 + t];
    atomicAdd(&sumsF[256 + ct*64 + t], v);
  }
  __syncthreads();
  #pragma unroll
  for (int ss=0; ss<4; ++ss) red[rg*64 + cg + ss*16] =
      fmaxf(fmaxf(hv[0][ss],hv[1][ss]), fmaxf(hv[2][ss],hv[3][ss]));
  __syncthreads();
  if (t < 64) {
    float v = -INFINITY;
    #pragma unroll
    for (int r=0;r<16;r++) v = fmaxf(v, red[r*64 + t]);
    atomicMax(&hpmx[b*256 + ct*64 + t], __float_as_uint(v));
  }
  __syncthreads();
  #pragma unroll
  for (int ss=0; ss<4; ++ss) red[rg*64 + cg + ss*16] =
      fminf(fminf(hv[0][ss],hv[1][ss]), fminf(hv[2][ss],hv[3][ss]));
  __syncthreads();
  if (t < 64) {
    float v = INFINITY;
    #pragma unroll
    for (int r=0;r<16;r++) v = fminf(v, red[r*64 + t]);
    atomicMin(&hpmn[b*256 + ct*64 + t], __float_as_uint(v));
  }
}

// ---------------- head ----------------
__global__ __launch_bounds__(256) void k_head(const float* __restrict__ sumsF, const float* __restrict__ gf,
                                              const float* __restrict__ bef,
                                              const unsigned* __restrict__ hpmx, const unsigned* __restrict__ hpmn,
                                              const float* __restrict__ wo1, const float* __restrict__ bo1,
                                              const float* __restrict__ go1, const float* __restrict__ beo1,
                                              const float* __restrict__ wo2, const float* __restrict__ bo2,
                                              const float* __restrict__ go2, const float* __restrict__ beo2,
                                              const float* __restrict__ wo3, const float* __restrict__ bo3,
                                              float* __restrict__ out) {
  __shared__ float hp[8][256];
  __shared__ float u1[8][128];
  __shared__ float u2[8][64];
  __shared__ float lg[8][16];
  int t = threadIdx.x;
  {
    float m = sumsF[t] * (1.f/16384.f);
    float v = sumsF[256+t] * (1.f/16384.f) - m*m;
    float sc = gf[t] / sqrtf(v + 1e-5f);
    float sh = bef[t] - m*sc;
    for (int b = 0; b < 8; ++b) {
      unsigned bits = (sc >= 0.f) ? hpmx[b*256+t] : hpmn[b*256+t];
      hp[b][t] = sc*__uint_as_float(bits) + sh;
    }
  }
  __syncthreads();
  for (int p = t; p < 1024; p += 256) {
    int b = p >> 7, c = p & 127;
    float z = bo1[c];
    for (int d = 0; d < 256; ++d) z += hp[b][d]*wo1[d*128+c];
    u1[b][c] = fmaxf(z, 0.f);
  }
  __syncthreads();
  if (t < 128) {
    float m = 0.f;
    for (int b=0;b<8;b++) m += u1[b][t];
    m *= 0.125f;
    float v = 0.f;
    for (int b=0;b<8;b++) { float dd = u1[b][t]-m; v += dd*dd; }
    v *= 0.125f;
    float sc = go1[t]/sqrtf(v+1e-5f), sh = beo1[t]-m*sc;
    for (int b=0;b<8;b++) u1[b][t] = sc*u1[b][t]+sh;
  }
  __syncthreads();
  for (int p = t; p < 512; p += 256) {
    int b = p >> 6, c = p & 63;
    float z = bo2[c];
    for (int d = 0; d < 128; ++d) z += u1[b][d]*wo2[d*64+c];
    u2[b][c] = fmaxf(z, 0.f);
  }
  __syncthreads();
  if (t < 64) {
    float m = 0.f;
    for (int b=0;b<8;b++) m += u2[b][t];
    m *= 0.125f;
    float v = 0.f;
    for (int b=0;b<8;b++) { float dd = u2[b][t]-m; v += dd*dd; }
    v *= 0.125f;
    float sc = go2[t]/sqrtf(v+1e-5f), sh = beo2[t]-m*sc;
    for (int b=0;b<8;b++) u2[b][t] = sc*u2[b][t]+sh;
  }
  __syncthreads();
  if (t < 128) {
    int b = t >> 4, c = t & 15;
    float z = bo3[c];
    for (int d = 0; d < 64; ++d) z += u2[b][d]*wo3[d*16+c];
    lg[b][c] = z;
  }
  __syncthreads();
  if (t < 8) {
    float m = -INFINITY;
    for (int j=0;j<16;j++) m = fmaxf(m, lg[t][j]);
    float s = 0.f;
    for (int j=0;j<16;j++) s += expf(lg[t][j]-m);
    float ls = logf(s);
    for (int j=0;j<16;j++) out[t*16+j] = (lg[t][j]-m) - ls;
  }
}

// ---------------- launch ----------------
extern "C" void kernel_launch(void* const* d_in, const int* in_sizes, int n_in,
                              void* d_out, int out_size, void* d_ws, size_t ws_size,
                              hipStream_t stream) {
  (void)in_sizes; (void)n_in; (void)out_size; (void)ws_size;
  const float* pos = (const float*)d_in[0];
  const float* x   = (const float*)d_in[1];
  const float* w1  = (const float*)d_in[3];
  const float* b1  = (const float*)d_in[4];
  const float* g1  = (const float*)d_in[5];
  const float* be1 = (const float*)d_in[6];
  const float* w2  = (const float*)d_in[7];
  const float* b2  = (const float*)d_in[8];
  const float* g2  = (const float*)d_in[9];
  const float* be2 = (const float*)d_in[10];
  const float* wf  = (const float*)d_in[11];
  const float* bf  = (const float*)d_in[12];
  const float* gf  = (const float*)d_in[13];
  const float* bef = (const float*)d_in[14];
  const float* wo1 = (const float*)d_in[15];
  const float* bo1 = (const float*)d_in[16];
  const float* go1 = (const float*)d_in[17];
  const float* beo1= (const float*)d_in[18];
  const float* wo2 = (const float*)d_in[19];
  const float* bo2 = (const float*)d_in[20];
  const float* go2 = (const float*)d_in[21];
  const float* beo2= (const float*)d_in[22];
  const float* wo3 = (const float*)d_in[23];
  const float* bo3 = (const float*)d_in[24];

  char* ws = (char*)d_ws;
  float4*   f0    = (float4*)  (ws + OFF_F0);
  float*    ssq0  = (float*)   (ws + OFF_SSQ0);
  int*      idx1  = (int*)     (ws + OFF_IDX1);
  float*    xmx1  = (float*)   (ws + OFF_XMX1);
  float*    xmn1  = (float*)   (ws + OFF_XMN1);
  float*    sum1  = (float*)   (ws + OFF_SUM1);
  float*    x1    = (float*)   (ws + OFF_X1);
  float*    ssq1  = (float*)   (ws + OFF_SSQ1);
  int*      idx2  = (int*)     (ws + OFF_IDX2);
  float*    xmx2  = (float*)   (ws + OFF_XMX2);
  float*    xmn2  = (float*)   (ws + OFF_XMN2);
  float*    sum2  = (float*)   (ws + OFF_SUM2);
  float*    x2    = (float*)   (ws + OFF_X2);
  float*    sumF  = (float*)   (ws + OFF_SUMF);
  unsigned* hpmx  = (unsigned*)(ws + OFF_HPMX);
  unsigned* hpmn  = (unsigned*)(ws + OFF_HPMN);
  short*    wtg   = (short*)   (ws + OFF_X2);    // aliases x2 head (x2 dead until bn2apply)

  k_init    <<<64,   256, 0, stream>>>(pos, x, w2, f0, ssq0, wtg, sum1, sum2, sumF, hpmx, hpmn);
  k_knn1    <<<2048, 256, 0, stream>>>(f0, ssq0, idx1);
  k_mlp1    <<<512,  256, 0, stream>>>(f0, idx1, w1, b1, xmx1, xmn1, sum1);
  k_bn1apply<<<4096, 256, 0, stream>>>(sum1, g1, be1, xmx1, xmn1, x1);
  k_ssq1    <<<64,   256, 0, stream>>>(x1, ssq1);
  k_knn2    <<<512,  256, 0, stream>>>(x1, ssq1, idx2);
  k_mlp2    <<<4096, 256, 0, stream>>>(x1, idx2, wtg, w2, b2, xmx2, xmn2, sum2);
  k_bn2apply<<<8192, 256, 0, stream>>>(sum2, g2, be2, xmx2, xmn2, x2);
  k_gemmF   <<<1024, 256, 0, stream>>>(x1, x2, wf, bf, sumF, hpmx, hpmn);
  k_head    <<<1,    256, 0, stream>>>(sumF, gf, bef, hpmx, hpmn,
                                       wo1, bo1, go1, beo1, wo2, bo2, go2, beo2, wo3, bo3,
                                       (float*)d_out);
}

// Round 14
// 604.135 us; speedup vs baseline: 1.3823x; 1.1150x over previous
//
#include <hip/hip_runtime.h>
#include <math.h>

#define NPTS 16384
#define KNB 20
#define SCAP 512

typedef __attribute__((ext_vector_type(8))) short short8;
typedef __attribute__((ext_vector_type(4))) float f32x4;

// ---------------- workspace layout (bytes, all naturally 256-aligned) ----------------
static const size_t OFF_F0   = 0;                                   // N x float4
static const size_t OFF_SSQ0 = OFF_F0   + (size_t)NPTS*4*4;         // N f32
static const size_t OFF_IDX1 = OFF_SSQ0 + (size_t)NPTS*4;           // N*20 i32
static const size_t OFF_XMX1 = OFF_IDX1 + (size_t)NPTS*KNB*4;       // N*64 f32
static const size_t OFF_XMN1 = OFF_XMX1 + (size_t)NPTS*64*4;        // N*64 f32
static const size_t OFF_SUM1 = OFF_XMN1 + (size_t)NPTS*64*4;        // 128 f32 (sum,sumsq)
static const size_t OFF_X1   = OFF_SUM1 + 512;                      // N*64 f32
static const size_t OFF_SSQ1 = OFF_X1   + (size_t)NPTS*64*4;        // N f32
static const size_t OFF_IDX2 = OFF_SSQ1 + (size_t)NPTS*4;           // N*20 i32 (global idx)
static const size_t OFF_XMX2 = OFF_IDX2 + (size_t)NPTS*KNB*4;       // N*128 f32
static const size_t OFF_XMN2 = OFF_XMX2 + (size_t)NPTS*128*4;       // N*128 f32
static const size_t OFF_SUM2 = OFF_XMN2 + (size_t)NPTS*128*4;       // 256 f32
static const size_t OFF_X2   = OFF_SUM2 + 1024;                     // N*128 f32
static const size_t OFF_SUMF = OFF_X2   + (size_t)NPTS*128*4;       // 512 f32
static const size_t OFF_HPMX = OFF_SUMF + 2048;                     // 8*256 u32 (float bits)
static const size_t OFF_HPMN = OFF_HPMX + 8*256*4;                  // 8*256 u32
// WT_g (bf16 W^T for mlp2, 32 KB) ALIASES x2 head: x2 is dead until bn2apply,
// which runs AFTER mlp2 has consumed wtg. k_init writes it first thing.

// ---------------- helpers ----------------
__device__ __forceinline__ float dot4f(float4 a, float4 b) {
  return a.x*b.x + a.y*b.y + a.z*b.z + a.w*b.w;
}

__device__ __forceinline__ float dot64v(const float* a, const float4* b4) {
  float s = 0.f;
  #pragma unroll
  for (int d4 = 0; d4 < 16; ++d4) {
    float4 b = b4[d4];
    s += a[4*d4+0]*b.x + a[4*d4+1]*b.y + a[4*d4+2]*b.z + a[4*d4+3]*b.w;
  }
  return s;
}

// f32 -> bf16 (RNE)
__device__ __forceinline__ short f2bf(float x) {
  union { float f; unsigned u; } v; v.f = x;
  unsigned r = (v.u + 0x7FFFu + ((v.u >> 16) & 1u)) >> 16;
  return (short)r;
}

// ---------------- branch-free sorting-network top-k machinery (with indices) ----------------
__device__ __forceinline__ void ce(float& a, int& ai, float& b, int& bi) {
  bool sw = b < a;
  float d0 = sw ? b : a;  float d1 = sw ? a : b;
  int   j0 = sw ? bi : ai; int  j1 = sw ? ai : bi;
  a = d0; ai = j0; b = d1; bi = j1;
}

__device__ __forceinline__ void sort16(float (&d)[16], int (&ix)[16]) {
  #pragma unroll
  for (int k = 2; k <= 16; k <<= 1) {
    #pragma unroll
    for (int j = k >> 1; j > 0; j >>= 1) {
      #pragma unroll
      for (int i = 0; i < 16; ++i) {
        int l = i ^ j;
        if (l > i) {
          if ((i & k) == 0) ce(d[i], ix[i], d[l], ix[l]);
          else              ce(d[l], ix[l], d[i], ix[i]);
        }
      }
    }
  }
}

__device__ __forceinline__ void bimerge32(float (&rd)[32], int (&ri)[32]) {
  #pragma unroll
  for (int j = 16; j > 0; j >>= 1) {
    #pragma unroll
    for (int i = 0; i < 32; ++i) {
      int l = i ^ j;
      if (l > i) ce(rd[i], ri[i], rd[l], ri[l]);
    }
  }
}

__device__ __forceinline__ void merge16(float (&rd)[32], int (&ri)[32],
                                        float (&bd)[16], int (&bi)[16]) {
  #pragma unroll
  for (int k = 0; k < 16; ++k) {
    bool sw = bd[15-k] < rd[16+k];
    rd[16+k] = sw ? bd[15-k] : rd[16+k];
    ri[16+k] = sw ? bi[15-k] : ri[16+k];
  }
  bimerge32(rd, ri);
}

__device__ __forceinline__ void mergelane(float (&rd)[32], int (&ri)[32], int mask) {
  float pd[32]; int pi[32];
  #pragma unroll
  for (int s = 0; s < 32; ++s) { pd[s] = __shfl_xor(rd[s], mask); pi[s] = __shfl_xor(ri[s], mask); }
  #pragma unroll
  for (int k = 0; k < 32; ++k) {
    bool sw = pd[31-k] < rd[k];
    rd[k] = sw ? pd[31-k] : rd[k];
    ri[k] = sw ? pi[31-k] : ri[k];
  }
  bimerge32(rd, ri);
}

// ---------------- value-only versions (threshold computation, 2 ops/CE) ----------------
__device__ __forceinline__ void vce(float& a, float& b) {
  float lo = fminf(a, b);
  b = fmaxf(a, b);
  a = lo;
}

__device__ __forceinline__ void vsort16(float (&d)[16]) {
  #pragma unroll
  for (int k = 2; k <= 16; k <<= 1) {
    #pragma unroll
    for (int j = k >> 1; j > 0; j >>= 1) {
      #pragma unroll
      for (int i = 0; i < 16; ++i) {
        int l = i ^ j;
        if (l > i) {
          if ((i & k) == 0) vce(d[i], d[l]);
          else              vce(d[l], d[i]);
        }
      }
    }
  }
}

__device__ __forceinline__ void vbimerge32(float (&rd)[32]) {
  #pragma unroll
  for (int j = 16; j > 0; j >>= 1) {
    #pragma unroll
    for (int i = 0; i < 32; ++i) {
      int l = i ^ j;
      if (l > i) vce(rd[i], rd[l]);
    }
  }
}

__device__ __forceinline__ void vmerge16(float (&rd)[32], float (&bd)[16]) {
  #pragma unroll
  for (int k = 0; k < 16; ++k) rd[16+k] = fminf(rd[16+k], bd[15-k]);
  vbimerge32(rd);
}

__device__ __forceinline__ void vmergelane(float (&rd)[32], int mask) {
  float pd[32];
  #pragma unroll
  for (int s = 0; s < 32; ++s) pd[s] = __shfl_xor(rd[s], mask);
  #pragma unroll
  for (int k = 0; k < 32; ++k) rd[k] = fminf(rd[k], pd[31-k]);
  vbimerge32(rd);
}

// ---------------- init + f0 + wprep fused (grid 64; accumulators reset EVERY launch) ----------------
__global__ __launch_bounds__(256) void k_init(const float* __restrict__ pos, const float* __restrict__ x,
                                              const float* __restrict__ w2,
                                              float4* __restrict__ f0, float* __restrict__ ssq,
                                              short* __restrict__ wtg,
                                              float* sum1, float* sum2, float* sumF,
                                              unsigned* hpmx, unsigned* hpmn) {
  int gt = blockIdx.x*256 + threadIdx.x;   // 0..16383
  float4 f;
  f.x = pos[3*gt+0]; f.y = pos[3*gt+1]; f.z = pos[3*gt+2]; f.w = x[gt];
  f0[gt] = f;
  ssq[gt] = dot4f(f, f);
  { int c = gt >> 7, k = gt & 127; wtg[c*128 + k] = f2bf(w2[k*128 + c]); }
  if (gt < 128) sum1[gt] = 0.f;
  if (gt < 256) sum2[gt] = 0.f;
  if (gt < 512) sumF[gt] = 0.f;
  if (gt < 2048) { hpmx[gt] = 0u; hpmn[gt] = 0x7f800000u; }   // relu>=0 -> uint order == float order
}

// ---------------- knn1 v5: two-phase exact; pass-3 via value-threshold SET extraction ----------------
// 8 rows x 32 lanes, grid 2048. f0+ssq (384 KB) L2-resident.
// Pass 1: value-only exact 20th of sample [0,2048) -> per-row threshold T0.
// Pass 2: candidate-major; survivors (d <= T0) append INDEX to LDS (E=160, 10.6 sigma cap).
// Pass 3a: value-only network over survivors -> exact 20th-smallest T20.
// Pass 3b: set extraction: all d < T20 (<=19 by order-statistic), plus equals
//          (d == T20) filled by ASCENDING INDEX = jax's tie rule. The emitted
//          ORDER is arbitrary -- downstream (mlp1 max/min/sum over K) is
//          permutation-invariant. Selected SET is exactly jax's.
__global__ __launch_bounds__(256) void k_knn1(const float4* __restrict__ f0, const float* __restrict__ ssq,
                                              int* __restrict__ idx1) {
  __shared__ int survj[8][SCAP];
  __shared__ int scnt[8];
  __shared__ float rowT[8];
  __shared__ int outj[8][20];
  __shared__ int eqj[8][16];
  __shared__ int oc[8], ec[8];
  int t = threadIdx.x;
  int r = t >> 5;
  int lane = t & 31;
  int row = blockIdx.x*8 + r;
  if (t < 8) { scnt[t] = 0; oc[t] = 0; ec[t] = 0; }
  float4 fi = f0[row];
  float sqi = ssq[row];
  // ---- pass 1: value-only top-32 of sample [0,2048) -> T0
  {
    float rd[32];
    #pragma unroll
    for (int s = 0; s < 32; ++s) rd[s] = INFINITY;
    #pragma unroll
    for (int b = 0; b < 4; ++b) {
      float bd[16];
      #pragma unroll
      for (int u = 0; u < 16; ++u) {
        int j = b*512 + u*32 + lane;
        float4 c = f0[j];
        bd[u] = (sqi - 2.f*dot4f(fi, c)) + ssq[j];
      }
      vsort16(bd);
      vmerge16(rd, bd);
    }
    vmergelane(rd, 1); vmergelane(rd, 2); vmergelane(rd, 4);
    vmergelane(rd, 8); vmergelane(rd, 16);
    if (lane == 0) rowT[r] = rd[19];
  }
  __syncthreads();
  // ---- pass 2: candidate-major filter over all 16384
  {
    float4 fr[8]; float sr[8], Tr[8];
    #pragma unroll
    for (int q = 0; q < 8; ++q) {
      fr[q] = f0[blockIdx.x*8 + q];
      sr[q] = ssq[blockIdx.x*8 + q];
      Tr[q] = rowT[q];
    }
    #pragma unroll 4
    for (int k = 0; k < 64; ++k) {
      int j = k*256 + t;
      float4 c = f0[j];
      float cq = ssq[j];
      #pragma unroll
      for (int q = 0; q < 8; ++q) {
        float d = (sr[q] - 2.f*dot4f(fr[q], c)) + cq;
        if (d <= Tr[q]) {
          int slot = atomicAdd(&scnt[q], 1);
          if (slot < SCAP) survj[q][slot] = j;
        }
      }
    }
  }
  __syncthreads();
  int n = scnt[r] < SCAP ? scnt[r] : SCAP;
  // ---- pass 3a: recompute survivor d (bitwise-identical expr); value-only exact T20
  float sd[16]; int sj[16];
  #pragma unroll
  for (int u = 0; u < 16; ++u) {
    int s = u*32 + lane;
    if (s < n) {
      int j = survj[r][s];
      float4 c = f0[j];
      sd[u] = (sqi - 2.f*dot4f(fi, c)) + ssq[j];
      sj[u] = j;
    } else { sd[u] = INFINITY; sj[u] = 0; }
  }
  float T20;
  {
    float rd[32];
    #pragma unroll
    for (int s = 0; s < 32; ++s) rd[s] = INFINITY;
    float bd[16];
    #pragma unroll
    for (int u = 0; u < 16; ++u) bd[u] = sd[u];
    vsort16(bd);
    vmerge16(rd, bd);
    vmergelane(rd, 1); vmergelane(rd, 2); vmergelane(rd, 4);
    vmergelane(rd, 8); vmergelane(rd, 16);
    T20 = rd[19];                       // row-uniform after butterfly merges
  }
  // ---- pass 3b: set extraction (strict-less + ties by ascending index)
  #pragma unroll
  for (int u = 0; u < 16; ++u) {
    if (sd[u] < T20) {
      int pos = atomicAdd(&oc[r], 1);   // total strict-less <= 19 -> no overflow
      outj[r][pos] = sj[u];
    } else if (sd[u] == T20) {
      int pos = atomicAdd(&ec[r], 1);
      if (pos < 16) eqj[r][pos] = sj[u];
    }
  }
  __syncthreads();
  if (lane == 0) {
    int m = oc[r];
    int e = ec[r] < 16 ? ec[r] : 16;
    int need = 20 - m;                  // >= 1 (at least the 20th itself equals T20)
    for (int it = 0; it < need; ++it) { // pick ascending indices among equals (jax tie rule)
      int best = 0x7fffffff, bq = -1;
      for (int q = 0; q < e; ++q) {
        int v = eqj[r][q];
        if (v < best) { best = v; bq = q; }
      }
      if (bq < 0) break;                // unreachable (>=20 survivors have d<=T20)
      eqj[r][bq] = 0x7fffffff;
      outj[r][m + it] = best;
    }
    #pragma unroll
    for (int s = 0; s < KNB; ++s) idx1[row*KNB + s] = outj[r][s];
  }
}

// ---------------- mlp1: edge MLP 8->64, relu, per-point max/min (pre-BN), channel sums ----------------
__global__ __launch_bounds__(256) void k_mlp1(const float4* __restrict__ f0, const int* __restrict__ idx1,
                                              const float* __restrict__ w1, const float* __restrict__ b1,
                                              float* __restrict__ xmx, float* __restrict__ xmn,
                                              float* __restrict__ sums) {
  __shared__ float rs[256], rs2[256];
  int t = threadIdx.x;
  int c = t & 63;
  int w = t >> 6;
  float wc[8];
  #pragma unroll
  for (int d = 0; d < 8; ++d) wc[d] = w1[d*64 + c];
  float bc = b1[c];
  float s = 0.f, s2 = 0.f;
  for (int p = 0; p < 8; ++p) {
    int i = blockIdx.x*32 + p*4 + w;
    float4 fi = f0[i];
    float mx = -INFINITY, mn = INFINITY;
    #pragma unroll
    for (int k = 0; k < KNB; ++k) {
      int j = idx1[i*KNB + k];
      float4 fj = f0[j];
      float h = bc + fi.x*wc[0] + fi.y*wc[1] + fi.z*wc[2] + fi.w*wc[3]
                   + (fj.x-fi.x)*wc[4] + (fj.y-fi.y)*wc[5] + (fj.z-fi.z)*wc[6] + (fj.w-fi.w)*wc[7];
      h = fmaxf(h, 0.f);
      mx = fmaxf(mx, h); mn = fminf(mn, h);
      s += h; s2 += h*h;
    }
    xmx[i*64+c] = mx; xmn[i*64+c] = mn;
  }
  rs[t] = s; rs2[t] = s2;
  __syncthreads();
  if (t < 64) {
    atomicAdd(&sums[c],      rs[t]+rs[t+64]+rs[t+128]+rs[t+192]);
    atomicAdd(&sums[64+c],   rs2[t]+rs2[t+64]+rs2[t+128]+rs2[t+192]);
  }
}

// ---------------- bn1 apply: x1 = affine(max or min by scale sign) ----------------
__global__ __launch_bounds__(256) void k_bn1apply(const float* __restrict__ sums, const float* __restrict__ g,
                                                  const float* __restrict__ be, const float* __restrict__ xmx,
                                                  const float* __restrict__ xmn, float* __restrict__ x1) {
  __shared__ float sc_s[64], sh_s[64];
  int t = threadIdx.x;
  if (t < 64) {
    float m = sums[t] * (1.f/327680.f);
    float v = sums[64+t] * (1.f/327680.f) - m*m;
    float sc = g[t] / sqrtf(v + 1e-5f);
    sc_s[t] = sc; sh_s[t] = be[t] - m*sc;
  }
  __syncthreads();
  int c = t & 63;
  int i = blockIdx.x*4 + (t>>6);
  float sc = sc_s[c], sh = sh_s[c];
  float val = (sc >= 0.f) ? xmx[i*64+c] : xmn[i*64+c];
  x1[i*64+c] = sc*val + sh;
}

// ---------------- ssq1 (same dot64v ordering as knn2 for exact self-distance) ----------------
__global__ __launch_bounds__(256) void k_ssq1(const float* __restrict__ x1, float* __restrict__ ssq1) {
  int i = blockIdx.x*256 + threadIdx.x;
  alignas(16) float f[64];
  #pragma unroll
  for (int d4 = 0; d4 < 16; ++d4) ((float4*)f)[d4] = ((const float4*)x1)[i*16 + d4];
  ssq1[i] = dot64v(f, (const float4*)f);
}

// ---------------- knn2 (bitonic, measured-best): per-batch 2048-point 64-d knn ----------------
__global__ __launch_bounds__(256) void k_knn2(const float* __restrict__ x1, const float* __restrict__ ssq1,
                                              int* __restrict__ idx2) {
  __shared__ __align__(16) float tf[128][68];
  __shared__ float tq[128];
  int t = threadIdx.x;
  int row = blockIdx.x*32 + (t>>3);
  int lane = t & 7;
  int cbase = (row >> 11) << 11;                // batch column base
  alignas(16) float fi[64];
  #pragma unroll
  for (int d4 = 0; d4 < 16; ++d4) ((float4*)fi)[d4] = ((const float4*)x1)[row*16 + d4];
  float sqi = ssq1[row];
  float rd[32]; int ri[32];
  #pragma unroll
  for (int s = 0; s < 32; ++s) { rd[s] = INFINITY; ri[s] = 0; }
  for (int tile = 0; tile < 16; ++tile) {
    int base = cbase + tile*128;
    __syncthreads();
    for (int v = t; v < 128*16; v += 256) {
      int jl = v >> 4, d4 = v & 15;
      *(float4*)&tf[jl][d4*4] = ((const float4*)x1)[(base+jl)*16 + d4];
    }
    if (t < 128) tq[t] = ssq1[base + t];
    __syncthreads();
    float bd[16]; int bix[16];
    #pragma unroll
    for (int u = 0; u < 16; ++u) {
      int jl = u*8 + lane;
      bd[u] = (sqi - 2.f*dot64v(fi, (const float4*)&tf[jl][0])) + tq[jl];
      bix[u] = base + jl;
    }
    sort16(bd, bix);
    merge16(rd, ri, bd, bix);
  }
  mergelane(rd, ri, 1);
  mergelane(rd, ri, 2);
  mergelane(rd, ri, 4);
  if (lane == 0) {
    int4* p = (int4*)&idx2[row*KNB];
    p[0] = make_int4(ri[0],ri[1],ri[2],ri[3]);
    p[1] = make_int4(ri[4],ri[5],ri[6],ri[7]);
    p[2] = make_int4(ri[8],ri[9],ri[10],ri[11]);
    p[3] = make_int4(ri[12],ri[13],ri[14],ri[15]);
    p[4] = make_int4(ri[16],ri[17],ri[18],ri[19]);
  }
}

// ---------------- mlp2: edge MLP 128->128, shared-xi decomposition ----------------
__global__ __launch_bounds__(256) void k_mlp2(const float* __restrict__ x1, const int* __restrict__ idx2,
                                              const short* __restrict__ wtg, const float* __restrict__ w2,
                                              const float* __restrict__ b2,
                                              float* __restrict__ xmx, float* __restrict__ xmn,
                                              float* __restrict__ sums) {
  __shared__ __align__(16) short Elds[4*32*72];   // diffs only: [p][row][k<64], pitch 72
  __shared__ float xi_s[4][64];
  __shared__ float vi[4][128];
  __shared__ int js[4][KNB];
  int t = threadIdx.x;
  if (t < 4*KNB) js[t/KNB][t%KNB] = idx2[blockIdx.x*4*KNB + t];
  {
    int p = t >> 6, k = t & 63;
    xi_s[p][k] = x1[(blockIdx.x*4 + p)*64 + k];
  }
  __syncthreads();
  // vi[p][c] = b2[c] + sum_{k<64} xi[k]*w2[k][c]  (fp32 exact top-half + bias)
  #pragma unroll
  for (int v2 = 0; v2 < 2; ++v2) {
    int v = t + v2*256;
    int p = v >> 7, c = v & 127;
    float a = b2[c];
    #pragma unroll 8
    for (int k = 0; k < 64; ++k) a += xi_s[p][k] * w2[k*128 + c];
    vi[p][c] = a;
  }
  // stage E diffs (bf16): 4 pts x 32 rows x 8 chunks of 8
  #pragma unroll
  for (int cc = 0; cc < 4; ++cc) {
    int v = t + cc*256;
    int p  = v >> 8;
    int rr = (v >> 3) & 31;
    int kc = v & 7;
    short8 outv = {0,0,0,0,0,0,0,0};
    if (rr < KNB) {
      int j = js[p][rr];
      float4 j0 = ((const float4*)x1)[j*16 + kc*2];
      float4 j1 = ((const float4*)x1)[j*16 + kc*2 + 1];
      const float* xp = &xi_s[p][kc*8];
      outv[0]=f2bf(j0.x-xp[0]); outv[1]=f2bf(j0.y-xp[1]); outv[2]=f2bf(j0.z-xp[2]); outv[3]=f2bf(j0.w-xp[3]);
      outv[4]=f2bf(j1.x-xp[4]); outv[5]=f2bf(j1.y-xp[5]); outv[6]=f2bf(j1.z-xp[6]); outv[7]=f2bf(j1.w-xp[7]);
    }
    *(short8*)&Elds[p*2304 + rr*72 + kc*8] = outv;
  }
  __syncthreads();
  // compute: wave w owns cols [w*32, w*32+32); B-frags from global wtg (bottom half)
  int w = t >> 6, l = t & 63;
  int colA = w*32 + (l & 15);
  int colB = colA + 16;
  short8 bfr[2][2];
  #pragma unroll
  for (int n = 0; n < 2; ++n)
    #pragma unroll
    for (int kb = 0; kb < 2; ++kb) {
      int col = w*32 + n*16 + (l & 15);
      int k0 = 64 + kb*32 + (l >> 4)*8;
      bfr[n][kb] = *(const short8*)&wtg[col*128 + k0];
    }
  float sT0=0.f, qT0=0.f, sT1=0.f, qT1=0.f;
  #pragma unroll
  for (int p = 0; p < 4; ++p) {
    int i = blockIdx.x*4 + p;
    float vA = vi[p][colA], vB = vi[p][colB];
    float mx0=-INFINITY, mn0=INFINITY, s0=0.f, q0=0.f;
    float mx1=-INFINITY, mn1=INFINITY, s1=0.f, q1=0.f;
    #pragma unroll
    for (int m = 0; m < 2; ++m) {
      short8 af[2];
      #pragma unroll
      for (int kb = 0; kb < 2; ++kb) {
        int row = m*16 + (l & 15);
        int k0 = kb*32 + (l >> 4)*8;
        af[kb] = *(short8*)&Elds[p*2304 + row*72 + k0];
      }
      f32x4 acc0 = {vA, vA, vA, vA};
      f32x4 acc1 = {vB, vB, vB, vB};
      #pragma unroll
      for (int kb = 0; kb < 2; ++kb) {
        acc0 = __builtin_amdgcn_mfma_f32_16x16x32_bf16(af[kb], bfr[0][kb], acc0, 0, 0, 0);
        acc1 = __builtin_amdgcn_mfma_f32_16x16x32_bf16(af[kb], bfr[1][kb], acc1, 0, 0, 0);
      }
      int rbase = (l >> 4)*4 + m*16;
      #pragma unroll
      for (int reg = 0; reg < 4; ++reg) {
        bool valid = (rbase + reg) < KNB;
        float h0 = fmaxf(acc0[reg], 0.f);
        float h1 = fmaxf(acc1[reg], 0.f);
        if (valid) {
          mx0 = fmaxf(mx0, h0); mn0 = fminf(mn0, h0); s0 += h0; q0 += h0*h0;
          mx1 = fmaxf(mx1, h1); mn1 = fminf(mn1, h1); s1 += h1; q1 += h1*h1;
        }
      }
    }
    // butterfly over the 4 lane-groups sharing each col
    #pragma unroll
    for (int dlt = 16; dlt <= 32; dlt <<= 1) {
      mx0 = fmaxf(mx0, __shfl_xor(mx0, dlt)); mn0 = fminf(mn0, __shfl_xor(mn0, dlt));
      s0 += __shfl_xor(s0, dlt);              q0 += __shfl_xor(q0, dlt);
      mx1 = fmaxf(mx1, __shfl_xor(mx1, dlt)); mn1 = fminf(mn1, __shfl_xor(mn1, dlt));
      s1 += __shfl_xor(s1, dlt);              q1 += __shfl_xor(q1, dlt);
    }
    if (l < 16) {
      xmx[i*128 + colA] = mx0; xmx[i*128 + colB] = mx1;
      xmn[i*128 + colA] = mn0; xmn[i*128 + colB] = mn1;
    }
    sT0 += s0; qT0 += q0; sT1 += s1; qT1 += q1;
  }
  if (l < 16) {
    atomicAdd(&sums[colA], sT0);       atomicAdd(&sums[colB], sT1);
    atomicAdd(&sums[128 + colA], qT0); atomicAdd(&sums[128 + colB], qT1);
  }
}

// ---------------- bn2 apply ----------------
__global__ __launch_bounds__(256) void k_bn2apply(const float* __restrict__ sums, const float* __restrict__ g,
                                                  const float* __restrict__ be, const float* __restrict__ xmx,
                                                  const float* __restrict__ xmn, float* __restrict__ x2) {
  __shared__ float sc_s[128], sh_s[128];
  int t = threadIdx.x;
  if (t < 128) {
    float m = sums[t] * (1.f/327680.f);
    float v = sums[128+t] * (1.f/327680.f) - m*m;
    float sc = g[t] / sqrtf(v + 1e-5f);
    sc_s[t] = sc; sh_s[t] = be[t] - m*sc;
  }
  __syncthreads();
  int c = t & 127;
  int i = blockIdx.x*2 + (t>>7);
  float sc = sc_s[c], sh = sh_s[c];
  float val = (sc >= 0.f) ? xmx[i*128+c] : xmn[i*128+c];
  x2[i*128+c] = sc*val + sh;
}

// ---------------- gemmF: relu([x1|x2] @ wf + bf); channel sums + per-batch max/min only ----------------
__global__ __launch_bounds__(256) void k_gemmF(const float* __restrict__ x1, const float* __restrict__ x2,
                                               const float* __restrict__ wf, const float* __restrict__ bf,
                                               float* __restrict__ sumsF, unsigned* __restrict__ hpmx,
                                               unsigned* __restrict__ hpmn) {
  __shared__ float A_s[64*193];
  __shared__ __align__(16) float B_s[192*64];
  __shared__ float red[1024];
  int t = threadIdx.x;
  int rt = blockIdx.x >> 2;
  int ct = blockIdx.x & 3;
  for (int v = t; v < 64*48; v += 256) {
    int r = v / 48, gg = v - r*48;
    int row = rt*64 + r;
    float4 e = (gg < 16) ? ((const float4*)x1)[row*16 + gg]
                         : ((const float4*)x2)[row*32 + (gg-16)];
    float* p = &A_s[r*193 + gg*4];
    p[0]=e.x; p[1]=e.y; p[2]=e.z; p[3]=e.w;
  }
  for (int v = t; v < 192*16; v += 256) {
    int d = v >> 4, c4 = v & 15;
    *(float4*)&B_s[d*64 + c4*4] = ((const float4*)wf)[d*64 + ct*16 + c4];
  }
  __syncthreads();
  int rg = t & 15, cg = t >> 4;
  float acc[4][4];
  #pragma unroll
  for (int a=0;a<4;a++) { acc[a][0]=0.f; acc[a][1]=0.f; acc[a][2]=0.f; acc[a][3]=0.f; }
  for (int d = 0; d < 192; ++d) {
    float a0 = A_s[(rg*4+0)*193 + d];
    float a1 = A_s[(rg*4+1)*193 + d];
    float a2 = A_s[(rg*4+2)*193 + d];
    float a3 = A_s[(rg*4+3)*193 + d];
    float b0 = B_s[d*64 + cg];
    float b1 = B_s[d*64 + cg + 16];
    float b2 = B_s[d*64 + cg + 32];
    float b3 = B_s[d*64 + cg + 48];
    acc[0][0]+=a0*b0; acc[0][1]+=a0*b1; acc[0][2]+=a0*b2; acc[0][3]+=a0*b3;
    acc[1][0]+=a1*b0; acc[1][1]+=a1*b1; acc[1][2]+=a1*b2; acc[1][3]+=a1*b3;
    acc[2][0]+=a2*b0; acc[2][1]+=a2*b1; acc[2][2]+=a2*b2; acc[2][3]+=a2*b3;
    acc[3][0]+=a3*b0; acc[3][1]+=a3*b1; acc[3][2]+=a3*b2; acc[3][3]+=a3*b3;
  }
  float hv[4][4];
  #pragma unroll
  for (int ss=0; ss<4; ++ss) {
    float bb = bf[ct*64 + cg + ss*16];
    #pragma unroll
    for (int rr=0; rr<4; ++rr) hv[rr][ss] = fmaxf(acc[rr][ss] + bb, 0.f);
  }
  int b = rt >> 5;
  #pragma unroll
  for (int ss=0; ss<4; ++ss) red[rg*64 + cg + ss*16] = hv[0][ss]+hv[1][ss]+hv[2][ss]+hv[3][ss];
  __syncthreads();
  if (t < 64) {
    float v = 0.f;
    #pragma unroll
    for (int r=0;r<16;r++) v += red[r*64 + t];
    atomicAdd(&sumsF[ct*64 + t], v);
  }
  __syncthreads();
  #pragma unroll
  for (int ss=0; ss<4; ++ss) red[rg*64 + cg + ss*16] =
      hv[0][ss]*hv[0][ss]+hv[1][ss]*hv[1][ss]+hv[2][ss]*hv[2][ss]+hv[3][ss]*hv[3][ss];
  __syncthreads();
  if (t < 64) {
    float v = 0.f;
    #pragma unroll
    for (int r=0;r<16;r++) v += red[r*64 + t];
    atomicAdd(&sumsF[256 + ct*64 + t], v);
  }
  __syncthreads();
  #pragma unroll
  for (int ss=0; ss<4; ++ss) red[rg*64 + cg + ss*16] =
      fmaxf(fmaxf(hv[0][ss],hv[1][ss]), fmaxf(hv[2][ss],hv[3][ss]));
  __syncthreads();
  if (t < 64) {
    float v = -INFINITY;
    #pragma unroll
    for (int r=0;r<16;r++) v = fmaxf(v, red[r*64 + t]);
    atomicMax(&hpmx[b*256 + ct*64 + t], __float_as_uint(v));
  }
  __syncthreads();
  #pragma unroll
  for (int ss=0; ss<4; ++ss) red[rg*64 + cg + ss*16] =
      fminf(fminf(hv[0][ss],hv[1][ss]), fminf(hv[2][ss],hv[3][ss]));
  __syncthreads();
  if (t < 64) {
    float v = INFINITY;
    #pragma unroll
    for (int r=0;r<16;r++) v = fminf(v, red[r*64 + t]);
    atomicMin(&hpmn[b*256 + ct*64 + t], __float_as_uint(v));
  }
}

// ---------------- head ----------------
__global__ __launch_bounds__(256) void k_head(const float* __restrict__ sumsF, const float* __restrict__ gf,
                                              const float* __restrict__ bef,
                                              const unsigned* __restrict__ hpmx, const unsigned* __restrict__ hpmn,
                                              const float* __restrict__ wo1, const float* __restrict__ bo1,
                                              const float* __restrict__ go1, const float* __restrict__ beo1,
                                              const float* __restrict__ wo2, const float* __restrict__ bo2,
                                              const float* __restrict__ go2, const float* __restrict__ beo2,
                                              const float* __restrict__ wo3, const float* __restrict__ bo3,
                                              float* __restrict__ out) {
  __shared__ float hp[8][256];
  __shared__ float u1[8][128];
  __shared__ float u2[8][64];
  __shared__ float lg[8][16];
  int t = threadIdx.x;
  {
    float m = sumsF[t] * (1.f/16384.f);
    float v = sumsF[256+t] * (1.f/16384.f) - m*m;
    float sc = gf[t] / sqrtf(v + 1e-5f);
    float sh = bef[t] - m*sc;
    for (int b = 0; b < 8; ++b) {
      unsigned bits = (sc >= 0.f) ? hpmx[b*256+t] : hpmn[b*256+t];
      hp[b][t] = sc*__uint_as_float(bits) + sh;
    }
  }
  __syncthreads();
  for (int p = t; p < 1024; p += 256) {
    int b = p >> 7, c = p & 127;
    float z = bo1[c];
    for (int d = 0; d < 256; ++d) z += hp[b][d]*wo1[d*128+c];
    u1[b][c] = fmaxf(z, 0.f);
  }
  __syncthreads();
  if (t < 128) {
    float m = 0.f;
    for (int b=0;b<8;b++) m += u1[b][t];
    m *= 0.125f;
    float v = 0.f;
    for (int b=0;b<8;b++) { float dd = u1[b][t]-m; v += dd*dd; }
    v *= 0.125f;
    float sc = go1[t]/sqrtf(v+1e-5f), sh = beo1[t]-m*sc;
    for (int b=0;b<8;b++) u1[b][t] = sc*u1[b][t]+sh;
  }
  __syncthreads();
  for (int p = t; p < 512; p += 256) {
    int b = p >> 6, c = p & 63;
    float z = bo2[c];
    for (int d = 0; d < 128; ++d) z += u1[b][d]*wo2[d*64+c];
    u2[b][c] = fmaxf(z, 0.f);
  }
  __syncthreads();
  if (t < 64) {
    float m = 0.f;
    for (int b=0;b<8;b++) m += u2[b][t];
    m *= 0.125f;
    float v = 0.f;
    for (int b=0;b<8;b++) { float dd = u2[b][t]-m; v += dd*dd; }
    v *= 0.125f;
    float sc = go2[t]/sqrtf(v+1e-5f), sh = beo2[t]-m*sc;
    for (int b=0;b<8;b++) u2[b][t] = sc*u2[b][t]+sh;
  }
  __syncthreads();
  if (t < 128) {
    int b = t >> 4, c = t & 15;
    float z = bo3[c];
    for (int d = 0; d < 64; ++d) z += u2[b][d]*wo3[d*16+c];
    lg[b][c] = z;
  }
  __syncthreads();
  if (t < 8) {
    float m = -INFINITY;
    for (int j=0;j<16;j++) m = fmaxf(m, lg[t][j]);
    float s = 0.f;
    for (int j=0;j<16;j++) s += expf(lg[t][j]-m);
    float ls = logf(s);
    for (int j=0;j<16;j++) out[t*16+j] = (lg[t][j]-m) - ls;
  }
}

// ---------------- launch ----------------
extern "C" void kernel_launch(void* const* d_in, const int* in_sizes, int n_in,
                              void* d_out, int out_size, void* d_ws, size_t ws_size,
                              hipStream_t stream) {
  (void)in_sizes; (void)n_in; (void)out_size; (void)ws_size;
  const float* pos = (const float*)d_in[0];
  const float* x   = (const float*)d_in[1];
  const float* w1  = (const float*)d_in[3];
  const float* b1  = (const float*)d_in[4];
  const float* g1  = (const float*)d_in[5];
  const float* be1 = (const float*)d_in[6];
  const float* w2  = (const float*)d_in[7];
  const float* b2  = (const float*)d_in[8];
  const float* g2  = (const float*)d_in[9];
  const float* be2 = (const float*)d_in[10];
  const float* wf  = (const float*)d_in[11];
  const float* bf  = (const float*)d_in[12];
  const float* gf  = (const float*)d_in[13];
  const float* bef = (const float*)d_in[14];
  const float* wo1 = (const float*)d_in[15];
  const float* bo1 = (const float*)d_in[16];
  const float* go1 = (const float*)d_in[17];
  const float* beo1= (const float*)d_in[18];
  const float* wo2 = (const float*)d_in[19];
  const float* bo2 = (const float*)d_in[20];
  const float* go2 = (const float*)d_in[21];
  const float* beo2= (const float*)d_in[22];
  const float* wo3 = (const float*)d_in[23];
  const float* bo3 = (const float*)d_in[24];

  char* ws = (char*)d_ws;
  float4*   f0    = (float4*)  (ws + OFF_F0);
  float*    ssq0  = (float*)   (ws + OFF_SSQ0);
  int*      idx1  = (int*)     (ws + OFF_IDX1);
  float*    xmx1  = (float*)   (ws + OFF_XMX1);
  float*    xmn1  = (float*)   (ws + OFF_XMN1);
  float*    sum1  = (float*)   (ws + OFF_SUM1);
  float*    x1    = (float*)   (ws + OFF_X1);
  float*    ssq1  = (float*)   (ws + OFF_SSQ1);
  int*      idx2  = (int*)     (ws + OFF_IDX2);
  float*    xmx2  = (float*)   (ws + OFF_XMX2);
  float*    xmn2  = (float*)   (ws + OFF_XMN2);
  float*    sum2  = (float*)   (ws + OFF_SUM2);
  float*    x2    = (float*)   (ws + OFF_X2);
  float*    sumF  = (float*)   (ws + OFF_SUMF);
  unsigned* hpmx  = (unsigned*)(ws + OFF_HPMX);
  unsigned* hpmn  = (unsigned*)(ws + OFF_HPMN);
  short*    wtg   = (short*)   (ws + OFF_X2);    // aliases x2 head (x2 dead until bn2apply)

  k_init    <<<64,   256, 0, stream>>>(pos, x, w2, f0, ssq0, wtg, sum1, sum2, sumF, hpmx, hpmn);
  k_knn1    <<<2048, 256, 0, stream>>>(f0, ssq0, idx1);
  k_mlp1    <<<512,  256, 0, stream>>>(f0, idx1, w1, b1, xmx1, xmn1, sum1);
  k_bn1apply<<<4096, 256, 0, stream>>>(sum1, g1, be1, xmx1, xmn1, x1);
  k_ssq1    <<<64,   256, 0, stream>>>(x1, ssq1);
  k_knn2    <<<512,  256, 0, stream>>>(x1, ssq1, idx2);
  k_mlp2    <<<4096, 256, 0, stream>>>(x1, idx2, wtg, w2, b2, xmx2, xmn2, sum2);
  k_bn2apply<<<8192, 256, 0, stream>>>(sum2, g2, be2, xmx2, xmn2, x2);
  k_gemmF   <<<1024, 256, 0, stream>>>(x1, x2, wf, bf, sumF, hpmx, hpmn);
  k_head    <<<1,    256, 0, stream>>>(sumF, gf, bef, hpmx, hpmn,
                                       wo1, bo1, go1, beo1, wo2, bo2, go2, beo2, wo3, bo3,
                                       (float*)d_out);
}

// Round 15
// 599.043 us; speedup vs baseline: 1.3940x; 1.0085x over previous
//
#include <hip/hip_runtime.h>
#include <math.h>

#define NPTS 16384
#define KNB 20
#define SCAP 512
#define SCAP2 352

typedef __attribute__((ext_vector_type(8))) short short8;
typedef __attribute__((ext_vector_type(4))) float f32x4;

// ---------------- workspace layout (bytes, all naturally 256-aligned) ----------------
static const size_t OFF_F0   = 0;                                   // N x float4
static const size_t OFF_SSQ0 = OFF_F0   + (size_t)NPTS*4*4;         // N f32
static const size_t OFF_IDX1 = OFF_SSQ0 + (size_t)NPTS*4;           // N*20 i32
static const size_t OFF_XMX1 = OFF_IDX1 + (size_t)NPTS*KNB*4;       // N*64 f32
static const size_t OFF_XMN1 = OFF_XMX1 + (size_t)NPTS*64*4;        // N*64 f32
static const size_t OFF_SUM1 = OFF_XMN1 + (size_t)NPTS*64*4;        // 128 f32 (sum,sumsq)
static const size_t OFF_X1   = OFF_SUM1 + 512;                      // N*64 f32
static const size_t OFF_SSQ1 = OFF_X1   + (size_t)NPTS*64*4;        // N f32
static const size_t OFF_IDX2 = OFF_SSQ1 + (size_t)NPTS*4;           // N*20 i32 (global idx)
static const size_t OFF_XMX2 = OFF_IDX2 + (size_t)NPTS*KNB*4;       // N*128 f32
static const size_t OFF_XMN2 = OFF_XMX2 + (size_t)NPTS*128*4;       // N*128 f32
static const size_t OFF_SUM2 = OFF_XMN2 + (size_t)NPTS*128*4;       // 256 f32
static const size_t OFF_X2   = OFF_SUM2 + 1024;                     // N*128 f32
static const size_t OFF_SUMF = OFF_X2   + (size_t)NPTS*128*4;       // 512 f32
static const size_t OFF_HPMX = OFF_SUMF + 2048;                     // 8*256 u32 (float bits)
static const size_t OFF_HPMN = OFF_HPMX + 8*256*4;                  // 8*256 u32
// WT_g (bf16 W^T for mlp2, 32 KB) ALIASES x2 head (x2 dead until bn2apply).
// rowTg (f32 thresholds for knn2, 64 KB) ALIASES xmx1 (dead after bn1apply).

// ---------------- helpers ----------------
__device__ __forceinline__ float dot4f(float4 a, float4 b) {
  return a.x*b.x + a.y*b.y + a.z*b.z + a.w*b.w;
}

__device__ __forceinline__ float dot64v(const float* a, const float4* b4) {
  float s = 0.f;
  #pragma unroll
  for (int d4 = 0; d4 < 16; ++d4) {
    float4 b = b4[d4];
    s += a[4*d4+0]*b.x + a[4*d4+1]*b.y + a[4*d4+2]*b.z + a[4*d4+3]*b.w;
  }
  return s;
}

// f32 -> bf16 (RNE)
__device__ __forceinline__ short f2bf(float x) {
  union { float f; unsigned u; } v; v.f = x;
  unsigned r = (v.u + 0x7FFFu + ((v.u >> 16) & 1u)) >> 16;
  return (short)r;
}

// ---------------- branch-free sorting-network top-k machinery (with indices) ----------------
__device__ __forceinline__ void ce(float& a, int& ai, float& b, int& bi) {
  bool sw = b < a;
  float d0 = sw ? b : a;  float d1 = sw ? a : b;
  int   j0 = sw ? bi : ai; int  j1 = sw ? ai : bi;
  a = d0; ai = j0; b = d1; bi = j1;
}

__device__ __forceinline__ void sort16(float (&d)[16], int (&ix)[16]) {
  #pragma unroll
  for (int k = 2; k <= 16; k <<= 1) {
    #pragma unroll
    for (int j = k >> 1; j > 0; j >>= 1) {
      #pragma unroll
      for (int i = 0; i < 16; ++i) {
        int l = i ^ j;
        if (l > i) {
          if ((i & k) == 0) ce(d[i], ix[i], d[l], ix[l]);
          else              ce(d[l], ix[l], d[i], ix[i]);
        }
      }
    }
  }
}

__device__ __forceinline__ void bimerge32(float (&rd)[32], int (&ri)[32]) {
  #pragma unroll
  for (int j = 16; j > 0; j >>= 1) {
    #pragma unroll
    for (int i = 0; i < 32; ++i) {
      int l = i ^ j;
      if (l > i) ce(rd[i], ri[i], rd[l], ri[l]);
    }
  }
}

__device__ __forceinline__ void merge16(float (&rd)[32], int (&ri)[32],
                                        float (&bd)[16], int (&bi)[16]) {
  #pragma unroll
  for (int k = 0; k < 16; ++k) {
    bool sw = bd[15-k] < rd[16+k];
    rd[16+k] = sw ? bd[15-k] : rd[16+k];
    ri[16+k] = sw ? bi[15-k] : ri[16+k];
  }
  bimerge32(rd, ri);
}

__device__ __forceinline__ void mergelane(float (&rd)[32], int (&ri)[32], int mask) {
  float pd[32]; int pi[32];
  #pragma unroll
  for (int s = 0; s < 32; ++s) { pd[s] = __shfl_xor(rd[s], mask); pi[s] = __shfl_xor(ri[s], mask); }
  #pragma unroll
  for (int k = 0; k < 32; ++k) {
    bool sw = pd[31-k] < rd[k];
    rd[k] = sw ? pd[31-k] : rd[k];
    ri[k] = sw ? pi[31-k] : ri[k];
  }
  bimerge32(rd, ri);
}

// ---------------- value-only versions (threshold computation, 2 ops/CE) ----------------
__device__ __forceinline__ void vce(float& a, float& b) {
  float lo = fminf(a, b);
  b = fmaxf(a, b);
  a = lo;
}

__device__ __forceinline__ void vsort16(float (&d)[16]) {
  #pragma unroll
  for (int k = 2; k <= 16; k <<= 1) {
    #pragma unroll
    for (int j = k >> 1; j > 0; j >>= 1) {
      #pragma unroll
      for (int i = 0; i < 16; ++i) {
        int l = i ^ j;
        if (l > i) {
          if ((i & k) == 0) vce(d[i], d[l]);
          else              vce(d[l], d[i]);
        }
      }
    }
  }
}

__device__ __forceinline__ void vbimerge32(float (&rd)[32]) {
  #pragma unroll
  for (int j = 16; j > 0; j >>= 1) {
    #pragma unroll
    for (int i = 0; i < 32; ++i) {
      int l = i ^ j;
      if (l > i) vce(rd[i], rd[l]);
    }
  }
}

__device__ __forceinline__ void vmerge16(float (&rd)[32], float (&bd)[16]) {
  #pragma unroll
  for (int k = 0; k < 16; ++k) rd[16+k] = fminf(rd[16+k], bd[15-k]);
  vbimerge32(rd);
}

__device__ __forceinline__ void vmergelane(float (&rd)[32], int mask) {
  float pd[32];
  #pragma unroll
  for (int s = 0; s < 32; ++s) pd[s] = __shfl_xor(rd[s], mask);
  #pragma unroll
  for (int k = 0; k < 32; ++k) rd[k] = fminf(rd[k], pd[31-k]);
  vbimerge32(rd);
}

// ---------------- init + f0 + wprep fused (grid 64; accumulators reset EVERY launch) ----------------
__global__ __launch_bounds__(256) void k_init(const float* __restrict__ pos, const float* __restrict__ x,
                                              const float* __restrict__ w2,
                                              float4* __restrict__ f0, float* __restrict__ ssq,
                                              short* __restrict__ wtg,
                                              float* sum1, float* sum2, float* sumF,
                                              unsigned* hpmx, unsigned* hpmn) {
  int gt = blockIdx.x*256 + threadIdx.x;   // 0..16383
  float4 f;
  f.x = pos[3*gt+0]; f.y = pos[3*gt+1]; f.z = pos[3*gt+2]; f.w = x[gt];
  f0[gt] = f;
  ssq[gt] = dot4f(f, f);
  { int c = gt >> 7, k = gt & 127; wtg[c*128 + k] = f2bf(w2[k*128 + c]); }
  if (gt < 128) sum1[gt] = 0.f;
  if (gt < 256) sum2[gt] = 0.f;
  if (gt < 512) sumF[gt] = 0.f;
  if (gt < 2048) { hpmx[gt] = 0u; hpmn[gt] = 0x7f800000u; }   // relu>=0 -> uint order == float order
}

// ---------------- knn1 v5: two-phase exact; pass-3 via value-threshold SET extraction ----------------
__global__ __launch_bounds__(256) void k_knn1(const float4* __restrict__ f0, const float* __restrict__ ssq,
                                              int* __restrict__ idx1) {
  __shared__ int survj[8][SCAP];
  __shared__ int scnt[8];
  __shared__ float rowT[8];
  __shared__ int outj[8][20];
  __shared__ int eqj[8][16];
  __shared__ int oc[8], ec[8];
  int t = threadIdx.x;
  int r = t >> 5;
  int lane = t & 31;
  int row = blockIdx.x*8 + r;
  if (t < 8) { scnt[t] = 0; oc[t] = 0; ec[t] = 0; }
  float4 fi = f0[row];
  float sqi = ssq[row];
  // ---- pass 1: value-only top-32 of sample [0,2048) -> T0
  {
    float rd[32];
    #pragma unroll
    for (int s = 0; s < 32; ++s) rd[s] = INFINITY;
    #pragma unroll
    for (int b = 0; b < 4; ++b) {
      float bd[16];
      #pragma unroll
      for (int u = 0; u < 16; ++u) {
        int j = b*512 + u*32 + lane;
        float4 c = f0[j];
        bd[u] = (sqi - 2.f*dot4f(fi, c)) + ssq[j];
      }
      vsort16(bd);
      vmerge16(rd, bd);
    }
    vmergelane(rd, 1); vmergelane(rd, 2); vmergelane(rd, 4);
    vmergelane(rd, 8); vmergelane(rd, 16);
    if (lane == 0) rowT[r] = rd[19];
  }
  __syncthreads();
  // ---- pass 2: candidate-major filter over all 16384
  {
    float4 fr[8]; float sr[8], Tr[8];
    #pragma unroll
    for (int q = 0; q < 8; ++q) {
      fr[q] = f0[blockIdx.x*8 + q];
      sr[q] = ssq[blockIdx.x*8 + q];
      Tr[q] = rowT[q];
    }
    #pragma unroll 4
    for (int k = 0; k < 64; ++k) {
      int j = k*256 + t;
      float4 c = f0[j];
      float cq = ssq[j];
      #pragma unroll
      for (int q = 0; q < 8; ++q) {
        float d = (sr[q] - 2.f*dot4f(fr[q], c)) + cq;
        if (d <= Tr[q]) {
          int slot = atomicAdd(&scnt[q], 1);
          if (slot < SCAP) survj[q][slot] = j;
        }
      }
    }
  }
  __syncthreads();
  int n = scnt[r] < SCAP ? scnt[r] : SCAP;
  // ---- pass 3a: recompute survivor d (bitwise-identical expr); value-only exact T20
  float sd[16]; int sj[16];
  #pragma unroll
  for (int u = 0; u < 16; ++u) {
    int s = u*32 + lane;
    if (s < n) {
      int j = survj[r][s];
      float4 c = f0[j];
      sd[u] = (sqi - 2.f*dot4f(fi, c)) + ssq[j];
      sj[u] = j;
    } else { sd[u] = INFINITY; sj[u] = 0; }
  }
  float T20;
  {
    float rd[32];
    #pragma unroll
    for (int s = 0; s < 32; ++s) rd[s] = INFINITY;
    float bd[16];
    #pragma unroll
    for (int u = 0; u < 16; ++u) bd[u] = sd[u];
    vsort16(bd);
    vmerge16(rd, bd);
    vmergelane(rd, 1); vmergelane(rd, 2); vmergelane(rd, 4);
    vmergelane(rd, 8); vmergelane(rd, 16);
    T20 = rd[19];                       // row-uniform after butterfly merges
  }
  // ---- pass 3b: set extraction (strict-less + ties by ascending index)
  #pragma unroll
  for (int u = 0; u < 16; ++u) {
    if (sd[u] < T20) {
      int pos = atomicAdd(&oc[r], 1);   // total strict-less <= 19 -> no overflow
      outj[r][pos] = sj[u];
    } else if (sd[u] == T20) {
      int pos = atomicAdd(&ec[r], 1);
      if (pos < 16) eqj[r][pos] = sj[u];
    }
  }
  __syncthreads();
  if (lane == 0) {
    int m = oc[r];
    int e = ec[r] < 16 ? ec[r] : 16;
    int need = 20 - m;                  // >= 1 (at least the 20th itself equals T20)
    for (int it = 0; it < need; ++it) { // pick ascending indices among equals (jax tie rule)
      int best = 0x7fffffff, bq = -1;
      for (int q = 0; q < e; ++q) {
        int v = eqj[r][q];
        if (v < best) { best = v; bq = q; }
      }
      if (bq < 0) break;                // unreachable (>=20 survivors have d<=T20)
      eqj[r][bq] = 0x7fffffff;
      outj[r][m + it] = best;
    }
    #pragma unroll
    for (int s = 0; s < KNB; ++s) idx1[row*KNB + s] = outj[r][s];
  }
}

// ---------------- mlp1: edge MLP 8->64, relu, per-point max/min (pre-BN), channel sums ----------------
__global__ __launch_bounds__(256) void k_mlp1(const float4* __restrict__ f0, const int* __restrict__ idx1,
                                              const float* __restrict__ w1, const float* __restrict__ b1,
                                              float* __restrict__ xmx, float* __restrict__ xmn,
                                              float* __restrict__ sums) {
  __shared__ float rs[256], rs2[256];
  int t = threadIdx.x;
  int c = t & 63;
  int w = t >> 6;
  float wc[8];
  #pragma unroll
  for (int d = 0; d < 8; ++d) wc[d] = w1[d*64 + c];
  float bc = b1[c];
  float s = 0.f, s2 = 0.f;
  for (int p = 0; p < 8; ++p) {
    int i = blockIdx.x*32 + p*4 + w;
    float4 fi = f0[i];
    float mx = -INFINITY, mn = INFINITY;
    #pragma unroll
    for (int k = 0; k < KNB; ++k) {
      int j = idx1[i*KNB + k];
      float4 fj = f0[j];
      float h = bc + fi.x*wc[0] + fi.y*wc[1] + fi.z*wc[2] + fi.w*wc[3]
                   + (fj.x-fi.x)*wc[4] + (fj.y-fi.y)*wc[5] + (fj.z-fi.z)*wc[6] + (fj.w-fi.w)*wc[7];
      h = fmaxf(h, 0.f);
      mx = fmaxf(mx, h); mn = fminf(mn, h);
      s += h; s2 += h*h;
    }
    xmx[i*64+c] = mx; xmn[i*64+c] = mn;
  }
  rs[t] = s; rs2[t] = s2;
  __syncthreads();
  if (t < 64) {
    atomicAdd(&sums[c],      rs[t]+rs[t+64]+rs[t+128]+rs[t+192]);
    atomicAdd(&sums[64+c],   rs2[t]+rs2[t+64]+rs2[t+128]+rs2[t+192]);
  }
}

// ---------------- bn1 apply: x1 = affine(max or min by scale sign) ----------------
__global__ __launch_bounds__(256) void k_bn1apply(const float* __restrict__ sums, const float* __restrict__ g,
                                                  const float* __restrict__ be, const float* __restrict__ xmx,
                                                  const float* __restrict__ xmn, float* __restrict__ x1) {
  __shared__ float sc_s[64], sh_s[64];
  int t = threadIdx.x;
  if (t < 64) {
    float m = sums[t] * (1.f/327680.f);
    float v = sums[64+t] * (1.f/327680.f) - m*m;
    float sc = g[t] / sqrtf(v + 1e-5f);
    sc_s[t] = sc; sh_s[t] = be[t] - m*sc;
  }
  __syncthreads();
  int c = t & 63;
  int i = blockIdx.x*4 + (t>>6);
  float sc = sc_s[c], sh = sh_s[c];
  float val = (sc >= 0.f) ? xmx[i*64+c] : xmn[i*64+c];
  x1[i*64+c] = sc*val + sh;
}

// ---------------- ssq1 (same dot64v ordering as knn2 phase-3 for exact self-distance) ----------------
__global__ __launch_bounds__(256) void k_ssq1(const float* __restrict__ x1, float* __restrict__ ssq1) {
  int i = blockIdx.x*256 + threadIdx.x;
  alignas(16) float f[64];
  #pragma unroll
  for (int d4 = 0; d4 < 16; ++d4) ((float4*)f)[d4] = ((const float4*)x1)[i*16 + d4];
  ssq1[i] = dot64v(f, (const float4*)f);
}

// ---------------- k_thresh: exact fp32 per-row threshold from sample-256 (value-only bitonic) ----------------
// Proven structure (trimmed bitonic knn2): 32 rows x 8 lanes, 2 tiles of 128.
// rowTg[row] = exact 20th-smallest distance within [cbase, cbase+256).
__global__ __launch_bounds__(256) void k_thresh(const float* __restrict__ x1, const float* __restrict__ ssq1,
                                                float* __restrict__ rowTg) {
  __shared__ __align__(16) float tf[128][68];
  __shared__ float tq[128];
  int t = threadIdx.x;
  int row = blockIdx.x*32 + (t>>3);
  int lane = t & 7;
  int cbase = (row >> 11) << 11;
  alignas(16) float fi[64];
  #pragma unroll
  for (int d4 = 0; d4 < 16; ++d4) ((float4*)fi)[d4] = ((const float4*)x1)[row*16 + d4];
  float sqi = ssq1[row];
  float rd[32];
  #pragma unroll
  for (int s = 0; s < 32; ++s) rd[s] = INFINITY;
  for (int tile = 0; tile < 2; ++tile) {
    int base = cbase + tile*128;
    __syncthreads();
    for (int v = t; v < 128*16; v += 256) {
      int jl = v >> 4, d4 = v & 15;
      *(float4*)&tf[jl][d4*4] = ((const float4*)x1)[(base+jl)*16 + d4];
    }
    if (t < 128) tq[t] = ssq1[base + t];
    __syncthreads();
    float bd[16];
    #pragma unroll
    for (int u = 0; u < 16; ++u) {
      int jl = u*8 + lane;
      bd[u] = (sqi - 2.f*dot64v(fi, (const float4*)&tf[jl][0])) + tq[jl];
    }
    vsort16(bd);
    vmerge16(rd, bd);
  }
  vmergelane(rd, 1); vmergelane(rd, 2); vmergelane(rd, 4);
  if (lane == 0) rowTg[row] = rd[19];
}

// ---------------- knn2 v4: MFMA-filtered exact, 32 rows/block, external thresholds ----------------
// Fixes vs R11/R12: (1) no serial fp32 phase-1 (k_thresh precomputes rowTg);
// (2) 32 rows share each staged B-tile (compute/staging ratio ~3x R12);
// (3) phase-3 = knn1-v5 set-extraction, distances kept in regs, ILP dots.
// Accept: dhat <= rowT + 2^-7(sa+sb) >= 3.9x provable bf16 error -> survivors
// PROVABLY contain true top-20; exact fp32 recompute; jax tie rule. EXACT set.
__global__ __launch_bounds__(256) void k_knn2(const float* __restrict__ x1, const float* __restrict__ ssq1,
                                              const float* __restrict__ rowTg, int* __restrict__ idx2) {
  __shared__ __align__(16) short Abf[32*72];
  __shared__ __align__(16) short Bbf[128*72];
  __shared__ float sqA[32], rowTs[32];
  __shared__ float sqB[128];
  __shared__ unsigned short surv[32][SCAP2];
  __shared__ int scnt[32];
  __shared__ int eqj[32][16];
  __shared__ int oc[32], ec[32];
  int t = threadIdx.x;
  int b = blockIdx.x >> 6;
  int rg = blockIdx.x & 63;
  int cbase = b*2048;
  int row0 = cbase + rg*32;
  if (t < 32) { scnt[t] = 0; oc[t] = 0; ec[t] = 0; sqA[t] = ssq1[row0 + t]; rowTs[t] = rowTg[row0 + t]; }
  // stage A (32 rows x 8 kc = 256 threads exactly)
  {
    int rr = t >> 3, kc = t & 7;
    float4 a0 = ((const float4*)x1)[(row0+rr)*16 + kc*2];
    float4 a1 = ((const float4*)x1)[(row0+rr)*16 + kc*2 + 1];
    short8 o;
    o[0]=f2bf(a0.x); o[1]=f2bf(a0.y); o[2]=f2bf(a0.z); o[3]=f2bf(a0.w);
    o[4]=f2bf(a1.x); o[5]=f2bf(a1.y); o[6]=f2bf(a1.z); o[7]=f2bf(a1.w);
    *(short8*)&Abf[rr*72 + kc*8] = o;
  }
  __syncthreads();
  int w = t >> 6, l = t & 63;
  int s = w & 1;                         // row strip: rows s*16..s*16+15
  int h = w >> 1;                        // col half: cands h*64..h*64+63 per tile
  short8 af[2];
  #pragma unroll
  for (int kb = 0; kb < 2; ++kb)
    af[kb] = *(short8*)&Abf[(s*16 + (l & 15))*72 + kb*32 + (l >> 4)*8];
  for (int ct = 0; ct < 16; ++ct) {
    int cb = ct*128;
    __syncthreads();                     // protect Bbf/sqB reuse
    #pragma unroll
    for (int cc = 0; cc < 4; ++cc) {
      int v = t + cc*256;
      int rr = v >> 3, kc = v & 7;
      int j = cbase + cb + rr;
      float4 a0 = ((const float4*)x1)[j*16 + kc*2];
      float4 a1 = ((const float4*)x1)[j*16 + kc*2 + 1];
      short8 o;
      o[0]=f2bf(a0.x); o[1]=f2bf(a0.y); o[2]=f2bf(a0.z); o[3]=f2bf(a0.w);
      o[4]=f2bf(a1.x); o[5]=f2bf(a1.y); o[6]=f2bf(a1.z); o[7]=f2bf(a1.w);
      *(short8*)&Bbf[rr*72 + kc*8] = o;
      if (kc == 0) sqB[rr] = ssq1[j];
    }
    __syncthreads();
    #pragma unroll
    for (int cs = 0; cs < 4; ++cs) {
      int c16 = h*64 + cs*16;
      short8 bfr[2];
      #pragma unroll
      for (int kb = 0; kb < 2; ++kb)
        bfr[kb] = *(short8*)&Bbf[(c16 + (l & 15))*72 + kb*32 + (l >> 4)*8];
      int jcol = c16 + (l & 15);
      float sb = sqB[jcol];
      f32x4 acc = {0.f, 0.f, 0.f, 0.f};
      acc = __builtin_amdgcn_mfma_f32_16x16x32_bf16(af[0], bfr[0], acc, 0, 0, 0);
      acc = __builtin_amdgcn_mfma_f32_16x16x32_bf16(af[1], bfr[1], acc, 0, 0, 0);
      #pragma unroll
      for (int reg = 0; reg < 4; ++reg) {
        int il = s*16 + (l >> 4)*4 + reg;
        float sa = sqA[il];
        float dh = (sa - 2.f*acc[reg]) + sb;
        if (dh <= rowTs[il] + 0.0078125f*(sa + sb)) {
          int slot = atomicAdd(&scnt[il], 1);
          if (slot < SCAP2) surv[il][slot] = (unsigned short)(cb + jcol);
        }
      }
    }
  }
  __syncthreads();
  // ---- phase 3: exact fp32 recompute + set extraction; 32 rows x 8 lanes
  {
    int r = t >> 3, lane = t & 7;
    int row = row0 + r;
    int n = scnt[r] < SCAP2 ? scnt[r] : SCAP2;
    alignas(16) float fi[64];
    #pragma unroll
    for (int d4 = 0; d4 < 16; ++d4) ((float4*)fi)[d4] = ((const float4*)x1)[row*16 + d4];
    float sqi = ssq1[row];
    float sd[3][16];
    #pragma unroll
    for (int g = 0; g < 3; ++g) {
      #pragma unroll
      for (int u = 0; u < 16; ++u) {
        int slot = (g*16 + u)*8 + lane;
        if (slot < n) {
          int j = cbase + (int)surv[r][slot];
          sd[g][u] = (sqi - 2.f*dot64v(fi, (const float4*)&x1[j*64])) + ssq1[j];
        } else sd[g][u] = INFINITY;
      }
    }
    float T20;
    {
      float rd[32];
      #pragma unroll
      for (int q = 0; q < 32; ++q) rd[q] = INFINITY;
      #pragma unroll
      for (int g = 0; g < 3; ++g) {
        float bd[16];
        #pragma unroll
        for (int u = 0; u < 16; ++u) bd[u] = sd[g][u];
        vsort16(bd);
        vmerge16(rd, bd);
      }
      vmergelane(rd, 1); vmergelane(rd, 2); vmergelane(rd, 4);
      T20 = rd[19];                      // row-uniform
    }
    #pragma unroll
    for (int g = 0; g < 3; ++g) {
      #pragma unroll
      for (int u = 0; u < 16; ++u) {
        int slot = (g*16 + u)*8 + lane;
        if (slot < n) {
          float d = sd[g][u];
          int j = cbase + (int)surv[r][slot];
          if (d < T20) {
            int pos = atomicAdd(&oc[r], 1);          // <= 19 strict-less
            idx2[row*KNB + pos] = j;
          } else if (d == T20) {
            int pos = atomicAdd(&ec[r], 1);
            if (pos < 16) eqj[r][pos] = j;
          }
        }
      }
    }
    __syncthreads();
    if (lane == 0) {
      int m = oc[r];
      int e = ec[r] < 16 ? ec[r] : 16;
      int need = KNB - m;                // >= 1
      for (int it = 0; it < need; ++it) {
        int best = 0x7fffffff, bq = -1;
        for (int q = 0; q < e; ++q) {
          int v = eqj[r][q];
          if (v < best) { best = v; bq = q; }
        }
        if (bq < 0) break;
        eqj[r][bq] = 0x7fffffff;
        idx2[row*KNB + m + it] = best;
      }
    }
  }
}

// ---------------- mlp2: edge MLP 128->128, shared-xi decomposition ----------------
__global__ __launch_bounds__(256) void k_mlp2(const float* __restrict__ x1, const int* __restrict__ idx2,
                                              const short* __restrict__ wtg, const float* __restrict__ w2,
                                              const float* __restrict__ b2,
                                              float* __restrict__ xmx, float* __restrict__ xmn,
                                              float* __restrict__ sums) {
  __shared__ __align__(16) short Elds[4*32*72];   // diffs only: [p][row][k<64], pitch 72
  __shared__ float xi_s[4][64];
  __shared__ float vi[4][128];
  __shared__ int js[4][KNB];
  int t = threadIdx.x;
  if (t < 4*KNB) js[t/KNB][t%KNB] = idx2[blockIdx.x*4*KNB + t];
  {
    int p = t >> 6, k = t & 63;
    xi_s[p][k] = x1[(blockIdx.x*4 + p)*64 + k];
  }
  __syncthreads();
  // vi[p][c] = b2[c] + sum_{k<64} xi[k]*w2[k][c]  (fp32 exact top-half + bias)
  #pragma unroll
  for (int v2 = 0; v2 < 2; ++v2) {
    int v = t + v2*256;
    int p = v >> 7, c = v & 127;
    float a = b2[c];
    #pragma unroll 8
    for (int k = 0; k < 64; ++k) a += xi_s[p][k] * w2[k*128 + c];
    vi[p][c] = a;
  }
  // stage E diffs (bf16): 4 pts x 32 rows x 8 chunks of 8
  #pragma unroll
  for (int cc = 0; cc < 4; ++cc) {
    int v = t + cc*256;
    int p  = v >> 8;
    int rr = (v >> 3) & 31;
    int kc = v & 7;
    short8 outv = {0,0,0,0,0,0,0,0};
    if (rr < KNB) {
      int j = js[p][rr];
      float4 j0 = ((const float4*)x1)[j*16 + kc*2];
      float4 j1 = ((const float4*)x1)[j*16 + kc*2 + 1];
      const float* xp = &xi_s[p][kc*8];
      outv[0]=f2bf(j0.x-xp[0]); outv[1]=f2bf(j0.y-xp[1]); outv[2]=f2bf(j0.z-xp[2]); outv[3]=f2bf(j0.w-xp[3]);
      outv[4]=f2bf(j1.x-xp[4]); outv[5]=f2bf(j1.y-xp[5]); outv[6]=f2bf(j1.z-xp[6]); outv[7]=f2bf(j1.w-xp[7]);
    }
    *(short8*)&Elds[p*2304 + rr*72 + kc*8] = outv;
  }
  __syncthreads();
  // compute: wave w owns cols [w*32, w*32+32); B-frags from global wtg (bottom half)
  int w = t >> 6, l = t & 63;
  int colA = w*32 + (l & 15);
  int colB = colA + 16;
  short8 bfr[2][2];
  #pragma unroll
  for (int n = 0; n < 2; ++n)
    #pragma unroll
    for (int kb = 0; kb < 2; ++kb) {
      int col = w*32 + n*16 + (l & 15);
      int k0 = 64 + kb*32 + (l >> 4)*8;
      bfr[n][kb] = *(const short8*)&wtg[col*128 + k0];
    }
  float sT0=0.f, qT0=0.f, sT1=0.f, qT1=0.f;
  #pragma unroll
  for (int p = 0; p < 4; ++p) {
    int i = blockIdx.x*4 + p;
    float vA = vi[p][colA], vB = vi[p][colB];
    float mx0=-INFINITY, mn0=INFINITY, s0=0.f, q0=0.f;
    float mx1=-INFINITY, mn1=INFINITY, s1=0.f, q1=0.f;
    #pragma unroll
    for (int m = 0; m < 2; ++m) {
      short8 af[2];
      #pragma unroll
      for (int kb = 0; kb < 2; ++kb) {
        int row = m*16 + (l & 15);
        int k0 = kb*32 + (l >> 4)*8;
        af[kb] = *(short8*)&Elds[p*2304 + row*72 + k0];
      }
      f32x4 acc0 = {vA, vA, vA, vA};
      f32x4 acc1 = {vB, vB, vB, vB};
      #pragma unroll
      for (int kb = 0; kb < 2; ++kb) {
        acc0 = __builtin_amdgcn_mfma_f32_16x16x32_bf16(af[kb], bfr[0][kb], acc0, 0, 0, 0);
        acc1 = __builtin_amdgcn_mfma_f32_16x16x32_bf16(af[kb], bfr[1][kb], acc1, 0, 0, 0);
      }
      int rbase = (l >> 4)*4 + m*16;
      #pragma unroll
      for (int reg = 0; reg < 4; ++reg) {
        bool valid = (rbase + reg) < KNB;
        float h0 = fmaxf(acc0[reg], 0.f);
        float h1 = fmaxf(acc1[reg], 0.f);
        if (valid) {
          mx0 = fmaxf(mx0, h0); mn0 = fminf(mn0, h0); s0 += h0; q0 += h0*h0;
          mx1 = fmaxf(mx1, h1); mn1 = fminf(mn1, h1); s1 += h1; q1 += h1*h1;
        }
      }
    }
    // butterfly over the 4 lane-groups sharing each col
    #pragma unroll
    for (int dlt = 16; dlt <= 32; dlt <<= 1) {
      mx0 = fmaxf(mx0, __shfl_xor(mx0, dlt)); mn0 = fminf(mn0, __shfl_xor(mn0, dlt));
      s0 += __shfl_xor(s0, dlt);              q0 += __shfl_xor(q0, dlt);
      mx1 = fmaxf(mx1, __shfl_xor(mx1, dlt)); mn1 = fminf(mn1, __shfl_xor(mn1, dlt));
      s1 += __shfl_xor(s1, dlt);              q1 += __shfl_xor(q1, dlt);
    }
    if (l < 16) {
      xmx[i*128 + colA] = mx0; xmx[i*128 + colB] = mx1;
      xmn[i*128 + colA] = mn0; xmn[i*128 + colB] = mn1;
    }
    sT0 += s0; qT0 += q0; sT1 += s1; qT1 += q1;
  }
  if (l < 16) {
    atomicAdd(&sums[colA], sT0);       atomicAdd(&sums[colB], sT1);
    atomicAdd(&sums[128 + colA], qT0); atomicAdd(&sums[128 + colB], qT1);
  }
}

// ---------------- bn2 apply ----------------
__global__ __launch_bounds__(256) void k_bn2apply(const float* __restrict__ sums, const float* __restrict__ g,
                                                  const float* __restrict__ be, const float* __restrict__ xmx,
                                                  const float* __restrict__ xmn, float* __restrict__ x2) {
  __shared__ float sc_s[128], sh_s[128];
  int t = threadIdx.x;
  if (t < 128) {
    float m = sums[t] * (1.f/327680.f);
    float v = sums[128+t] * (1.f/327680.f) - m*m;
    float sc = g[t] / sqrtf(v + 1e-5f);
    sc_s[t] = sc; sh_s[t] = be[t] - m*sc;
  }
  __syncthreads();
  int c = t & 127;
  int i = blockIdx.x*2 + (t>>7);
  float sc = sc_s[c], sh = sh_s[c];
  float val = (sc >= 0.f) ? xmx[i*128+c] : xmn[i*128+c];
  x2[i*128+c] = sc*val + sh;
}

// ---------------- gemmF: relu([x1|x2] @ wf + bf); channel sums + per-batch max/min only ----------------
__global__ __launch_bounds__(256) void k_gemmF(const float* __restrict__ x1, const float* __restrict__ x2,
                                               const float* __restrict__ wf, const float* __restrict__ bf,
                                               float* __restrict__ sumsF, unsigned* __restrict__ hpmx,
                                               unsigned* __restrict__ hpmn) {
  __shared__ float A_s[64*193];
  __shared__ __align__(16) float B_s[192*64];
  __shared__ float red[1024];
  int t = threadIdx.x;
  int rt = blockIdx.x >> 2;
  int ct = blockIdx.x & 3;
  for (int v = t; v < 64*48; v += 256) {
    int r = v / 48, gg = v - r*48;
    int row = rt*64 + r;
    float4 e = (gg < 16) ? ((const float4*)x1)[row*16 + gg]
                         : ((const float4*)x2)[row*32 + (gg-16)];
    float* p = &A_s[r*193 + gg*4];
    p[0]=e.x; p[1]=e.y; p[2]=e.z; p[3]=e.w;
  }
  for (int v = t; v < 192*16; v += 256) {
    int d = v >> 4, c4 = v & 15;
    *(float4*)&B_s[d*64 + c4*4] = ((const float4*)wf)[d*64 + ct*16 + c4];
  }
  __syncthreads();
  int rg = t & 15, cg = t >> 4;
  float acc[4][4];
  #pragma unroll
  for (int a=0;a<4;a++) { acc[a][0]=0.f; acc[a][1]=0.f; acc[a][2]=0.f; acc[a][3]=0.f; }
  for (int d = 0; d < 192; ++d) {
    float a0 = A_s[(rg*4+0)*193 + d];
    float a1 = A_s[(rg*4+1)*193 + d];
    float a2 = A_s[(rg*4+2)*193 + d];
    float a3 = A_s[(rg*4+3)*193 + d];
    float b0 = B_s[d*64 + cg];
    float b1 = B_s[d*64 + cg + 16];
    float b2 = B_s[d*64 + cg + 32];
    float b3 = B_s[d*64 + cg + 48];
    acc[0][0]+=a0*b0; acc[0][1]+=a0*b1; acc[0][2]+=a0*b2; acc[0][3]+=a0*b3;
    acc[1][0]+=a1*b0; acc[1][1]+=a1*b1; acc[1][2]+=a1*b2; acc[1][3]+=a1*b3;
    acc[2][0]+=a2*b0; acc[2][1]+=a2*b1; acc[2][2]+=a2*b2; acc[2][3]+=a2*b3;
    acc[3][0]+=a3*b0; acc[3][1]+=a3*b1; acc[3][2]+=a3*b2; acc[3][3]+=a3*b3;
  }
  float hv[4][4];
  #pragma unroll
  for (int ss=0; ss<4; ++ss) {
    float bb = bf[ct*64 + cg + ss*16];
    #pragma unroll
    for (int rr=0; rr<4; ++rr) hv[rr][ss] = fmaxf(acc[rr][ss] + bb, 0.f);
  }
  int b = rt >> 5;
  #pragma unroll
  for (int ss=0; ss<4; ++ss) red[rg*64 + cg + ss*16] = hv[0][ss]+hv[1][ss]+hv[2][ss]+hv[3][ss];
  __syncthreads();
  if (t < 64) {
    float v = 0.f;
    #pragma unroll
    for (int r=0;r<16;r++) v += red[r*64 + t];
    atomicAdd(&sumsF[ct*64 + t], v);
  }
  __syncthreads();
  #pragma unroll
  for (int ss=0; ss<4; ++ss) red[rg*64 + cg + ss*16] =
      hv[0][ss]*hv[0][ss]+hv[1][ss]*hv[1][ss]+hv[2][ss]*hv[2][ss]+hv[3][ss]*hv[3][ss];
  __syncthreads();
  if (t < 64) {
    float v = 0.f;
    #pragma unroll
    for (int r=0;r<16;r++) v += red[r*64 + t];
    atomicAdd(&sumsF[256 + ct*64 + t], v);
  }
  __syncthreads();
  #pragma unroll
  for (int ss=0; ss<4; ++ss) red[rg*64 + cg + ss*16] =
      fmaxf(fmaxf(hv[0][ss],hv[1][ss]), fmaxf(hv[2][ss],hv[3][ss]));
  __syncthreads();
  if (t < 64) {
    float v = -INFINITY;
    #pragma unroll
    for (int r=0;r<16;r++) v = fmaxf(v, red[r*64 + t]);
    atomicMax(&hpmx[b*256 + ct*64 + t], __float_as_uint(v));
  }
  __syncthreads();
  #pragma unroll
  for (int ss=0; ss<4; ++ss) red[rg*64 + cg + ss*16] =
      fminf(fminf(hv[0][ss],hv[1][ss]), fminf(hv[2][ss],hv[3][ss]));
  __syncthreads();
  if (t < 64) {
    float v = INFINITY;
    #pragma unroll
    for (int r=0;r<16;r++) v = fminf(v, red[r*64 + t]);
    atomicMin(&hpmn[b*256 + ct*64 + t], __float_as_uint(v));
  }
}

// ---------------- head ----------------
__global__ __launch_bounds__(256) void k_head(const float* __restrict__ sumsF, const float* __restrict__ gf,
                                              const float* __restrict__ bef,
                                              const unsigned* __restrict__ hpmx, const unsigned* __restrict__ hpmn,
                                              const float* __restrict__ wo1, const float* __restrict__ bo1,
                                              const float* __restrict__ go1, const float* __restrict__ beo1,
                                              const float* __restrict__ wo2, const float* __restrict__ bo2,
                                              const float* __restrict__ go2, const float* __restrict__ beo2,
                                              const float* __restrict__ wo3, const float* __restrict__ bo3,
                                              float* __restrict__ out) {
  __shared__ float hp[8][256];
  __shared__ float u1[8][128];
  __shared__ float u2[8][64];
  __shared__ float lg[8][16];
  int t = threadIdx.x;
  {
    float m = sumsF[t] * (1.f/16384.f);
    float v = sumsF[256+t] * (1.f/16384.f) - m*m;
    float sc = gf[t] / sqrtf(v + 1e-5f);
    float sh = bef[t] - m*sc;
    for (int b = 0; b < 8; ++b) {
      unsigned bits = (sc >= 0.f) ? hpmx[b*256+t] : hpmn[b*256+t];
      hp[b][t] = sc*__uint_as_float(bits) + sh;
    }
  }
  __syncthreads();
  for (int p = t; p < 1024; p += 256) {
    int b = p >> 7, c = p & 127;
    float z = bo1[c];
    for (int d = 0; d < 256; ++d) z += hp[b][d]*wo1[d*128+c];
    u1[b][c] = fmaxf(z, 0.f);
  }
  __syncthreads();
  if (t < 128) {
    float m = 0.f;
    for (int b=0;b<8;b++) m += u1[b][t];
    m *= 0.125f;
    float v = 0.f;
    for (int b=0;b<8;b++) { float dd = u1[b][t]-m; v += dd*dd; }
    v *= 0.125f;
    float sc = go1[t]/sqrtf(v+1e-5f), sh = beo1[t]-m*sc;
    for (int b=0;b<8;b++) u1[b][t] = sc*u1[b][t]+sh;
  }
  __syncthreads();
  for (int p = t; p < 512; p += 256) {
    int b = p >> 6, c = p & 63;
    float z = bo2[c];
    for (int d = 0; d < 128; ++d) z += u1[b][d]*wo2[d*64+c];
    u2[b][c] = fmaxf(z, 0.f);
  }
  __syncthreads();
  if (t < 64) {
    float m = 0.f;
    for (int b=0;b<8;b++) m += u2[b][t];
    m *= 0.125f;
    float v = 0.f;
    for (int b=0;b<8;b++) { float dd = u2[b][t]-m; v += dd*dd; }
    v *= 0.125f;
    float sc = go2[t]/sqrtf(v+1e-5f), sh = beo2[t]-m*sc;
    for (int b=0;b<8;b++) u2[b][t] = sc*u2[b][t]+sh;
  }
  __syncthreads();
  if (t < 128) {
    int b = t >> 4, c = t & 15;
    float z = bo3[c];
    for (int d = 0; d < 64; ++d) z += u2[b][d]*wo3[d*16+c];
    lg[b][c] = z;
  }
  __syncthreads();
  if (t < 8) {
    float m = -INFINITY;
    for (int j=0;j<16;j++) m = fmaxf(m, lg[t][j]);
    float s = 0.f;
    for (int j=0;j<16;j++) s += expf(lg[t][j]-m);
    float ls = logf(s);
    for (int j=0;j<16;j++) out[t*16+j] = (lg[t][j]-m) - ls;
  }
}

// ---------------- launch ----------------
extern "C" void kernel_launch(void* const* d_in, const int* in_sizes, int n_in,
                              void* d_out, int out_size, void* d_ws, size_t ws_size,
                              hipStream_t stream) {
  (void)in_sizes; (void)n_in; (void)out_size; (void)ws_size;
  const float* pos = (const float*)d_in[0];
  const float* x   = (const float*)d_in[1];
  const float* w1  = (const float*)d_in[3];
  const float* b1  = (const float*)d_in[4];
  const float* g1  = (const float*)d_in[5];
  const float* be1 = (const float*)d_in[6];
  const float* w2  = (const float*)d_in[7];
  const float* b2  = (const float*)d_in[8];
  const float* g2  = (const float*)d_in[9];
  const float* be2 = (const float*)d_in[10];
  const float* wf  = (const float*)d_in[11];
  const float* bf  = (const float*)d_in[12];
  const float* gf  = (const float*)d_in[13];
  const float* bef = (const float*)d_in[14];
  const float* wo1 = (const float*)d_in[15];
  const float* bo1 = (const float*)d_in[16];
  const float* go1 = (const float*)d_in[17];
  const float* beo1= (const float*)d_in[18];
  const float* wo2 = (const float*)d_in[19];
  const float* bo2 = (const float*)d_in[20];
  const float* go2 = (const float*)d_in[21];
  const float* beo2= (const float*)d_in[22];
  const float* wo3 = (const float*)d_in[23];
  const float* bo3 = (const float*)d_in[24];

  char* ws = (char*)d_ws;
  float4*   f0    = (float4*)  (ws + OFF_F0);
  float*    ssq0  = (float*)   (ws + OFF_SSQ0);
  int*      idx1  = (int*)     (ws + OFF_IDX1);
  float*    xmx1  = (float*)   (ws + OFF_XMX1);
  float*    xmn1  = (float*)   (ws + OFF_XMN1);
  float*    sum1  = (float*)   (ws + OFF_SUM1);
  float*    x1    = (float*)   (ws + OFF_X1);
  float*    ssq1  = (float*)   (ws + OFF_SSQ1);
  int*      idx2  = (int*)     (ws + OFF_IDX2);
  float*    xmx2  = (float*)   (ws + OFF_XMX2);
  float*    xmn2  = (float*)   (ws + OFF_XMN2);
  float*    sum2  = (float*)   (ws + OFF_SUM2);
  float*    x2    = (float*)   (ws + OFF_X2);
  float*    sumF  = (float*)   (ws + OFF_SUMF);
  unsigned* hpmx  = (unsigned*)(ws + OFF_HPMX);
  unsigned* hpmn  = (unsigned*)(ws + OFF_HPMN);
  short*    wtg   = (short*)   (ws + OFF_X2);    // aliases x2 head (x2 dead until bn2apply)
  float*    rowTg = (float*)   (ws + OFF_XMX1);  // aliases xmx1 (dead after bn1apply)

  k_init    <<<64,   256, 0, stream>>>(pos, x, w2, f0, ssq0, wtg, sum1, sum2, sumF, hpmx, hpmn);
  k_knn1    <<<2048, 256, 0, stream>>>(f0, ssq0, idx1);
  k_mlp1    <<<512,  256, 0, stream>>>(f0, idx1, w1, b1, xmx1, xmn1, sum1);
  k_bn1apply<<<4096, 256, 0, stream>>>(sum1, g1, be1, xmx1, xmn1, x1);
  k_ssq1    <<<64,   256, 0, stream>>>(x1, ssq1);
  k_thresh  <<<512,  256, 0, stream>>>(x1, ssq1, rowTg);
  k_knn2    <<<512,  256, 0, stream>>>(x1, ssq1, rowTg, idx2);
  k_mlp2    <<<4096, 256, 0, stream>>>(x1, idx2, wtg, w2, b2, xmx2, xmn2, sum2);
  k_bn2apply<<<8192, 256, 0, stream>>>(sum2, g2, be2, xmx2, xmn2, x2);
  k_gemmF   <<<1024, 256, 0, stream>>>(x1, x2, wf, bf, sumF, hpmx, hpmn);
  k_head    <<<1,    256, 0, stream>>>(sumF, gf, bef, hpmx, hpmn,
                                       wo1, bo1, go1, beo1, wo2, bo2, go2, beo2, wo3, bo3,
                                       (float*)d_out);
}